// Round 5
// baseline (12201.581 us; speedup 1.0000x reference)
//
#include <hip/hip_runtime.h>

// ---------------------------------------------------------------------------
// SageCox: 4-layer GraphSAGE (mean aggr), N=100000 nodes, E=640000 edges.
// Per layer: out = mean_neigh(x) @ Wl + bl + x @ Wr
// Restructured: p = x@Wl ; acc = x@Wr + bl ; acc[d] += invdeg[d]*sum p[src].
// Aggregation via CSR gather (no float atomics).
// Proj: register-only GEMM with EXPLICIT double-buffered prefetch: chunk
// (4 k-values) of x (4 float4) + W (4*NQ float4) loaded into alternating
// register buffers one iteration ahead of the FMA block, so the compiler
// emits counted vmcnt and loads overlap FMAs. Fully unrolled -> all buffer
// indices static (no scratch).
// ---------------------------------------------------------------------------

#define NNODES 100000
#define NEDGES 640000

// ---- CSR build ------------------------------------------------------------

__global__ void hist_kernel(const int* __restrict__ edst, int* __restrict__ deg, int E) {
    int i = blockIdx.x * blockDim.x + threadIdx.x;
    if (i < E) atomicAdd(&deg[edst[i]], 1);
}

__global__ void scanA_kernel(const int* __restrict__ deg, int* __restrict__ bsum, int N) {
    __shared__ int s[256];
    int i = blockIdx.x * 256 + threadIdx.x;
    s[threadIdx.x] = (i < N) ? deg[i] : 0;
    __syncthreads();
    for (int off = 128; off > 0; off >>= 1) {
        if (threadIdx.x < off) s[threadIdx.x] += s[threadIdx.x + off];
        __syncthreads();
    }
    if (threadIdx.x == 0) bsum[blockIdx.x] = s[0];
}

__global__ void scanB_kernel(const int* __restrict__ bsum, int* __restrict__ bpre, int nb) {
    __shared__ int s[512];
    int t = threadIdx.x;
    int v = (t < nb) ? bsum[t] : 0;
    s[t] = v;
    __syncthreads();
    for (int off = 1; off < 512; off <<= 1) {
        int add = (t >= off) ? s[t - off] : 0;
        __syncthreads();
        s[t] += add;
        __syncthreads();
    }
    if (t < nb) bpre[t] = s[t] - v;  // exclusive
}

__global__ void scanC_kernel(const int* __restrict__ deg, const int* __restrict__ bpre,
                             int* __restrict__ rowptr, int* __restrict__ cursor, int N, int E) {
    __shared__ int s[256];
    int t = threadIdx.x;
    int i = blockIdx.x * 256 + t;
    int v = (i < N) ? deg[i] : 0;
    s[t] = v;
    __syncthreads();
    for (int off = 1; off < 256; off <<= 1) {
        int add = (t >= off) ? s[t - off] : 0;
        __syncthreads();
        s[t] += add;
        __syncthreads();
    }
    if (i < N) {
        int excl = bpre[blockIdx.x] + s[t] - v;
        rowptr[i] = excl;
        cursor[i] = excl;
        if (i == N - 1) rowptr[N] = E;
    }
}

__global__ void fill_kernel(const int* __restrict__ esrc, const int* __restrict__ edst,
                            int* __restrict__ cursor, int* __restrict__ csr, int E) {
    int i = blockIdx.x * blockDim.x + threadIdx.x;
    if (i < E) {
        int pos = atomicAdd(&cursor[edst[i]], 1);
        csr[pos] = esrc[i];
    }
}

// ---- weight pack ----------------------------------------------------------

__global__ void pack_kernel(const float* __restrict__ Wl, const float* __restrict__ Wr,
                            float* __restrict__ Wcat, int DIN, int DINP, int DOUT,
                            int DOUTP, int CWALL) {
    int idx = blockIdx.x * blockDim.x + threadIdx.x;
    int tot = DINP * CWALL;
    if (idx >= tot) return;
    int k = idx / CWALL, c = idx - k * CWALL;
    float v = 0.0f;
    if (k < DIN) {
        if (c < DOUT) v = Wl[k * DOUT + c];
        else if (c >= DOUTP && c < DOUTP + DOUT) v = Wr[k * DOUT + (c - DOUTP)];
    }
    Wcat[idx] = v;
}

// ---- projection: p = x@Wl, out = x@Wr + bl (register double-buffered) -----

template <int DINP, int SIN, int DOUT, int SOUT, int DOUTP, int CWALL, int MINW>
__global__ void __launch_bounds__(256, MINW)
proj_kernel(const float* __restrict__ x, const float* __restrict__ Wcat,
            const float* __restrict__ bl, float* __restrict__ p,
            float* __restrict__ out, int N) {
    constexpr int NQ = CWALL / 64;
    constexpr int NCH = DINP / 4;
    const int row0 = blockIdx.x * 64;
    const int cq = threadIdx.x & 15;
    const int rq = threadIdx.x >> 4;
    const int c0 = cq * 4;

    const float* __restrict__ xr[4];
#pragma unroll
    for (int j = 0; j < 4; ++j) {
        int r = row0 + rq * 4 + j;
        if (r >= N) r = N - 1;           // clamp: results discarded at store
        xr[j] = x + (size_t)r * SIN;
    }
    const float* __restrict__ wbase = Wcat + c0;

    float acc[4][NQ * 4] = {};
    float xbuf[2][4][4];                 // [buf][row][kk]
    float wbuf[2][4][NQ][4];             // [buf][kk][q][i]

    // prologue: chunk 0 -> buf 0
#pragma unroll
    for (int j = 0; j < 4; ++j)
        *(float4*)&xbuf[0][j][0] = *(const float4*)(xr[j]);
#pragma unroll
    for (int kk = 0; kk < 4; ++kk)
#pragma unroll
        for (int q = 0; q < NQ; ++q)
            *(float4*)&wbuf[0][kk][q][0] =
                *(const float4*)(wbase + (size_t)kk * CWALL + q * 64);

#pragma unroll
    for (int ch = 0; ch < NCH; ++ch) {
        const int cur = ch & 1;
        const int nxt = cur ^ 1;
        if (ch + 1 < NCH) {
            const int k0 = (ch + 1) * 4;
#pragma unroll
            for (int j = 0; j < 4; ++j)
                *(float4*)&xbuf[nxt][j][0] = *(const float4*)(xr[j] + k0);
#pragma unroll
            for (int kk = 0; kk < 4; ++kk)
#pragma unroll
                for (int q = 0; q < NQ; ++q)
                    *(float4*)&wbuf[nxt][kk][q][0] =
                        *(const float4*)(wbase + (size_t)(k0 + kk) * CWALL + q * 64);
        }
#pragma unroll
        for (int kk = 0; kk < 4; ++kk)
#pragma unroll
            for (int q = 0; q < NQ; ++q)
#pragma unroll
                for (int j = 0; j < 4; ++j)
#pragma unroll
                    for (int i = 0; i < 4; ++i)
                        acc[j][q * 4 + i] = fmaf(xbuf[cur][j][kk],
                                                 wbuf[cur][kk][q][i],
                                                 acc[j][q * 4 + i]);
    }

#pragma unroll
    for (int j = 0; j < 4; ++j) {
        const int row = row0 + rq * 4 + j;
        if (row >= N) continue;
#pragma unroll
        for (int q = 0; q < NQ; ++q)
#pragma unroll
            for (int i = 0; i < 4; ++i) {
                const int c = c0 + q * 64 + i;
                if (c < DOUT) {
                    p[(size_t)row * SOUT + c] = acc[j][q * 4 + i];
                } else if (c >= DOUTP && c < DOUTP + DOUT) {
                    const int co = c - DOUTP;
                    out[(size_t)row * SOUT + co] = acc[j][q * 4 + i] + bl[co];
                }
            }
    }
}

// ---- gather aggregation: out[d] += invdeg * sum_{s in N(d)} p[s] ----------
// node id readfirstlane'd -> beg/end/csr become scalar loads; neighbor loop
// unrolled x2 with independent accumulators to overlap row-load latency.

template <int DOUT, int SP>
__global__ void __launch_bounds__(256)
gather_kernel(const int* __restrict__ rowptr, const int* __restrict__ csr,
              const float* __restrict__ p, float* __restrict__ out, int N) {
    const int node = __builtin_amdgcn_readfirstlane((blockIdx.x * 256 + threadIdx.x) >> 6);
    const int lane = threadIdx.x & 63;
    if (node >= N) return;
    const int beg = rowptr[node];
    const int end = rowptr[node + 1];
    const float inv = 1.0f / (float)max(end - beg, 1);
    float a0 = 0.0f, a1 = 0.0f, b0 = 0.0f, b1 = 0.0f;
    int j = beg;
    for (; j + 2 <= end; j += 2) {
        const int s0 = csr[j];
        const int s1 = csr[j + 1];
        const float* __restrict__ p0 = p + (size_t)s0 * SP;
        const float* __restrict__ p1 = p + (size_t)s1 * SP;
        if (lane < DOUT) { a0 += p0[lane]; a1 += p1[lane]; }
        if (DOUT > 64 && lane + 64 < DOUT) { b0 += p0[lane + 64]; b1 += p1[lane + 64]; }
    }
    if (j < end) {
        const float* __restrict__ p0 = p + (size_t)csr[j] * SP;
        if (lane < DOUT) a0 += p0[lane];
        if (DOUT > 64 && lane + 64 < DOUT) b0 += p0[lane + 64];
    }
    if (lane < DOUT) out[(size_t)node * SP + lane] += inv * (a0 + a1);
    if (DOUT > 64 && lane + 64 < DOUT) out[(size_t)node * SP + lane + 64] += inv * (b0 + b1);
}

__global__ void gather1_kernel(const int* __restrict__ rowptr, const int* __restrict__ csr,
                               const float* __restrict__ p, float* __restrict__ out, int N) {
    const int node = blockIdx.x * blockDim.x + threadIdx.x;
    if (node >= N) return;
    const int beg = rowptr[node];
    const int end = rowptr[node + 1];
    const float inv = 1.0f / (float)max(end - beg, 1);
    float a0 = 0.0f, a1 = 0.0f;
    int j = beg;
    for (; j + 2 <= end; j += 2) { a0 += p[csr[j]]; a1 += p[csr[j + 1]]; }
    if (j < end) a0 += p[csr[j]];
    out[node] += inv * (a0 + a1);
}

// ---- layer 3 (28 -> 1) GEMV ----------------------------------------------

__global__ void __launch_bounds__(256)
gemv3_kernel(const float* __restrict__ x, const float* __restrict__ Wl,
             const float* __restrict__ bl, const float* __restrict__ Wr,
             float* __restrict__ p, float* __restrict__ out, int N) {
    const int row = blockIdx.x * 256 + threadIdx.x;
    if (row >= N) return;
    const float* __restrict__ xrow = x + (size_t)row * 28;
    float sl = 0.0f, sr = 0.0f;
#pragma unroll
    for (int k = 0; k < 28; ++k) {
        const float xv = xrow[k];
        sl = fmaf(xv, Wl[k], sl);
        sr = fmaf(xv, Wr[k], sr);
    }
    p[row] = sl;
    out[row] = sr + bl[0];
}

// ---------------------------------------------------------------------------

extern "C" void kernel_launch(void* const* d_in, const int* in_sizes, int n_in,
                              void* d_out, int out_size, void* d_ws, size_t ws_size,
                              hipStream_t stream) {
    const float* x  = (const float*)d_in[0];
    const int*   ei = (const int*)d_in[1];
    const int N = NNODES;
    const int E = NEDGES;
    const int* esrc = ei;
    const int* edst = ei + E;

    const float* Wl[4] = {(const float*)d_in[2], (const float*)d_in[5],
                          (const float*)d_in[8], (const float*)d_in[11]};
    const float* bl[4] = {(const float*)d_in[3], (const float*)d_in[6],
                          (const float*)d_in[9], (const float*)d_in[12]};
    const float* Wr[4] = {(const float*)d_in[4], (const float*)d_in[7],
                          (const float*)d_in[10], (const float*)d_in[13]};

    // workspace layout (floats), 16B-aligned chunks
    float* ws = (float*)d_ws;
    size_t off = 0;
    auto alloc = [&](size_t n) { float* r = ws + off; off += (n + 3) & ~(size_t)3; return r; };
    float* Wc0  = alloc(128 * 192);
    float* Wc1  = alloc(88 * 128);
    float* Wc2  = alloc(56 * 64);
    float* pbuf = alloc((size_t)N * 88);   // stride-88 (L0) / 56 (L1) / 28 (L2)
    float* bufA = alloc((size_t)N * 88);   // L0/L2 acc
    float* bufB = alloc((size_t)N * 56);   // L1 acc
    int* degi   = (int*)alloc(N);
    int* rowptr = (int*)alloc(N + 1);
    int* cursor = (int*)alloc(N);
    int* csr    = (int*)alloc(E);
    int* bsum   = (int*)alloc(512);
    int* bpre   = (int*)alloc(512);

    const int nb = (N + 255) / 256;  // 391

    // CSR build
    hipMemsetAsync(degi, 0, (size_t)N * sizeof(int), stream);
    hist_kernel<<<(E + 255) / 256, 256, 0, stream>>>(edst, degi, E);
    scanA_kernel<<<nb, 256, 0, stream>>>(degi, bsum, N);
    scanB_kernel<<<1, 512, 0, stream>>>(bsum, bpre, nb);
    scanC_kernel<<<nb, 256, 0, stream>>>(degi, bpre, rowptr, cursor, N, E);
    fill_kernel<<<(E + 255) / 256, 256, 0, stream>>>(esrc, edst, cursor, csr, E);

    // weight packs
    pack_kernel<<<(128 * 192 + 255) / 256, 256, 0, stream>>>(Wl[0], Wr[0], Wc0, 128, 128, 85, 88, 192);
    pack_kernel<<<(88 * 128 + 255) / 256, 256, 0, stream>>>(Wl[1], Wr[1], Wc1, 85, 88, 56, 64, 128);
    pack_kernel<<<(56 * 64 + 255) / 256, 256, 0, stream>>>(Wl[2], Wr[2], Wc2, 56, 56, 28, 32, 64);

    const int rowTiles = (N + 63) / 64;  // 1563

    // Layer 0: 128 -> 85 (strides: in 128, out 88)
    proj_kernel<128, 128, 85, 88, 88, 192, 2><<<rowTiles, 256, 0, stream>>>(
        x, Wc0, bl[0], pbuf, bufA, N);
    gather_kernel<85, 88><<<(N + 3) / 4, 256, 0, stream>>>(rowptr, csr, pbuf, bufA, N);

    // Layer 1: 85 -> 56 (in stride 88, out stride 56)
    proj_kernel<88, 88, 56, 56, 64, 128, 3><<<rowTiles, 256, 0, stream>>>(
        bufA, Wc1, bl[1], pbuf, bufB, N);
    gather_kernel<56, 56><<<(N + 3) / 4, 256, 0, stream>>>(rowptr, csr, pbuf, bufB, N);

    // Layer 2: 56 -> 28 (in stride 56, out stride 28)
    proj_kernel<56, 56, 28, 28, 32, 64, 4><<<rowTiles, 256, 0, stream>>>(
        bufB, Wc2, bl[2], pbuf, bufA, N);
    gather_kernel<28, 28><<<(N + 3) / 4, 256, 0, stream>>>(rowptr, csr, pbuf, bufA, N);

    // Layer 3: 28 -> 1 (in stride 28)
    gemv3_kernel<<<(N + 255) / 256, 256, 0, stream>>>(
        bufA, Wl[3], bl[3], Wr[3], pbuf, (float*)d_out, N);
    gather1_kernel<<<(N + 255) / 256, 256, 0, stream>>>(
        rowptr, csr, pbuf, (float*)d_out, N);
}

// Round 6
// 321.295 us; speedup vs baseline: 37.9762x; 37.9762x over previous
//
#include <hip/hip_runtime.h>

// ---------------------------------------------------------------------------
// SageCox: 4-layer GraphSAGE (mean aggr), N=100000, E=640000.
// out = mean_neigh(x)@Wl + bl + x@Wr  per layer.
// Restructured: p = x@Wl ; acc = x@Wr + bl ; x_next = bf16(acc + invdeg*sum p[src]).
// proj = MFMA bf16 (16x16x32, f32 accum). B (weights) register-resident per
// wave, loaded once from transposed bf16 pack WcT[col][K]. A = 16B row loads.
// Aggregation via CSR gather (no float atomics), p stored bf16.
// ---------------------------------------------------------------------------

#define NNODES 100000
#define NEDGES 640000

using bf16x8 = __attribute__((ext_vector_type(8))) short;
using f32x4  = __attribute__((ext_vector_type(4))) float;

__device__ __forceinline__ unsigned short f2bf(float f) {
    union { float f; unsigned u; } v; v.f = f;
    unsigned r = v.u + 0x7fffu + ((v.u >> 16) & 1u);
    return (unsigned short)(r >> 16);
}
__device__ __forceinline__ float bf2f(unsigned short b) {
    union { unsigned u; float f; } v; v.u = ((unsigned)b) << 16;
    return v.f;
}

// ---- CSR build ------------------------------------------------------------

__global__ void hist_kernel(const int* __restrict__ edst, int* __restrict__ deg, int E) {
    int i = blockIdx.x * blockDim.x + threadIdx.x;
    if (i < E) atomicAdd(&deg[edst[i]], 1);
}

__global__ void scanA_kernel(const int* __restrict__ deg, int* __restrict__ bsum, int N) {
    __shared__ int s[256];
    int i = blockIdx.x * 256 + threadIdx.x;
    s[threadIdx.x] = (i < N) ? deg[i] : 0;
    __syncthreads();
    for (int off = 128; off > 0; off >>= 1) {
        if (threadIdx.x < off) s[threadIdx.x] += s[threadIdx.x + off];
        __syncthreads();
    }
    if (threadIdx.x == 0) bsum[blockIdx.x] = s[0];
}

__global__ void scanB_kernel(const int* __restrict__ bsum, int* __restrict__ bpre, int nb) {
    __shared__ int s[512];
    int t = threadIdx.x;
    int v = (t < nb) ? bsum[t] : 0;
    s[t] = v;
    __syncthreads();
    for (int off = 1; off < 512; off <<= 1) {
        int add = (t >= off) ? s[t - off] : 0;
        __syncthreads();
        s[t] += add;
        __syncthreads();
    }
    if (t < nb) bpre[t] = s[t] - v;  // exclusive
}

__global__ void scanC_kernel(const int* __restrict__ deg, const int* __restrict__ bpre,
                             int* __restrict__ rowptr, int* __restrict__ cursor, int N, int E) {
    __shared__ int s[256];
    int t = threadIdx.x;
    int i = blockIdx.x * 256 + t;
    int v = (i < N) ? deg[i] : 0;
    s[t] = v;
    __syncthreads();
    for (int off = 1; off < 256; off <<= 1) {
        int add = (t >= off) ? s[t - off] : 0;
        __syncthreads();
        s[t] += add;
        __syncthreads();
    }
    if (i < N) {
        int excl = bpre[blockIdx.x] + s[t] - v;
        rowptr[i] = excl;
        cursor[i] = excl;
        if (i == N - 1) rowptr[N] = E;
    }
}

__global__ void fill_kernel(const int* __restrict__ esrc, const int* __restrict__ edst,
                            int* __restrict__ cursor, int* __restrict__ csr, int E) {
    int i = blockIdx.x * blockDim.x + threadIdx.x;
    if (i < E) {
        int pos = atomicAdd(&cursor[edst[i]], 1);
        csr[pos] = esrc[i];
    }
}

// ---- fp32 -> bf16 convert -------------------------------------------------

__global__ void cvt_kernel(const float* __restrict__ in, unsigned short* __restrict__ out, int n4) {
    int i = blockIdx.x * blockDim.x + threadIdx.x;
    if (i >= n4) return;
    const float4 f = *(const float4*)(in + (size_t)i * 4);
    unsigned short* o = out + (size_t)i * 4;
    o[0] = f2bf(f.x); o[1] = f2bf(f.y); o[2] = f2bf(f.z); o[3] = f2bf(f.w);
}

// ---- weight pack: WcT[c][k] bf16, c<DOUT -> Wl, DOUTP<=c<DOUTP+DOUT -> Wr -

__global__ void packT_kernel(const float* __restrict__ Wl, const float* __restrict__ Wr,
                             unsigned short* __restrict__ WcT, int DIN, int KP,
                             int DOUT, int DOUTP, int CW) {
    int idx = blockIdx.x * blockDim.x + threadIdx.x;
    if (idx >= KP * CW) return;
    int c = idx / KP, k = idx - c * KP;
    float v = 0.0f;
    if (k < DIN) {
        if (c < DOUT) v = Wl[k * DOUT + c];
        else if (c >= DOUTP && c < DOUTP + DOUT) v = Wr[k * DOUT + (c - DOUTP)];
    }
    WcT[idx] = f2bf(v);
}

// ---- MFMA projection ------------------------------------------------------
// block = 4 waves, each wave owns one 16-row tile; B frags register-resident.
// A-frag: lane l holds x[row0+(l&15)][kt*32+(l>>4)*8 + 0..7]
// B-frag: lane l holds W[kt*32+(l>>4)*8+e][CB+nt*16+(l&15)] via WcT[c][k]
// D: row = row0+(l>>4)*4+j, col = CB+nt*16+(l&15)   (m89/m91-verified layout)

template <int KP, int SIN, int CB, int NT, int DOUT, int DOUTP, int SPP, int SACC>
__global__ void __launch_bounds__(256)
projm_kernel(const unsigned short* __restrict__ xin,
             const unsigned short* __restrict__ WcT,
             const float* __restrict__ bl,
             unsigned short* __restrict__ p,
             float* __restrict__ acc_out, int N) {
    constexpr int KT = KP / 32;
    const int lane = threadIdx.x & 63;
    const int wave = threadIdx.x >> 6;
    const int l15 = lane & 15;
    const int lk  = lane >> 4;

    bf16x8 bfrag[KT][NT];
#pragma unroll
    for (int nt = 0; nt < NT; ++nt) {
        const unsigned short* wp = WcT + (size_t)(CB + nt * 16 + l15) * KP + lk * 8;
#pragma unroll
        for (int kt = 0; kt < KT; ++kt)
            bfrag[kt][nt] = *(const bf16x8*)(wp + kt * 32);
    }

    const int row0 = (blockIdx.x * 4 + wave) * 16;
    int arow = row0 + l15;
    if (arow >= N) arow = N - 1;              // clamp; stores skipped later
    const unsigned short* xr = xin + (size_t)arow * SIN + lk * 8;
    bf16x8 afrag[KT];
#pragma unroll
    for (int kt = 0; kt < KT; ++kt)
        afrag[kt] = *(const bf16x8*)(xr + kt * 32);

    f32x4 acc[NT];
#pragma unroll
    for (int nt = 0; nt < NT; ++nt) {
        f32x4 a = {0.f, 0.f, 0.f, 0.f};
#pragma unroll
        for (int kt = 0; kt < KT; ++kt)
            a = __builtin_amdgcn_mfma_f32_16x16x32_bf16(afrag[kt], bfrag[kt][nt], a, 0, 0, 0);
        acc[nt] = a;
    }

    const int rbase = row0 + lk * 4;
#pragma unroll
    for (int nt = 0; nt < NT; ++nt) {
        const int col = CB + nt * 16 + l15;
#pragma unroll
        for (int j = 0; j < 4; ++j) {
            const int row = rbase + j;
            if (row >= N) continue;
            const float v = acc[nt][j];
            if (col < DOUT) {
                p[(size_t)row * SPP + col] = f2bf(v);
            } else if (col >= DOUTP && col < DOUTP + DOUT) {
                const int co = col - DOUTP;
                acc_out[(size_t)row * SACC + co] = v + bl[co];
            }
        }
    }
}

// ---- gather: x_next = bf16(acc + invdeg * sum p[src]), zero-pad to PADN ---

template <int DOUT, int SP, int SA, int SN, int PADN>
__global__ void __launch_bounds__(256)
gatherb_kernel(const int* __restrict__ rowptr, const int* __restrict__ csr,
               const unsigned short* __restrict__ p, const float* __restrict__ acc,
               unsigned short* __restrict__ xnext, int N) {
    const int node = __builtin_amdgcn_readfirstlane((blockIdx.x * 256 + threadIdx.x) >> 6);
    const int lane = threadIdx.x & 63;
    if (node >= N) return;
    const int beg = rowptr[node], end = rowptr[node + 1];
    const float inv = 1.0f / (float)max(end - beg, 1);
    float a0 = 0.f, a1 = 0.f, b0 = 0.f, b1 = 0.f;
    int j = beg;
    for (; j + 2 <= end; j += 2) {
        const unsigned short* p0 = p + (size_t)csr[j] * SP;
        const unsigned short* p1 = p + (size_t)csr[j + 1] * SP;
        if (lane < DOUT) { a0 += bf2f(p0[lane]); a1 += bf2f(p1[lane]); }
        if (DOUT > 64 && lane + 64 < DOUT) { b0 += bf2f(p0[lane + 64]); b1 += bf2f(p1[lane + 64]); }
    }
    if (j < end) {
        const unsigned short* p0 = p + (size_t)csr[j] * SP;
        if (lane < DOUT) a0 += bf2f(p0[lane]);
        if (DOUT > 64 && lane + 64 < DOUT) b0 += bf2f(p0[lane + 64]);
    }
    if (lane < DOUT)
        xnext[(size_t)node * SN + lane] = f2bf(acc[(size_t)node * SA + lane] + inv * (a0 + a1));
    else if (lane < PADN)
        xnext[(size_t)node * SN + lane] = 0;
    if (DOUT > 64) {
        const int c2 = lane + 64;
        if (c2 < DOUT)
            xnext[(size_t)node * SN + c2] = f2bf(acc[(size_t)node * SA + c2] + inv * (b0 + b1));
        else if (c2 < PADN)
            xnext[(size_t)node * SN + c2] = 0;
    }
}

// ---- layer 3 (28 -> 1) GEMV + scalar gather -------------------------------

__global__ void __launch_bounds__(256)
gemv3_kernel(const unsigned short* __restrict__ x, const float* __restrict__ Wl,
             const float* __restrict__ bl, const float* __restrict__ Wr,
             float* __restrict__ p, float* __restrict__ out, int N) {
    const int row = blockIdx.x * 256 + threadIdx.x;
    if (row >= N) return;
    const unsigned short* xrow = x + (size_t)row * 32;
    float sl = 0.f, sr = 0.f;
#pragma unroll
    for (int k = 0; k < 28; ++k) {
        const float xv = bf2f(xrow[k]);
        sl = fmaf(xv, Wl[k], sl);
        sr = fmaf(xv, Wr[k], sr);
    }
    p[row] = sl;
    out[row] = sr + bl[0];
}

__global__ void gather1_kernel(const int* __restrict__ rowptr, const int* __restrict__ csr,
                               const float* __restrict__ p, float* __restrict__ out, int N) {
    const int node = blockIdx.x * blockDim.x + threadIdx.x;
    if (node >= N) return;
    const int beg = rowptr[node], end = rowptr[node + 1];
    const float inv = 1.0f / (float)max(end - beg, 1);
    float a0 = 0.f, a1 = 0.f;
    int j = beg;
    for (; j + 2 <= end; j += 2) { a0 += p[csr[j]]; a1 += p[csr[j + 1]]; }
    if (j < end) a0 += p[csr[j]];
    out[node] += inv * (a0 + a1);
}

// ---------------------------------------------------------------------------

extern "C" void kernel_launch(void* const* d_in, const int* in_sizes, int n_in,
                              void* d_out, int out_size, void* d_ws, size_t ws_size,
                              hipStream_t stream) {
    const float* x  = (const float*)d_in[0];
    const int*   ei = (const int*)d_in[1];
    const int N = NNODES;
    const int E = NEDGES;
    const int* esrc = ei;
    const int* edst = ei + E;

    const float* Wl[4] = {(const float*)d_in[2], (const float*)d_in[5],
                          (const float*)d_in[8], (const float*)d_in[11]};
    const float* bl[4] = {(const float*)d_in[3], (const float*)d_in[6],
                          (const float*)d_in[9], (const float*)d_in[12]};
    const float* Wr[4] = {(const float*)d_in[4], (const float*)d_in[7],
                          (const float*)d_in[10], (const float*)d_in[13]};

    // ---- workspace arena (byte offsets, 256B aligned) ----
    char* base = (char*)d_ws;
    size_t off = 0;
    auto alloc = [&](size_t bytes) {
        char* r = base + off;
        off += (bytes + 255) & ~(size_t)255;
        return r;
    };
    unsigned short* xb   = (unsigned short*)alloc((size_t)N * 128 * 2);  // x bf16; reused as x2 (N*64*2)
    unsigned short* pB   = (unsigned short*)alloc((size_t)N * 88 * 2);   // p bf16 (also L3 p fp32: N*4)
    float*          accB = (float*)alloc((size_t)N * 88 * 4);            // acc fp32 (all layers)
    unsigned short* xp   = (unsigned short*)alloc((size_t)N * 96 * 2);   // x1 (and x3: N*32*2)
    unsigned short* Wc0  = (unsigned short*)alloc((size_t)176 * 128 * 2);
    unsigned short* Wc1  = (unsigned short*)alloc((size_t)112 * 96 * 2);
    unsigned short* Wc2  = (unsigned short*)alloc((size_t)64 * 64 * 2);
    int* degi   = (int*)alloc((size_t)N * 4);
    int* rowptr = (int*)alloc((size_t)(N + 1) * 4);
    int* cursor = (int*)alloc((size_t)N * 4);
    int* csr    = (int*)alloc((size_t)E * 4);
    int* bsum   = (int*)alloc(512 * 4);
    int* bpre   = (int*)alloc(512 * 4);

    unsigned short* x2 = xb;                 // aliases (non-overlapping lifetimes)
    unsigned short* x3 = xp;
    float* p3 = (float*)pB;

    const int nb = (N + 255) / 256;  // 391

    // CSR build
    hipMemsetAsync(degi, 0, (size_t)N * sizeof(int), stream);
    hist_kernel<<<(E + 255) / 256, 256, 0, stream>>>(edst, degi, E);
    scanA_kernel<<<nb, 256, 0, stream>>>(degi, bsum, N);
    scanB_kernel<<<1, 512, 0, stream>>>(bsum, bpre, nb);
    scanC_kernel<<<nb, 256, 0, stream>>>(degi, bpre, rowptr, cursor, N, E);
    fill_kernel<<<(E + 255) / 256, 256, 0, stream>>>(esrc, edst, cursor, csr, E);

    // x -> bf16
    cvt_kernel<<<(N * 128 / 4 + 255) / 256, 256, 0, stream>>>(x, xb, N * 128 / 4);

    // weight packs (transposed, bf16, zero-padded)
    packT_kernel<<<(176 * 128 + 255) / 256, 256, 0, stream>>>(Wl[0], Wr[0], Wc0, 128, 128, 85, 85, 176);
    packT_kernel<<<(112 * 96 + 255) / 256, 256, 0, stream>>>(Wl[1], Wr[1], Wc1, 85, 96, 56, 56, 112);
    packT_kernel<<<(64 * 64 + 255) / 256, 256, 0, stream>>>(Wl[2], Wr[2], Wc2, 56, 64, 28, 28, 64);

    const int projBlocks = ((N + 15) / 16 + 3) / 4;  // 1563

    // Layer 0: K=128, cols 176 (split 96+80): p stride 88 bf16, acc stride 88 f32
    projm_kernel<128, 128, 0, 6, 85, 85, 88, 88><<<projBlocks, 256, 0, stream>>>(
        xb, Wc0, bl[0], pB, accB, N);
    projm_kernel<128, 128, 96, 5, 85, 85, 88, 88><<<projBlocks, 256, 0, stream>>>(
        xb, Wc0, bl[0], pB, accB, N);
    gatherb_kernel<85, 88, 88, 96, 96><<<(N + 3) / 4, 256, 0, stream>>>(
        rowptr, csr, pB, accB, xp, N);

    // Layer 1: K=96 (85 zero-padded), cols 112
    projm_kernel<96, 96, 0, 7, 56, 56, 56, 56><<<projBlocks, 256, 0, stream>>>(
        xp, Wc1, bl[1], pB, accB, N);
    gatherb_kernel<56, 56, 56, 64, 64><<<(N + 3) / 4, 256, 0, stream>>>(
        rowptr, csr, pB, accB, x2, N);

    // Layer 2: K=64 (56 zero-padded), cols 64
    projm_kernel<64, 64, 0, 4, 28, 28, 28, 28><<<projBlocks, 256, 0, stream>>>(
        x2, Wc2, bl[2], pB, accB, N);
    gatherb_kernel<28, 28, 28, 32, 32><<<(N + 3) / 4, 256, 0, stream>>>(
        rowptr, csr, pB, accB, x3, N);

    // Layer 3: 28 -> 1 (fp32 VALU)
    gemv3_kernel<<<(N + 255) / 256, 256, 0, stream>>>(
        x3, Wl[3], bl[3], Wr[3], p3, (float*)d_out, N);
    gather1_kernel<<<(N + 255) / 256, 256, 0, stream>>>(
        rowptr, csr, p3, (float*)d_out, N);
}

// Round 7
// 305.543 us; speedup vs baseline: 39.9341x; 1.0516x over previous
//
#include <hip/hip_runtime.h>

// ---------------------------------------------------------------------------
// SageCox: 4-layer GraphSAGE (mean aggr), N=100000, E=640000.
// out = mean_neigh(x)@Wl + bl + x@Wr per layer.
// Restructured: p = x@Wl ; acc = bf16(x@Wr + bl) ; x_next = bf16(acc + invdeg*sum p[src]).
// proj = MFMA bf16 (16x16x32, f32 accum), B register-resident from WcT[col][K].
// Layer-0 proj reads fp32 x directly (inline bf16 convert). p/acc rows padded
// to 96/64/32 elements so random gather reads touch whole 128B lines.
// Layer-3 GEMV fused into layer-2 gather (wave shfl_xor reduce).
// ---------------------------------------------------------------------------

#define NNODES 100000
#define NEDGES 640000

using bf16x8 = __attribute__((ext_vector_type(8))) short;
using f32x4  = __attribute__((ext_vector_type(4))) float;

__device__ __forceinline__ unsigned short f2bf(float f) {
    union { float f; unsigned u; } v; v.f = f;
    unsigned r = v.u + 0x7fffu + ((v.u >> 16) & 1u);
    return (unsigned short)(r >> 16);
}
__device__ __forceinline__ float bf2f(unsigned short b) {
    union { unsigned u; float f; } v; v.u = ((unsigned)b) << 16;
    return v.f;
}

// ---- CSR build ------------------------------------------------------------

__global__ void hist_kernel(const int* __restrict__ edst, int* __restrict__ deg, int E) {
    int i = blockIdx.x * blockDim.x + threadIdx.x;
    if (i < E) atomicAdd(&deg[edst[i]], 1);
}

__global__ void scanA_kernel(const int* __restrict__ deg, int* __restrict__ bsum, int N) {
    __shared__ int s[256];
    int i = blockIdx.x * 256 + threadIdx.x;
    s[threadIdx.x] = (i < N) ? deg[i] : 0;
    __syncthreads();
    for (int off = 128; off > 0; off >>= 1) {
        if (threadIdx.x < off) s[threadIdx.x] += s[threadIdx.x + off];
        __syncthreads();
    }
    if (threadIdx.x == 0) bsum[blockIdx.x] = s[0];
}

__global__ void scanB_kernel(const int* __restrict__ bsum, int* __restrict__ bpre, int nb) {
    __shared__ int s[512];
    int t = threadIdx.x;
    int v = (t < nb) ? bsum[t] : 0;
    s[t] = v;
    __syncthreads();
    for (int off = 1; off < 512; off <<= 1) {
        int add = (t >= off) ? s[t - off] : 0;
        __syncthreads();
        s[t] += add;
        __syncthreads();
    }
    if (t < nb) bpre[t] = s[t] - v;  // exclusive
}

__global__ void scanC_kernel(const int* __restrict__ deg, const int* __restrict__ bpre,
                             int* __restrict__ rowptr, int* __restrict__ cursor, int N, int E) {
    __shared__ int s[256];
    int t = threadIdx.x;
    int i = blockIdx.x * 256 + t;
    int v = (i < N) ? deg[i] : 0;
    s[t] = v;
    __syncthreads();
    for (int off = 1; off < 256; off <<= 1) {
        int add = (t >= off) ? s[t - off] : 0;
        __syncthreads();
        s[t] += add;
        __syncthreads();
    }
    if (i < N) {
        int excl = bpre[blockIdx.x] + s[t] - v;
        rowptr[i] = excl;
        cursor[i] = excl;
        if (i == N - 1) rowptr[N] = E;
    }
}

__global__ void fill_kernel(const int* __restrict__ esrc, const int* __restrict__ edst,
                            int* __restrict__ cursor, int* __restrict__ csr, int E) {
    int i = blockIdx.x * blockDim.x + threadIdx.x;
    if (i < E) {
        int pos = atomicAdd(&cursor[edst[i]], 1);
        csr[pos] = esrc[i];
    }
}

// ---- merged weight pack: WcT[c][k] bf16 for all 3 MFMA layers ------------

__device__ __forceinline__ void packT_one(const float* Wl, const float* Wr,
                                          unsigned short* WcT, int idx, int DIN,
                                          int KP, int DOUT, int DOUTP) {
    int c = idx / KP, k = idx - c * KP;
    float v = 0.0f;
    if (k < DIN) {
        if (c < DOUT) v = Wl[k * DOUT + c];
        else if (c >= DOUTP && c < DOUTP + DOUT) v = Wr[k * DOUT + (c - DOUTP)];
    }
    WcT[idx] = f2bf(v);
}

__global__ void packAll_kernel(const float* __restrict__ Wl0, const float* __restrict__ Wr0,
                               const float* __restrict__ Wl1, const float* __restrict__ Wr1,
                               const float* __restrict__ Wl2, const float* __restrict__ Wr2,
                               unsigned short* __restrict__ Wc0,
                               unsigned short* __restrict__ Wc1,
                               unsigned short* __restrict__ Wc2) {
    const int S0 = 176 * 128, S1 = 112 * 96, S2 = 64 * 64;
    int idx = blockIdx.x * blockDim.x + threadIdx.x;
    if (idx < S0) packT_one(Wl0, Wr0, Wc0, idx, 128, 128, 85, 85);
    else if (idx < S0 + S1) packT_one(Wl1, Wr1, Wc1, idx - S0, 85, 96, 56, 56);
    else if (idx < S0 + S1 + S2) packT_one(Wl2, Wr2, Wc2, idx - S0 - S1, 56, 64, 28, 28);
}

// ---- MFMA projection ------------------------------------------------------
// block = 4 waves, each wave one 16-row tile; B frags register-resident.
// D layout: row = row0+(lane>>4)*4+j, col = CB+nt*16+(lane&15).

template <bool XFP32, int KP, int SIN, int CB, int NT, int DOUT, int DOUTP, int SPP, int SACC>
__global__ void __launch_bounds__(256)
projm_kernel(const void* __restrict__ xin,
             const unsigned short* __restrict__ WcT,
             const float* __restrict__ bl,
             unsigned short* __restrict__ p,
             unsigned short* __restrict__ acc_out, int N) {
    constexpr int KT = KP / 32;
    const int lane = threadIdx.x & 63;
    const int wave = threadIdx.x >> 6;
    const int l15 = lane & 15;
    const int lk  = lane >> 4;

    bf16x8 bfrag[KT][NT];
#pragma unroll
    for (int nt = 0; nt < NT; ++nt) {
        const unsigned short* wp = WcT + (size_t)(CB + nt * 16 + l15) * KP + lk * 8;
#pragma unroll
        for (int kt = 0; kt < KT; ++kt)
            bfrag[kt][nt] = *(const bf16x8*)(wp + kt * 32);
    }

    const int row0 = (blockIdx.x * 4 + wave) * 16;
    int arow = row0 + l15;
    if (arow >= N) arow = N - 1;              // clamp; stores skipped later
    bf16x8 afrag[KT];
    if constexpr (XFP32) {
        const float* xr = (const float*)xin + (size_t)arow * SIN + lk * 8;
#pragma unroll
        for (int kt = 0; kt < KT; ++kt) {
            const float4 a = *(const float4*)(xr + kt * 32);
            const float4 b = *(const float4*)(xr + kt * 32 + 4);
            bf16x8 v;
            v[0] = (short)f2bf(a.x); v[1] = (short)f2bf(a.y);
            v[2] = (short)f2bf(a.z); v[3] = (short)f2bf(a.w);
            v[4] = (short)f2bf(b.x); v[5] = (short)f2bf(b.y);
            v[6] = (short)f2bf(b.z); v[7] = (short)f2bf(b.w);
            afrag[kt] = v;
        }
    } else {
        const unsigned short* xr = (const unsigned short*)xin + (size_t)arow * SIN + lk * 8;
#pragma unroll
        for (int kt = 0; kt < KT; ++kt)
            afrag[kt] = *(const bf16x8*)(xr + kt * 32);
    }

    f32x4 acc[NT];
#pragma unroll
    for (int nt = 0; nt < NT; ++nt) {
        f32x4 a = {0.f, 0.f, 0.f, 0.f};
#pragma unroll
        for (int kt = 0; kt < KT; ++kt)
            a = __builtin_amdgcn_mfma_f32_16x16x32_bf16(afrag[kt], bfrag[kt][nt], a, 0, 0, 0);
        acc[nt] = a;
    }

    const int rbase = row0 + lk * 4;
#pragma unroll
    for (int nt = 0; nt < NT; ++nt) {
        const int col = CB + nt * 16 + l15;
#pragma unroll
        for (int j = 0; j < 4; ++j) {
            const int row = rbase + j;
            if (row >= N) continue;
            const float v = acc[nt][j];
            if (col < DOUT) {
                p[(size_t)row * SPP + col] = f2bf(v);
            } else if (col >= DOUTP && col < DOUTP + DOUT) {
                const int co = col - DOUTP;
                acc_out[(size_t)row * SACC + co] = f2bf(v + bl[co]);
            }
        }
    }
}

// ---- gather: x_next = bf16(acc + invdeg * sum p[src]), zero-pad to PADN ---

template <int DOUT, int SP, int SA, int SN, int PADN>
__global__ void __launch_bounds__(256)
gatherb_kernel(const int* __restrict__ rowptr, const int* __restrict__ csr,
               const unsigned short* __restrict__ p, const unsigned short* __restrict__ acc,
               unsigned short* __restrict__ xnext, int N) {
    const int node = __builtin_amdgcn_readfirstlane((blockIdx.x * 256 + threadIdx.x) >> 6);
    const int lane = threadIdx.x & 63;
    if (node >= N) return;
    const int beg = rowptr[node], end = rowptr[node + 1];
    const float inv = 1.0f / (float)max(end - beg, 1);
    float a0 = 0.f, a1 = 0.f, b0 = 0.f, b1 = 0.f;
    int j = beg;
    for (; j + 2 <= end; j += 2) {
        const unsigned short* p0 = p + (size_t)csr[j] * SP;
        const unsigned short* p1 = p + (size_t)csr[j + 1] * SP;
        if (lane < DOUT) { a0 += bf2f(p0[lane]); a1 += bf2f(p1[lane]); }
        if (DOUT > 64 && lane + 64 < DOUT) { b0 += bf2f(p0[lane + 64]); b1 += bf2f(p1[lane + 64]); }
    }
    if (j < end) {
        const unsigned short* p0 = p + (size_t)csr[j] * SP;
        if (lane < DOUT) a0 += bf2f(p0[lane]);
        if (DOUT > 64 && lane + 64 < DOUT) b0 += bf2f(p0[lane + 64]);
    }
    if (lane < DOUT)
        xnext[(size_t)node * SN + lane] = f2bf(bf2f(acc[(size_t)node * SA + lane]) + inv * (a0 + a1));
    else if (lane < PADN)
        xnext[(size_t)node * SN + lane] = 0;
    if (DOUT > 64) {
        const int c2 = lane + 64;
        if (c2 < DOUT)
            xnext[(size_t)node * SN + c2] = f2bf(bf2f(acc[(size_t)node * SA + c2]) + inv * (b0 + b1));
        else if (c2 < PADN)
            xnext[(size_t)node * SN + c2] = 0;
    }
}

// ---- layer-2 gather fused with layer-3 GEMV (28 -> 1) ---------------------
// xv[lane<28] = acc + inv*sum p[src]; sl = sum xv*Wl3, sr = sum xv*Wr3 via
// wave shfl_xor reduce; lane 0 writes p3[node] = sl, out[node] = sr + bl3.

__global__ void __launch_bounds__(256)
gather2g_kernel(const int* __restrict__ rowptr, const int* __restrict__ csr,
                const unsigned short* __restrict__ p, const unsigned short* __restrict__ acc,
                const float* __restrict__ Wl3, const float* __restrict__ bl3,
                const float* __restrict__ Wr3,
                float* __restrict__ p3, float* __restrict__ out, int N) {
    const int node = __builtin_amdgcn_readfirstlane((blockIdx.x * 256 + threadIdx.x) >> 6);
    const int lane = threadIdx.x & 63;
    if (node >= N) return;
    const int beg = rowptr[node], end = rowptr[node + 1];
    const float inv = 1.0f / (float)max(end - beg, 1);
    float a0 = 0.f, a1 = 0.f;
    int j = beg;
    for (; j + 2 <= end; j += 2) {
        const unsigned short* p0 = p + (size_t)csr[j] * 32;
        const unsigned short* p1 = p + (size_t)csr[j + 1] * 32;
        if (lane < 28) { a0 += bf2f(p0[lane]); a1 += bf2f(p1[lane]); }
    }
    if (j < end) {
        const unsigned short* p0 = p + (size_t)csr[j] * 32;
        if (lane < 28) a0 += bf2f(p0[lane]);
    }
    float xv = 0.f, wl = 0.f, wr = 0.f;
    if (lane < 28) {
        xv = bf2f(acc[(size_t)node * 32 + lane]) + inv * (a0 + a1);
        wl = Wl3[lane];
        wr = Wr3[lane];
    }
    float sl = xv * wl, sr = xv * wr;
#pragma unroll
    for (int off = 32; off > 0; off >>= 1) {
        sl += __shfl_xor(sl, off, 64);
        sr += __shfl_xor(sr, off, 64);
    }
    if (lane == 0) {
        p3[node] = sl;
        out[node] = sr + bl3[0];
    }
}

__global__ void gather1_kernel(const int* __restrict__ rowptr, const int* __restrict__ csr,
                               const float* __restrict__ p, float* __restrict__ out, int N) {
    const int node = blockIdx.x * blockDim.x + threadIdx.x;
    if (node >= N) return;
    const int beg = rowptr[node], end = rowptr[node + 1];
    const float inv = 1.0f / (float)max(end - beg, 1);
    float a0 = 0.f, a1 = 0.f;
    int j = beg;
    for (; j + 2 <= end; j += 2) { a0 += p[csr[j]]; a1 += p[csr[j + 1]]; }
    if (j < end) a0 += p[csr[j]];
    out[node] += inv * (a0 + a1);
}

// ---------------------------------------------------------------------------

extern "C" void kernel_launch(void* const* d_in, const int* in_sizes, int n_in,
                              void* d_out, int out_size, void* d_ws, size_t ws_size,
                              hipStream_t stream) {
    const float* x  = (const float*)d_in[0];
    const int*   ei = (const int*)d_in[1];
    const int N = NNODES;
    const int E = NEDGES;
    const int* esrc = ei;
    const int* edst = ei + E;

    const float* Wl[4] = {(const float*)d_in[2], (const float*)d_in[5],
                          (const float*)d_in[8], (const float*)d_in[11]};
    const float* bl[4] = {(const float*)d_in[3], (const float*)d_in[6],
                          (const float*)d_in[9], (const float*)d_in[12]};
    const float* Wr[4] = {(const float*)d_in[4], (const float*)d_in[7],
                          (const float*)d_in[10], (const float*)d_in[13]};

    // ---- workspace arena (byte offsets, 256B aligned) ----
    char* base = (char*)d_ws;
    size_t off = 0;
    auto alloc = [&](size_t bytes) {
        char* r = base + off;
        off += (bytes + 255) & ~(size_t)255;
        return r;
    };
    unsigned short* pB   = (unsigned short*)alloc((size_t)N * 96 * 2);  // p bf16, stride 96/64/32
    unsigned short* accB = (unsigned short*)alloc((size_t)N * 96 * 2);  // acc bf16, stride 96/64/32
    unsigned short* xp   = (unsigned short*)alloc((size_t)N * 96 * 2);  // x1 (stride 96); reused as x2 (stride 64)
    float*          p3   = (float*)alloc((size_t)N * 4);
    unsigned short* Wc0  = (unsigned short*)alloc((size_t)176 * 128 * 2);
    unsigned short* Wc1  = (unsigned short*)alloc((size_t)112 * 96 * 2);
    unsigned short* Wc2  = (unsigned short*)alloc((size_t)64 * 64 * 2);
    int* degi   = (int*)alloc((size_t)N * 4);
    int* rowptr = (int*)alloc((size_t)(N + 1) * 4);
    int* cursor = (int*)alloc((size_t)N * 4);
    int* csr    = (int*)alloc((size_t)E * 4);
    int* bsum   = (int*)alloc(512 * 4);
    int* bpre   = (int*)alloc(512 * 4);

    unsigned short* x2 = xp;   // x1 dead after L1 proj; reuse region for x2

    const int nb = (N + 255) / 256;  // 391

    // CSR build
    hipMemsetAsync(degi, 0, (size_t)N * sizeof(int), stream);
    hist_kernel<<<(E + 255) / 256, 256, 0, stream>>>(edst, degi, E);
    scanA_kernel<<<nb, 256, 0, stream>>>(degi, bsum, N);
    scanB_kernel<<<1, 512, 0, stream>>>(bsum, bpre, nb);
    scanC_kernel<<<nb, 256, 0, stream>>>(degi, bpre, rowptr, cursor, N, E);
    fill_kernel<<<(E + 255) / 256, 256, 0, stream>>>(esrc, edst, cursor, csr, E);

    // weight packs (transposed, bf16, zero-padded), one dispatch
    const int packTot = 176 * 128 + 112 * 96 + 64 * 64;
    packAll_kernel<<<(packTot + 255) / 256, 256, 0, stream>>>(
        Wl[0], Wr[0], Wl[1], Wr[1], Wl[2], Wr[2], Wc0, Wc1, Wc2);

    const int projBlocks = ((N + 15) / 16 + 3) / 4;  // 1563

    // Layer 0: K=128 fp32 input, cols 176 split 96+80; p/acc stride 96
    projm_kernel<true, 128, 128, 0, 6, 85, 85, 96, 96><<<projBlocks, 256, 0, stream>>>(
        x, Wc0, bl[0], pB, accB, N);
    projm_kernel<true, 128, 128, 96, 5, 85, 85, 96, 96><<<projBlocks, 256, 0, stream>>>(
        x, Wc0, bl[0], pB, accB, N);
    gatherb_kernel<85, 96, 96, 96, 96><<<(N + 3) / 4, 256, 0, stream>>>(
        rowptr, csr, pB, accB, xp, N);

    // Layer 1: K=96 (85 zero-padded), cols 112; p/acc stride 64
    projm_kernel<false, 96, 96, 0, 7, 56, 56, 64, 64><<<projBlocks, 256, 0, stream>>>(
        xp, Wc1, bl[1], pB, accB, N);
    gatherb_kernel<56, 64, 64, 64, 64><<<(N + 3) / 4, 256, 0, stream>>>(
        rowptr, csr, pB, accB, x2, N);

    // Layer 2: K=64 (56 zero-padded), cols 64; p/acc stride 32
    projm_kernel<false, 64, 64, 0, 4, 28, 28, 32, 32><<<projBlocks, 256, 0, stream>>>(
        x2, Wc2, bl[2], pB, accB, N);

    // Layer-2 gather + layer-3 GEMV fused; then scalar gather for layer 3
    gather2g_kernel<<<(N + 3) / 4, 256, 0, stream>>>(
        rowptr, csr, pB, accB, Wl[3], bl[3], Wr[3], p3, (float*)d_out, N);
    gather1_kernel<<<(N + 255) / 256, 256, 0, stream>>>(
        rowptr, csr, p3, (float*)d_out, N);
}

// Round 8
// 279.276 us; speedup vs baseline: 43.6901x; 1.0941x over previous
//
#include <hip/hip_runtime.h>

// ---------------------------------------------------------------------------
// SageCox: 4-layer GraphSAGE (mean aggr), N=100000, E=640000.
// out = mean_neigh(x)@Wl + bl + x@Wr per layer.
// Restructured: p = x@Wl ; acc = bf16(x@Wr + bl) ; x_next = bf16(acc + invdeg*sum p[src]).
// proj = MFMA bf16 (16x16x32, f32 accum), loop over 16-col tiles with B frags
// loaded per tile (low VGPR, x read once). L0 reads fp32 x inline-converted.
// Gather: CSR, node-per-wave, paired-uint column loads, 4-edge unroll.
// p/acc/xnext rows padded to 96/64/32 elems (whole 128B lines).
// Layer-3 GEMV fused into layer-2 gather (wave shfl_xor reduce).
// ---------------------------------------------------------------------------

#define NNODES 100000
#define NEDGES 640000

using bf16x8 = __attribute__((ext_vector_type(8))) short;
using f32x4  = __attribute__((ext_vector_type(4))) float;

__device__ __forceinline__ unsigned short f2bf(float f) {
    union { float f; unsigned u; } v; v.f = f;
    unsigned r = v.u + 0x7fffu + ((v.u >> 16) & 1u);
    return (unsigned short)(r >> 16);
}
__device__ __forceinline__ float bf2f(unsigned b) {
    union { unsigned u; float f; } v; v.u = b << 16;
    return v.f;
}

// ---- CSR build ------------------------------------------------------------

__global__ void hist_kernel(const int* __restrict__ edst, int* __restrict__ deg, int E) {
    int i = blockIdx.x * blockDim.x + threadIdx.x;
    if (i < E) atomicAdd(&deg[edst[i]], 1);
}

__global__ void scanA_kernel(const int* __restrict__ deg, int* __restrict__ bsum, int N) {
    __shared__ int s[256];
    int i = blockIdx.x * 256 + threadIdx.x;
    s[threadIdx.x] = (i < N) ? deg[i] : 0;
    __syncthreads();
    for (int off = 128; off > 0; off >>= 1) {
        if (threadIdx.x < off) s[threadIdx.x] += s[threadIdx.x + off];
        __syncthreads();
    }
    if (threadIdx.x == 0) bsum[blockIdx.x] = s[0];
}

__global__ void scanB_kernel(const int* __restrict__ bsum, int* __restrict__ bpre, int nb) {
    __shared__ int s[512];
    int t = threadIdx.x;
    int v = (t < nb) ? bsum[t] : 0;
    s[t] = v;
    __syncthreads();
    for (int off = 1; off < 512; off <<= 1) {
        int add = (t >= off) ? s[t - off] : 0;
        __syncthreads();
        s[t] += add;
        __syncthreads();
    }
    if (t < nb) bpre[t] = s[t] - v;  // exclusive
}

__global__ void scanC_kernel(const int* __restrict__ deg, const int* __restrict__ bpre,
                             int* __restrict__ rowptr, int* __restrict__ cursor, int N, int E) {
    __shared__ int s[256];
    int t = threadIdx.x;
    int i = blockIdx.x * 256 + t;
    int v = (i < N) ? deg[i] : 0;
    s[t] = v;
    __syncthreads();
    for (int off = 1; off < 256; off <<= 1) {
        int add = (t >= off) ? s[t - off] : 0;
        __syncthreads();
        s[t] += add;
        __syncthreads();
    }
    if (i < N) {
        int excl = bpre[blockIdx.x] + s[t] - v;
        rowptr[i] = excl;
        cursor[i] = excl;
        if (i == N - 1) rowptr[N] = E;
    }
}

__global__ void fill_kernel(const int* __restrict__ esrc, const int* __restrict__ edst,
                            int* __restrict__ cursor, int* __restrict__ csr, int E) {
    int i = blockIdx.x * blockDim.x + threadIdx.x;
    if (i < E) {
        int pos = atomicAdd(&cursor[edst[i]], 1);
        csr[pos] = esrc[i];
    }
}

// ---- merged weight pack: WcT[c][k] bf16 for all 3 MFMA layers -------------

__device__ __forceinline__ void packT_one(const float* Wl, const float* Wr,
                                          unsigned short* WcT, int idx, int DIN,
                                          int KP, int DOUT, int DOUTP) {
    int c = idx / KP, k = idx - c * KP;
    float v = 0.0f;
    if (k < DIN) {
        if (c < DOUT) v = Wl[k * DOUT + c];
        else if (c >= DOUTP && c < DOUTP + DOUT) v = Wr[k * DOUT + (c - DOUTP)];
    }
    WcT[idx] = f2bf(v);
}

__global__ void packAll_kernel(const float* __restrict__ Wl0, const float* __restrict__ Wr0,
                               const float* __restrict__ Wl1, const float* __restrict__ Wr1,
                               const float* __restrict__ Wl2, const float* __restrict__ Wr2,
                               unsigned short* __restrict__ Wc0,
                               unsigned short* __restrict__ Wc1,
                               unsigned short* __restrict__ Wc2) {
    const int S0 = 176 * 128, S1 = 112 * 96, S2 = 64 * 64;
    int idx = blockIdx.x * blockDim.x + threadIdx.x;
    if (idx < S0) packT_one(Wl0, Wr0, Wc0, idx, 128, 128, 85, 85);
    else if (idx < S0 + S1) packT_one(Wl1, Wr1, Wc1, idx - S0, 85, 96, 56, 56);
    else if (idx < S0 + S1 + S2) packT_one(Wl2, Wr2, Wc2, idx - S0 - S1, 56, 64, 28, 28);
}

// ---- MFMA projection ------------------------------------------------------
// block = 4 waves, each wave one 16-row tile x all NTILES col-tiles.
// B frags loaded per col-tile (registers reused across tiles -> low VGPR).
// D layout: row = row0+(lane>>4)*4+j, col = nt*16+(lane&15).

template <bool XFP32, int KP, int SIN, int NTILES, int DOUT, int DOUTP, int SPP, int SACC>
__global__ void __launch_bounds__(256)
projm_kernel(const void* __restrict__ xin,
             const unsigned short* __restrict__ WcT,
             const float* __restrict__ bl,
             unsigned short* __restrict__ p,
             unsigned short* __restrict__ acc_out, int N) {
    constexpr int KT = KP / 32;
    const int lane = threadIdx.x & 63;
    const int wave = threadIdx.x >> 6;
    const int l15 = lane & 15;
    const int lk  = lane >> 4;

    const int row0 = (blockIdx.x * 4 + wave) * 16;
    int arow = row0 + l15;
    if (arow >= N) arow = N - 1;              // clamp; stores skipped later
    bf16x8 afrag[KT];
    if constexpr (XFP32) {
        const float* xr = (const float*)xin + (size_t)arow * SIN + lk * 8;
#pragma unroll
        for (int kt = 0; kt < KT; ++kt) {
            const float4 a = *(const float4*)(xr + kt * 32);
            const float4 b = *(const float4*)(xr + kt * 32 + 4);
            bf16x8 v;
            v[0] = (short)f2bf(a.x); v[1] = (short)f2bf(a.y);
            v[2] = (short)f2bf(a.z); v[3] = (short)f2bf(a.w);
            v[4] = (short)f2bf(b.x); v[5] = (short)f2bf(b.y);
            v[6] = (short)f2bf(b.z); v[7] = (short)f2bf(b.w);
            afrag[kt] = v;
        }
    } else {
        const unsigned short* xr = (const unsigned short*)xin + (size_t)arow * SIN + lk * 8;
#pragma unroll
        for (int kt = 0; kt < KT; ++kt)
            afrag[kt] = *(const bf16x8*)(xr + kt * 32);
    }

    const int rbase = row0 + lk * 4;

#pragma unroll 2
    for (int nt = 0; nt < NTILES; ++nt) {
        const unsigned short* wp = WcT + (size_t)(nt * 16 + l15) * KP + lk * 8;
        bf16x8 bfrag[KT];
#pragma unroll
        for (int kt = 0; kt < KT; ++kt)
            bfrag[kt] = *(const bf16x8*)(wp + kt * 32);

        f32x4 a = {0.f, 0.f, 0.f, 0.f};
#pragma unroll
        for (int kt = 0; kt < KT; ++kt)
            a = __builtin_amdgcn_mfma_f32_16x16x32_bf16(afrag[kt], bfrag[kt], a, 0, 0, 0);

        const int col = nt * 16 + l15;
#pragma unroll
        for (int j = 0; j < 4; ++j) {
            const int row = rbase + j;
            if (row >= N) continue;
            const float v = a[j];
            if (col < DOUT) {
                p[(size_t)row * SPP + col] = f2bf(v);
            } else if (col >= DOUTP && col < DOUTP + DOUT) {
                const int co = col - DOUTP;
                acc_out[(size_t)row * SACC + co] = f2bf(v + bl[co]);
            }
        }
    }
}

// ---- gather: x_next = bf16(acc + invdeg * sum p[src]) ---------------------
// Paired-uint column loads (2 bf16/lane/edge), 4-edge unroll. Pad cols of
// xnext written 0 (they multiply zero-padded W rows in next proj anyway).

template <int DOUT, int SP, int SN>
__global__ void __launch_bounds__(256)
gatherb_kernel(const int* __restrict__ rowptr, const int* __restrict__ csr,
               const unsigned short* __restrict__ p, const unsigned short* __restrict__ acc,
               unsigned short* __restrict__ xnext, int N) {
    const int node = __builtin_amdgcn_readfirstlane((blockIdx.x * 256 + threadIdx.x) >> 6);
    const int lane = threadIdx.x & 63;
    if (node >= N) return;
    const int beg = rowptr[node], end = rowptr[node + 1];
    const float inv = 1.0f / (float)max(end - beg, 1);
    constexpr int NPAIR = (DOUT + 1) / 2;
    const int co = 2 * lane;

    float s0 = 0.f, s1 = 0.f, s2 = 0.f, s3 = 0.f;
    float h0 = 0.f, h1 = 0.f, h2 = 0.f, h3 = 0.f;
    if (lane < NPAIR) {
        int j = beg;
        for (; j + 4 <= end; j += 4) {
            const unsigned u0 = *(const unsigned*)(p + (size_t)csr[j]     * SP + co);
            const unsigned u1 = *(const unsigned*)(p + (size_t)csr[j + 1] * SP + co);
            const unsigned u2 = *(const unsigned*)(p + (size_t)csr[j + 2] * SP + co);
            const unsigned u3 = *(const unsigned*)(p + (size_t)csr[j + 3] * SP + co);
            s0 += bf2f(u0 & 0xffffu); h0 += bf2f(u0 >> 16);
            s1 += bf2f(u1 & 0xffffu); h1 += bf2f(u1 >> 16);
            s2 += bf2f(u2 & 0xffffu); h2 += bf2f(u2 >> 16);
            s3 += bf2f(u3 & 0xffffu); h3 += bf2f(u3 >> 16);
        }
        for (; j < end; ++j) {
            const unsigned u0 = *(const unsigned*)(p + (size_t)csr[j] * SP + co);
            s0 += bf2f(u0 & 0xffffu); h0 += bf2f(u0 >> 16);
        }
    }
    if (co < SN) {
        const float slo = (s0 + s1) + (s2 + s3);
        const float shi = (h0 + h1) + (h2 + h3);
        float lo = 0.f, hi = 0.f;
        if (co < DOUT)     lo = bf2f((unsigned)acc[(size_t)node * SP + co])     + inv * slo;
        if (co + 1 < DOUT) hi = bf2f((unsigned)acc[(size_t)node * SP + co + 1]) + inv * shi;
        const unsigned w = (unsigned)f2bf(lo) | ((unsigned)f2bf(hi) << 16);
        *(unsigned*)(xnext + (size_t)node * SN + co) = w;
    }
}

// ---- layer-2 gather fused with layer-3 GEMV (28 -> 1) ---------------------

__global__ void __launch_bounds__(256)
gather2g_kernel(const int* __restrict__ rowptr, const int* __restrict__ csr,
                const unsigned short* __restrict__ p, const unsigned short* __restrict__ acc,
                const float* __restrict__ Wl3, const float* __restrict__ bl3,
                const float* __restrict__ Wr3,
                float* __restrict__ p3, float* __restrict__ out, int N) {
    const int node = __builtin_amdgcn_readfirstlane((blockIdx.x * 256 + threadIdx.x) >> 6);
    const int lane = threadIdx.x & 63;
    if (node >= N) return;
    const int beg = rowptr[node], end = rowptr[node + 1];
    const float inv = 1.0f / (float)max(end - beg, 1);
    const int co = 2 * lane;

    float s0 = 0.f, s1 = 0.f, s2 = 0.f, s3 = 0.f;
    float h0 = 0.f, h1 = 0.f, h2 = 0.f, h3 = 0.f;
    if (lane < 14) {
        int j = beg;
        for (; j + 4 <= end; j += 4) {
            const unsigned u0 = *(const unsigned*)(p + (size_t)csr[j]     * 32 + co);
            const unsigned u1 = *(const unsigned*)(p + (size_t)csr[j + 1] * 32 + co);
            const unsigned u2 = *(const unsigned*)(p + (size_t)csr[j + 2] * 32 + co);
            const unsigned u3 = *(const unsigned*)(p + (size_t)csr[j + 3] * 32 + co);
            s0 += bf2f(u0 & 0xffffu); h0 += bf2f(u0 >> 16);
            s1 += bf2f(u1 & 0xffffu); h1 += bf2f(u1 >> 16);
            s2 += bf2f(u2 & 0xffffu); h2 += bf2f(u2 >> 16);
            s3 += bf2f(u3 & 0xffffu); h3 += bf2f(u3 >> 16);
        }
        for (; j < end; ++j) {
            const unsigned u0 = *(const unsigned*)(p + (size_t)csr[j] * 32 + co);
            s0 += bf2f(u0 & 0xffffu); h0 += bf2f(u0 >> 16);
        }
    }
    float xlo = 0.f, xhi = 0.f, wl0 = 0.f, wl1 = 0.f, wr0 = 0.f, wr1 = 0.f;
    if (lane < 14) {
        xlo = bf2f((unsigned)acc[(size_t)node * 32 + co])     + inv * ((s0 + s1) + (s2 + s3));
        xhi = bf2f((unsigned)acc[(size_t)node * 32 + co + 1]) + inv * ((h0 + h1) + (h2 + h3));
        wl0 = Wl3[co]; wl1 = Wl3[co + 1];
        wr0 = Wr3[co]; wr1 = Wr3[co + 1];
    }
    float sl = xlo * wl0 + xhi * wl1;
    float sr = xlo * wr0 + xhi * wr1;
#pragma unroll
    for (int off = 32; off > 0; off >>= 1) {
        sl += __shfl_xor(sl, off, 64);
        sr += __shfl_xor(sr, off, 64);
    }
    if (lane == 0) {
        p3[node] = sl;
        out[node] = sr + bl3[0];
    }
}

__global__ void gather1_kernel(const int* __restrict__ rowptr, const int* __restrict__ csr,
                               const float* __restrict__ p, float* __restrict__ out, int N) {
    const int node = blockIdx.x * blockDim.x + threadIdx.x;
    if (node >= N) return;
    const int beg = rowptr[node], end = rowptr[node + 1];
    const float inv = 1.0f / (float)max(end - beg, 1);
    float a0 = 0.f, a1 = 0.f, a2 = 0.f, a3 = 0.f;
    int j = beg;
    for (; j + 4 <= end; j += 4) {
        a0 += p[csr[j]]; a1 += p[csr[j + 1]]; a2 += p[csr[j + 2]]; a3 += p[csr[j + 3]];
    }
    for (; j < end; ++j) a0 += p[csr[j]];
    out[node] += inv * ((a0 + a1) + (a2 + a3));
}

// ---------------------------------------------------------------------------

extern "C" void kernel_launch(void* const* d_in, const int* in_sizes, int n_in,
                              void* d_out, int out_size, void* d_ws, size_t ws_size,
                              hipStream_t stream) {
    const float* x  = (const float*)d_in[0];
    const int*   ei = (const int*)d_in[1];
    const int N = NNODES;
    const int E = NEDGES;
    const int* esrc = ei;
    const int* edst = ei + E;

    const float* Wl[4] = {(const float*)d_in[2], (const float*)d_in[5],
                          (const float*)d_in[8], (const float*)d_in[11]};
    const float* bl[4] = {(const float*)d_in[3], (const float*)d_in[6],
                          (const float*)d_in[9], (const float*)d_in[12]};
    const float* Wr[4] = {(const float*)d_in[4], (const float*)d_in[7],
                          (const float*)d_in[10], (const float*)d_in[13]};

    // ---- workspace arena (byte offsets, 256B aligned) ----
    char* base = (char*)d_ws;
    size_t off = 0;
    auto alloc = [&](size_t bytes) {
        char* r = base + off;
        off += (bytes + 255) & ~(size_t)255;
        return r;
    };
    unsigned short* pB   = (unsigned short*)alloc((size_t)N * 96 * 2);  // p bf16, stride 96/64/32
    unsigned short* accB = (unsigned short*)alloc((size_t)N * 96 * 2);  // acc bf16, stride 96/64/32
    unsigned short* xp   = (unsigned short*)alloc((size_t)N * 96 * 2);  // x1 (stride 96); reused as x2 (stride 64)
    float*          p3   = (float*)alloc((size_t)N * 4);
    unsigned short* Wc0  = (unsigned short*)alloc((size_t)176 * 128 * 2);
    unsigned short* Wc1  = (unsigned short*)alloc((size_t)112 * 96 * 2);
    unsigned short* Wc2  = (unsigned short*)alloc((size_t)64 * 64 * 2);
    int* degi   = (int*)alloc((size_t)N * 4);
    int* rowptr = (int*)alloc((size_t)(N + 1) * 4);
    int* cursor = (int*)alloc((size_t)N * 4);
    int* csr    = (int*)alloc((size_t)E * 4);
    int* bsum   = (int*)alloc(512 * 4);
    int* bpre   = (int*)alloc(512 * 4);

    unsigned short* x2 = xp;   // x1 dead after L1 proj; reuse region for x2

    const int nb = (N + 255) / 256;  // 391

    // CSR build
    hipMemsetAsync(degi, 0, (size_t)N * sizeof(int), stream);
    hist_kernel<<<(E + 255) / 256, 256, 0, stream>>>(edst, degi, E);
    scanA_kernel<<<nb, 256, 0, stream>>>(degi, bsum, N);
    scanB_kernel<<<1, 512, 0, stream>>>(bsum, bpre, nb);
    scanC_kernel<<<nb, 256, 0, stream>>>(degi, bpre, rowptr, cursor, N, E);
    fill_kernel<<<(E + 255) / 256, 256, 0, stream>>>(esrc, edst, cursor, csr, E);

    // weight packs (transposed, bf16, zero-padded), one dispatch
    const int packTot = 176 * 128 + 112 * 96 + 64 * 64;
    packAll_kernel<<<(packTot + 255) / 256, 256, 0, stream>>>(
        Wl[0], Wr[0], Wl[1], Wr[1], Wl[2], Wr[2], Wc0, Wc1, Wc2);

    const int projBlocks = ((N + 15) / 16 + 3) / 4;  // 1563

    // Layer 0: K=128 fp32 input, all 11 col-tiles in one dispatch
    projm_kernel<true, 128, 128, 11, 85, 85, 96, 96><<<projBlocks, 256, 0, stream>>>(
        x, Wc0, bl[0], pB, accB, N);
    gatherb_kernel<85, 96, 96><<<(N + 3) / 4, 256, 0, stream>>>(
        rowptr, csr, pB, accB, xp, N);

    // Layer 1: K=96 (85 zero-padded), 7 col-tiles
    projm_kernel<false, 96, 96, 7, 56, 56, 64, 64><<<projBlocks, 256, 0, stream>>>(
        xp, Wc1, bl[1], pB, accB, N);
    gatherb_kernel<56, 64, 64><<<(N + 3) / 4, 256, 0, stream>>>(
        rowptr, csr, pB, accB, x2, N);

    // Layer 2: K=64 (56 zero-padded), 4 col-tiles
    projm_kernel<false, 64, 64, 4, 28, 28, 32, 32><<<projBlocks, 256, 0, stream>>>(
        x2, Wc2, bl[2], pB, accB, N);

    // Layer-2 gather + layer-3 GEMV fused; then scalar gather for layer 3
    gather2g_kernel<<<(N + 3) / 4, 256, 0, stream>>>(
        rowptr, csr, pB, accB, Wl[3], bl[3], Wr[3], p3, (float*)d_out, N);
    gather1_kernel<<<(N + 255) / 256, 256, 0, stream>>>(
        rowptr, csr, p3, (float*)d_out, N);
}

// Round 9
// 268.536 us; speedup vs baseline: 45.4375x; 1.0400x over previous
//
#include <hip/hip_runtime.h>

// ---------------------------------------------------------------------------
// SageCox: 4-layer GraphSAGE (mean aggr), N=100000, E=640000.
// out = mean_neigh(x)@Wl + bl + x@Wr per layer.
// Restructured: p = x@Wl ; acc = bf16(x@Wr + bl) ; x_next = bf16(acc + invdeg*sum p[src]).
// proj = MFMA bf16 (16x16x32, f32 accum); wave owns 32 rows (2 A-frag sets,
// 2 acc per col-tile) and loops over 16-col tiles with B frags loaded per
// tile -> B L2-traffic amortized 2x, 8 MFMA per B-load chain.
// Gather: CSR, node-per-wave, paired-uint column loads, 4-edge unroll.
// p/acc/xnext rows padded to 96/64/32 elems (whole 128B lines).
// Layer-3 GEMV fused into layer-2 gather (wave shfl_xor reduce).
// ---------------------------------------------------------------------------

#define NNODES 100000
#define NEDGES 640000

using bf16x8 = __attribute__((ext_vector_type(8))) short;
using f32x4  = __attribute__((ext_vector_type(4))) float;

__device__ __forceinline__ unsigned short f2bf(float f) {
    union { float f; unsigned u; } v; v.f = f;
    unsigned r = v.u + 0x7fffu + ((v.u >> 16) & 1u);
    return (unsigned short)(r >> 16);
}
__device__ __forceinline__ float bf2f(unsigned b) {
    union { unsigned u; float f; } v; v.u = b << 16;
    return v.f;
}

// ---- CSR build ------------------------------------------------------------

__global__ void hist_kernel(const int* __restrict__ edst, int* __restrict__ deg, int E) {
    int i = blockIdx.x * blockDim.x + threadIdx.x;
    if (i < E) atomicAdd(&deg[edst[i]], 1);
}

__global__ void scanA_kernel(const int* __restrict__ deg, int* __restrict__ bsum, int N) {
    __shared__ int s[256];
    int i = blockIdx.x * 256 + threadIdx.x;
    s[threadIdx.x] = (i < N) ? deg[i] : 0;
    __syncthreads();
    for (int off = 128; off > 0; off >>= 1) {
        if (threadIdx.x < off) s[threadIdx.x] += s[threadIdx.x + off];
        __syncthreads();
    }
    if (threadIdx.x == 0) bsum[blockIdx.x] = s[0];
}

__global__ void scanB_kernel(const int* __restrict__ bsum, int* __restrict__ bpre, int nb) {
    __shared__ int s[512];
    int t = threadIdx.x;
    int v = (t < nb) ? bsum[t] : 0;
    s[t] = v;
    __syncthreads();
    for (int off = 1; off < 512; off <<= 1) {
        int add = (t >= off) ? s[t - off] : 0;
        __syncthreads();
        s[t] += add;
        __syncthreads();
    }
    if (t < nb) bpre[t] = s[t] - v;  // exclusive
}

__global__ void scanC_kernel(const int* __restrict__ deg, const int* __restrict__ bpre,
                             int* __restrict__ rowptr, int* __restrict__ cursor, int N, int E) {
    __shared__ int s[256];
    int t = threadIdx.x;
    int i = blockIdx.x * 256 + t;
    int v = (i < N) ? deg[i] : 0;
    s[t] = v;
    __syncthreads();
    for (int off = 1; off < 256; off <<= 1) {
        int add = (t >= off) ? s[t - off] : 0;
        __syncthreads();
        s[t] += add;
        __syncthreads();
    }
    if (i < N) {
        int excl = bpre[blockIdx.x] + s[t] - v;
        rowptr[i] = excl;
        cursor[i] = excl;
        if (i == N - 1) rowptr[N] = E;
    }
}

__global__ void fill_kernel(const int* __restrict__ esrc, const int* __restrict__ edst,
                            int* __restrict__ cursor, int* __restrict__ csr, int E) {
    int i = blockIdx.x * blockDim.x + threadIdx.x;
    if (i < E) {
        int pos = atomicAdd(&cursor[edst[i]], 1);
        csr[pos] = esrc[i];
    }
}

// ---- merged weight pack: WcT[c][k] bf16 for all 3 MFMA layers -------------

__device__ __forceinline__ void packT_one(const float* Wl, const float* Wr,
                                          unsigned short* WcT, int idx, int DIN,
                                          int KP, int DOUT, int DOUTP) {
    int c = idx / KP, k = idx - c * KP;
    float v = 0.0f;
    if (k < DIN) {
        if (c < DOUT) v = Wl[k * DOUT + c];
        else if (c >= DOUTP && c < DOUTP + DOUT) v = Wr[k * DOUT + (c - DOUTP)];
    }
    WcT[idx] = f2bf(v);
}

__global__ void packAll_kernel(const float* __restrict__ Wl0, const float* __restrict__ Wr0,
                               const float* __restrict__ Wl1, const float* __restrict__ Wr1,
                               const float* __restrict__ Wl2, const float* __restrict__ Wr2,
                               unsigned short* __restrict__ Wc0,
                               unsigned short* __restrict__ Wc1,
                               unsigned short* __restrict__ Wc2) {
    const int S0 = 176 * 128, S1 = 112 * 96, S2 = 64 * 64;
    int idx = blockIdx.x * blockDim.x + threadIdx.x;
    if (idx < S0) packT_one(Wl0, Wr0, Wc0, idx, 128, 128, 85, 85);
    else if (idx < S0 + S1) packT_one(Wl1, Wr1, Wc1, idx - S0, 85, 96, 56, 56);
    else if (idx < S0 + S1 + S2) packT_one(Wl2, Wr2, Wc2, idx - S0 - S1, 56, 64, 28, 28);
}

// ---- MFMA projection ------------------------------------------------------
// block = 4 waves, each wave 32 rows (2 A-frag sets) x all NTILES col-tiles.
// D layout: row = rowbase+(lane>>4)*4+j, col = nt*16+(lane&15).

template <bool XFP32, int KP, int SIN, int NTILES, int DOUT, int DOUTP, int SPP, int SACC>
__global__ void __launch_bounds__(256)
projm_kernel(const void* __restrict__ xin,
             const unsigned short* __restrict__ WcT,
             const float* __restrict__ bl,
             unsigned short* __restrict__ p,
             unsigned short* __restrict__ acc_out, int N) {
    constexpr int KT = KP / 32;
    const int lane = threadIdx.x & 63;
    const int wave = threadIdx.x >> 6;
    const int l15 = lane & 15;
    const int lk  = lane >> 4;

    const int row0 = (blockIdx.x * 4 + wave) * 32;

    bf16x8 afrag[2][KT];
#pragma unroll
    for (int h = 0; h < 2; ++h) {
        int arow = row0 + h * 16 + l15;
        if (arow >= N) arow = N - 1;          // clamp; stores skipped later
        if constexpr (XFP32) {
            const float* xr = (const float*)xin + (size_t)arow * SIN + lk * 8;
#pragma unroll
            for (int kt = 0; kt < KT; ++kt) {
                const float4 a = *(const float4*)(xr + kt * 32);
                const float4 b = *(const float4*)(xr + kt * 32 + 4);
                bf16x8 v;
                v[0] = (short)f2bf(a.x); v[1] = (short)f2bf(a.y);
                v[2] = (short)f2bf(a.z); v[3] = (short)f2bf(a.w);
                v[4] = (short)f2bf(b.x); v[5] = (short)f2bf(b.y);
                v[6] = (short)f2bf(b.z); v[7] = (short)f2bf(b.w);
                afrag[h][kt] = v;
            }
        } else {
            const unsigned short* xr = (const unsigned short*)xin + (size_t)arow * SIN + lk * 8;
#pragma unroll
            for (int kt = 0; kt < KT; ++kt)
                afrag[h][kt] = *(const bf16x8*)(xr + kt * 32);
        }
    }

#pragma unroll 2
    for (int nt = 0; nt < NTILES; ++nt) {
        const unsigned short* wp = WcT + (size_t)(nt * 16 + l15) * KP + lk * 8;
        bf16x8 bfrag[KT];
#pragma unroll
        for (int kt = 0; kt < KT; ++kt)
            bfrag[kt] = *(const bf16x8*)(wp + kt * 32);

        f32x4 a0 = {0.f, 0.f, 0.f, 0.f};
        f32x4 a1 = {0.f, 0.f, 0.f, 0.f};
#pragma unroll
        for (int kt = 0; kt < KT; ++kt) {
            a0 = __builtin_amdgcn_mfma_f32_16x16x32_bf16(afrag[0][kt], bfrag[kt], a0, 0, 0, 0);
            a1 = __builtin_amdgcn_mfma_f32_16x16x32_bf16(afrag[1][kt], bfrag[kt], a1, 0, 0, 0);
        }

        const int col = nt * 16 + l15;
#pragma unroll
        for (int h = 0; h < 2; ++h) {
            const f32x4 a = h ? a1 : a0;
            const int rbase = row0 + h * 16 + lk * 4;
#pragma unroll
            for (int j = 0; j < 4; ++j) {
                const int row = rbase + j;
                if (row >= N) continue;
                const float v = a[j];
                if (col < DOUT) {
                    p[(size_t)row * SPP + col] = f2bf(v);
                } else if (col >= DOUTP && col < DOUTP + DOUT) {
                    const int co = col - DOUTP;
                    acc_out[(size_t)row * SACC + co] = f2bf(v + bl[co]);
                }
            }
        }
    }
}

// ---- gather: x_next = bf16(acc + invdeg * sum p[src]) ---------------------

template <int DOUT, int SP, int SN>
__global__ void __launch_bounds__(256)
gatherb_kernel(const int* __restrict__ rowptr, const int* __restrict__ csr,
               const unsigned short* __restrict__ p, const unsigned short* __restrict__ acc,
               unsigned short* __restrict__ xnext, int N) {
    const int node = __builtin_amdgcn_readfirstlane((blockIdx.x * 256 + threadIdx.x) >> 6);
    const int lane = threadIdx.x & 63;
    if (node >= N) return;
    const int beg = rowptr[node], end = rowptr[node + 1];
    const float inv = 1.0f / (float)max(end - beg, 1);
    constexpr int NPAIR = (DOUT + 1) / 2;
    const int co = 2 * lane;

    float s0 = 0.f, s1 = 0.f, s2 = 0.f, s3 = 0.f;
    float h0 = 0.f, h1 = 0.f, h2 = 0.f, h3 = 0.f;
    if (lane < NPAIR) {
        int j = beg;
        for (; j + 4 <= end; j += 4) {
            const unsigned u0 = *(const unsigned*)(p + (size_t)csr[j]     * SP + co);
            const unsigned u1 = *(const unsigned*)(p + (size_t)csr[j + 1] * SP + co);
            const unsigned u2 = *(const unsigned*)(p + (size_t)csr[j + 2] * SP + co);
            const unsigned u3 = *(const unsigned*)(p + (size_t)csr[j + 3] * SP + co);
            s0 += bf2f(u0 & 0xffffu); h0 += bf2f(u0 >> 16);
            s1 += bf2f(u1 & 0xffffu); h1 += bf2f(u1 >> 16);
            s2 += bf2f(u2 & 0xffffu); h2 += bf2f(u2 >> 16);
            s3 += bf2f(u3 & 0xffffu); h3 += bf2f(u3 >> 16);
        }
        for (; j < end; ++j) {
            const unsigned u0 = *(const unsigned*)(p + (size_t)csr[j] * SP + co);
            s0 += bf2f(u0 & 0xffffu); h0 += bf2f(u0 >> 16);
        }
    }
    if (co < SN) {
        const float slo = (s0 + s1) + (s2 + s3);
        const float shi = (h0 + h1) + (h2 + h3);
        float lo = 0.f, hi = 0.f;
        if (co < DOUT)     lo = bf2f((unsigned)acc[(size_t)node * SP + co])     + inv * slo;
        if (co + 1 < DOUT) hi = bf2f((unsigned)acc[(size_t)node * SP + co + 1]) + inv * shi;
        const unsigned w = (unsigned)f2bf(lo) | ((unsigned)f2bf(hi) << 16);
        *(unsigned*)(xnext + (size_t)node * SN + co) = w;
    }
}

// ---- layer-2 gather fused with layer-3 GEMV (28 -> 1) ---------------------

__global__ void __launch_bounds__(256)
gather2g_kernel(const int* __restrict__ rowptr, const int* __restrict__ csr,
                const unsigned short* __restrict__ p, const unsigned short* __restrict__ acc,
                const float* __restrict__ Wl3, const float* __restrict__ bl3,
                const float* __restrict__ Wr3,
                float* __restrict__ p3, float* __restrict__ out, int N) {
    const int node = __builtin_amdgcn_readfirstlane((blockIdx.x * 256 + threadIdx.x) >> 6);
    const int lane = threadIdx.x & 63;
    if (node >= N) return;
    const int beg = rowptr[node], end = rowptr[node + 1];
    const float inv = 1.0f / (float)max(end - beg, 1);
    const int co = 2 * lane;

    float s0 = 0.f, s1 = 0.f, s2 = 0.f, s3 = 0.f;
    float h0 = 0.f, h1 = 0.f, h2 = 0.f, h3 = 0.f;
    if (lane < 14) {
        int j = beg;
        for (; j + 4 <= end; j += 4) {
            const unsigned u0 = *(const unsigned*)(p + (size_t)csr[j]     * 32 + co);
            const unsigned u1 = *(const unsigned*)(p + (size_t)csr[j + 1] * 32 + co);
            const unsigned u2 = *(const unsigned*)(p + (size_t)csr[j + 2] * 32 + co);
            const unsigned u3 = *(const unsigned*)(p + (size_t)csr[j + 3] * 32 + co);
            s0 += bf2f(u0 & 0xffffu); h0 += bf2f(u0 >> 16);
            s1 += bf2f(u1 & 0xffffu); h1 += bf2f(u1 >> 16);
            s2 += bf2f(u2 & 0xffffu); h2 += bf2f(u2 >> 16);
            s3 += bf2f(u3 & 0xffffu); h3 += bf2f(u3 >> 16);
        }
        for (; j < end; ++j) {
            const unsigned u0 = *(const unsigned*)(p + (size_t)csr[j] * 32 + co);
            s0 += bf2f(u0 & 0xffffu); h0 += bf2f(u0 >> 16);
        }
    }
    float xlo = 0.f, xhi = 0.f, wl0 = 0.f, wl1 = 0.f, wr0 = 0.f, wr1 = 0.f;
    if (lane < 14) {
        xlo = bf2f((unsigned)acc[(size_t)node * 32 + co])     + inv * ((s0 + s1) + (s2 + s3));
        xhi = bf2f((unsigned)acc[(size_t)node * 32 + co + 1]) + inv * ((h0 + h1) + (h2 + h3));
        wl0 = Wl3[co]; wl1 = Wl3[co + 1];
        wr0 = Wr3[co]; wr1 = Wr3[co + 1];
    }
    float sl = xlo * wl0 + xhi * wl1;
    float sr = xlo * wr0 + xhi * wr1;
#pragma unroll
    for (int off = 32; off > 0; off >>= 1) {
        sl += __shfl_xor(sl, off, 64);
        sr += __shfl_xor(sr, off, 64);
    }
    if (lane == 0) {
        p3[node] = sl;
        out[node] = sr + bl3[0];
    }
}

__global__ void gather1_kernel(const int* __restrict__ rowptr, const int* __restrict__ csr,
                               const float* __restrict__ p, float* __restrict__ out, int N) {
    const int node = blockIdx.x * blockDim.x + threadIdx.x;
    if (node >= N) return;
    const int beg = rowptr[node], end = rowptr[node + 1];
    const float inv = 1.0f / (float)max(end - beg, 1);
    float a0 = 0.f, a1 = 0.f, a2 = 0.f, a3 = 0.f;
    int j = beg;
    for (; j + 4 <= end; j += 4) {
        a0 += p[csr[j]]; a1 += p[csr[j + 1]]; a2 += p[csr[j + 2]]; a3 += p[csr[j + 3]];
    }
    for (; j < end; ++j) a0 += p[csr[j]];
    out[node] += inv * ((a0 + a1) + (a2 + a3));
}

// ---------------------------------------------------------------------------

extern "C" void kernel_launch(void* const* d_in, const int* in_sizes, int n_in,
                              void* d_out, int out_size, void* d_ws, size_t ws_size,
                              hipStream_t stream) {
    const float* x  = (const float*)d_in[0];
    const int*   ei = (const int*)d_in[1];
    const int N = NNODES;
    const int E = NEDGES;
    const int* esrc = ei;
    const int* edst = ei + E;

    const float* Wl[4] = {(const float*)d_in[2], (const float*)d_in[5],
                          (const float*)d_in[8], (const float*)d_in[11]};
    const float* bl[4] = {(const float*)d_in[3], (const float*)d_in[6],
                          (const float*)d_in[9], (const float*)d_in[12]};
    const float* Wr[4] = {(const float*)d_in[4], (const float*)d_in[7],
                          (const float*)d_in[10], (const float*)d_in[13]};

    // ---- workspace arena (byte offsets, 256B aligned) ----
    char* base = (char*)d_ws;
    size_t off = 0;
    auto alloc = [&](size_t bytes) {
        char* r = base + off;
        off += (bytes + 255) & ~(size_t)255;
        return r;
    };
    unsigned short* pB   = (unsigned short*)alloc((size_t)N * 96 * 2);  // p bf16, stride 96/64/32
    unsigned short* accB = (unsigned short*)alloc((size_t)N * 96 * 2);  // acc bf16, stride 96/64/32
    unsigned short* xp   = (unsigned short*)alloc((size_t)N * 96 * 2);  // x1 (stride 96); reused as x2 (stride 64)
    float*          p3   = (float*)alloc((size_t)N * 4);
    unsigned short* Wc0  = (unsigned short*)alloc((size_t)176 * 128 * 2);
    unsigned short* Wc1  = (unsigned short*)alloc((size_t)112 * 96 * 2);
    unsigned short* Wc2  = (unsigned short*)alloc((size_t)64 * 64 * 2);
    int* degi   = (int*)alloc((size_t)N * 4);
    int* rowptr = (int*)alloc((size_t)(N + 1) * 4);
    int* cursor = (int*)alloc((size_t)N * 4);
    int* csr    = (int*)alloc((size_t)E * 4);
    int* bsum   = (int*)alloc(512 * 4);
    int* bpre   = (int*)alloc(512 * 4);

    unsigned short* x2 = xp;   // x1 dead after L1 proj; reuse region for x2

    const int nb = (N + 255) / 256;  // 391

    // CSR build
    hipMemsetAsync(degi, 0, (size_t)N * sizeof(int), stream);
    hist_kernel<<<(E + 255) / 256, 256, 0, stream>>>(edst, degi, E);
    scanA_kernel<<<nb, 256, 0, stream>>>(degi, bsum, N);
    scanB_kernel<<<1, 512, 0, stream>>>(bsum, bpre, nb);
    scanC_kernel<<<nb, 256, 0, stream>>>(degi, bpre, rowptr, cursor, N, E);
    fill_kernel<<<(E + 255) / 256, 256, 0, stream>>>(esrc, edst, cursor, csr, E);

    // weight packs (transposed, bf16, zero-padded), one dispatch
    const int packTot = 176 * 128 + 112 * 96 + 64 * 64;
    packAll_kernel<<<(packTot + 255) / 256, 256, 0, stream>>>(
        Wl[0], Wr[0], Wl[1], Wr[1], Wl[2], Wr[2], Wc0, Wc1, Wc2);

    const int projBlocks = (N + 127) / 128;  // 782 (4 waves x 32 rows)

    // Layer 0: K=128 fp32 input, 11 col-tiles
    projm_kernel<true, 128, 128, 11, 85, 85, 96, 96><<<projBlocks, 256, 0, stream>>>(
        x, Wc0, bl[0], pB, accB, N);
    gatherb_kernel<85, 96, 96><<<(N + 3) / 4, 256, 0, stream>>>(
        rowptr, csr, pB, accB, xp, N);

    // Layer 1: K=96 (85 zero-padded), 7 col-tiles
    projm_kernel<false, 96, 96, 7, 56, 56, 64, 64><<<projBlocks, 256, 0, stream>>>(
        xp, Wc1, bl[1], pB, accB, N);
    gatherb_kernel<56, 64, 64><<<(N + 3) / 4, 256, 0, stream>>>(
        rowptr, csr, pB, accB, x2, N);

    // Layer 2: K=64 (56 zero-padded), 4 col-tiles
    projm_kernel<false, 64, 64, 4, 28, 28, 32, 32><<<projBlocks, 256, 0, stream>>>(
        x2, Wc2, bl[2], pB, accB, N);

    // Layer-2 gather + layer-3 GEMV fused; then scalar gather for layer 3
    gather2g_kernel<<<(N + 3) / 4, 256, 0, stream>>>(
        rowptr, csr, pB, accB, Wl[3], bl[3], Wr[3], p3, (float*)d_out, N);
    gather1_kernel<<<(N + 255) / 256, 256, 0, stream>>>(
        rowptr, csr, p3, (float*)d_out, N);
}

// Round 10
// 258.093 us; speedup vs baseline: 47.2759x; 1.0405x over previous
//
#include <hip/hip_runtime.h>

// ---------------------------------------------------------------------------
// SageCox: 4-layer GraphSAGE (mean aggr), N=100000, E=640000.
// out = mean_neigh(x)@Wl + bl + x@Wr per layer.
// Restructured: p = x@Wl ; acc = bf16(x@Wr + bl) ; x_next = bf16(acc + invdeg*sum p[src]).
// proj = MFMA bf16 (16x16x32, f32 accum); wave owns 32 rows x all col-tiles,
// B frags loaded per tile. Epilogue: D-frags scattered (2B) into LDS tile
// [128][SPP+8], then block-cooperative CONTIGUOUS bf16x8 stores to global
// (fixes 1.67x partial-line write amplification of direct 2B stores).
// Gather: CSR, node-per-wave, paired-uint column loads, 4-edge unroll.
// p/acc/xnext rows padded to 96/64/32 elems (whole 128B lines).
// Layer-3 GEMV fused into layer-2 gather (wave shfl_xor reduce).
// ---------------------------------------------------------------------------

#define NNODES 100000
#define NEDGES 640000

using bf16x8 = __attribute__((ext_vector_type(8))) short;
using f32x4  = __attribute__((ext_vector_type(4))) float;

__device__ __forceinline__ unsigned short f2bf(float f) {
    union { float f; unsigned u; } v; v.f = f;
    unsigned r = v.u + 0x7fffu + ((v.u >> 16) & 1u);
    return (unsigned short)(r >> 16);
}
__device__ __forceinline__ float bf2f(unsigned b) {
    union { unsigned u; float f; } v; v.u = b << 16;
    return v.f;
}

// ---- CSR build ------------------------------------------------------------

__global__ void hist_kernel(const int* __restrict__ edst, int* __restrict__ deg, int E) {
    int i = blockIdx.x * blockDim.x + threadIdx.x;
    if (i < E) atomicAdd(&deg[edst[i]], 1);
}

__global__ void scanA_kernel(const int* __restrict__ deg, int* __restrict__ bsum, int N) {
    __shared__ int s[256];
    int i = blockIdx.x * 256 + threadIdx.x;
    s[threadIdx.x] = (i < N) ? deg[i] : 0;
    __syncthreads();
    for (int off = 128; off > 0; off >>= 1) {
        if (threadIdx.x < off) s[threadIdx.x] += s[threadIdx.x + off];
        __syncthreads();
    }
    if (threadIdx.x == 0) bsum[blockIdx.x] = s[0];
}

__global__ void scanB_kernel(const int* __restrict__ bsum, int* __restrict__ bpre, int nb) {
    __shared__ int s[512];
    int t = threadIdx.x;
    int v = (t < nb) ? bsum[t] : 0;
    s[t] = v;
    __syncthreads();
    for (int off = 1; off < 512; off <<= 1) {
        int add = (t >= off) ? s[t - off] : 0;
        __syncthreads();
        s[t] += add;
        __syncthreads();
    }
    if (t < nb) bpre[t] = s[t] - v;  // exclusive
}

__global__ void scanC_kernel(const int* __restrict__ deg, const int* __restrict__ bpre,
                             int* __restrict__ rowptr, int* __restrict__ cursor, int N, int E) {
    __shared__ int s[256];
    int t = threadIdx.x;
    int i = blockIdx.x * 256 + t;
    int v = (i < N) ? deg[i] : 0;
    s[t] = v;
    __syncthreads();
    for (int off = 1; off < 256; off <<= 1) {
        int add = (t >= off) ? s[t - off] : 0;
        __syncthreads();
        s[t] += add;
        __syncthreads();
    }
    if (i < N) {
        int excl = bpre[blockIdx.x] + s[t] - v;
        rowptr[i] = excl;
        cursor[i] = excl;
        if (i == N - 1) rowptr[N] = E;
    }
}

__global__ void fill_kernel(const int* __restrict__ esrc, const int* __restrict__ edst,
                            int* __restrict__ cursor, int* __restrict__ csr, int E) {
    int i = blockIdx.x * blockDim.x + threadIdx.x;
    if (i < E) {
        int pos = atomicAdd(&cursor[edst[i]], 1);
        csr[pos] = esrc[i];
    }
}

// ---- merged weight pack: WcT[c][k] bf16 for all 3 MFMA layers -------------

__device__ __forceinline__ void packT_one(const float* Wl, const float* Wr,
                                          unsigned short* WcT, int idx, int DIN,
                                          int KP, int DOUT, int DOUTP) {
    int c = idx / KP, k = idx - c * KP;
    float v = 0.0f;
    if (k < DIN) {
        if (c < DOUT) v = Wl[k * DOUT + c];
        else if (c >= DOUTP && c < DOUTP + DOUT) v = Wr[k * DOUT + (c - DOUTP)];
    }
    WcT[idx] = f2bf(v);
}

__global__ void packAll_kernel(const float* __restrict__ Wl0, const float* __restrict__ Wr0,
                               const float* __restrict__ Wl1, const float* __restrict__ Wr1,
                               const float* __restrict__ Wl2, const float* __restrict__ Wr2,
                               unsigned short* __restrict__ Wc0,
                               unsigned short* __restrict__ Wc1,
                               unsigned short* __restrict__ Wc2) {
    const int S0 = 176 * 128, S1 = 112 * 96, S2 = 64 * 64;
    int idx = blockIdx.x * blockDim.x + threadIdx.x;
    if (idx < S0) packT_one(Wl0, Wr0, Wc0, idx, 128, 128, 85, 85);
    else if (idx < S0 + S1) packT_one(Wl1, Wr1, Wc1, idx - S0, 85, 96, 56, 56);
    else if (idx < S0 + S1 + S2) packT_one(Wl2, Wr2, Wc2, idx - S0 - S1, 56, 64, 28, 28);
}

// ---- MFMA projection with LDS-staged coalesced epilogue -------------------
// block = 4 waves x 32 rows = 128 rows, all NTILES col-tiles per wave.
// D layout: row = rowbase+(lane>>4)*4+j, col = nt*16+(lane&15).
// LDS tiles pS/aS [128][LSTR] bf16 (LSTR = SPP+8; 2B-elem stride -> 16B-
// aligned rows, 2-way-max bank alias on frag scatter = free).
// Final stores: contiguous bf16x8, block rows adjacent in pB/accB.

template <bool XFP32, int KP, int SIN, int NTILES, int DOUT, int DOUTP, int SPP>
__global__ void __launch_bounds__(256)
projm_kernel(const void* __restrict__ xin,
             const unsigned short* __restrict__ WcT,
             const float* __restrict__ bl,
             unsigned short* __restrict__ p,
             unsigned short* __restrict__ acc_out, int N) {
    constexpr int KT = KP / 32;
    constexpr int LSTR = SPP + 8;          // (SPP+8)*2B is a multiple of 16B
    __shared__ short pS[128 * LSTR];
    __shared__ short aS[128 * LSTR];

    const int lane = threadIdx.x & 63;
    const int wave = threadIdx.x >> 6;
    const int l15 = lane & 15;
    const int lk  = lane >> 4;

    const int row0 = blockIdx.x * 128;
    const int wrow = wave * 32;            // wave's base row within block

    // zero the pad columns [DOUT, SPP) (16-wide stripe covers them)
    for (int i = threadIdx.x; i < 128 * 16; i += 256) {
        const int r = i >> 4;
        const int c = DOUT + (i & 15);
        if (c < SPP) {
            pS[r * LSTR + c] = 0;
            aS[r * LSTR + c] = 0;
        }
    }

    bf16x8 afrag[2][KT];
#pragma unroll
    for (int h = 0; h < 2; ++h) {
        int arow = row0 + wrow + h * 16 + l15;
        if (arow >= N) arow = N - 1;       // clamp; rows >= N never stored
        if constexpr (XFP32) {
            const float* xr = (const float*)xin + (size_t)arow * SIN + lk * 8;
#pragma unroll
            for (int kt = 0; kt < KT; ++kt) {
                const float4 a = *(const float4*)(xr + kt * 32);
                const float4 b = *(const float4*)(xr + kt * 32 + 4);
                bf16x8 v;
                v[0] = (short)f2bf(a.x); v[1] = (short)f2bf(a.y);
                v[2] = (short)f2bf(a.z); v[3] = (short)f2bf(a.w);
                v[4] = (short)f2bf(b.x); v[5] = (short)f2bf(b.y);
                v[6] = (short)f2bf(b.z); v[7] = (short)f2bf(b.w);
                afrag[h][kt] = v;
            }
        } else {
            const unsigned short* xr = (const unsigned short*)xin + (size_t)arow * SIN + lk * 8;
#pragma unroll
            for (int kt = 0; kt < KT; ++kt)
                afrag[h][kt] = *(const bf16x8*)(xr + kt * 32);
        }
    }

#pragma unroll 2
    for (int nt = 0; nt < NTILES; ++nt) {
        const unsigned short* wp = WcT + (size_t)(nt * 16 + l15) * KP + lk * 8;
        bf16x8 bfrag[KT];
#pragma unroll
        for (int kt = 0; kt < KT; ++kt)
            bfrag[kt] = *(const bf16x8*)(wp + kt * 32);

        f32x4 a0 = {0.f, 0.f, 0.f, 0.f};
        f32x4 a1 = {0.f, 0.f, 0.f, 0.f};
#pragma unroll
        for (int kt = 0; kt < KT; ++kt) {
            a0 = __builtin_amdgcn_mfma_f32_16x16x32_bf16(afrag[0][kt], bfrag[kt], a0, 0, 0, 0);
            a1 = __builtin_amdgcn_mfma_f32_16x16x32_bf16(afrag[1][kt], bfrag[kt], a1, 0, 0, 0);
        }

        const int col = nt * 16 + l15;
#pragma unroll
        for (int h = 0; h < 2; ++h) {
            const f32x4 a = h ? a1 : a0;
            const int rl = wrow + h * 16 + lk * 4;   // local row base
#pragma unroll
            for (int j = 0; j < 4; ++j) {
                const float v = a[j];
                if (col < DOUT) {
                    pS[(rl + j) * LSTR + col] = (short)f2bf(v);
                } else if (col >= DOUTP && col < DOUTP + DOUT) {
                    const int co = col - DOUTP;
                    aS[(rl + j) * LSTR + co] = (short)f2bf(v + bl[co]);
                }
            }
        }
    }

    __syncthreads();

    // block-cooperative contiguous stores: rows row0..row0+rows_here-1,
    // global region [row0*SPP, (row0+rows_here)*SPP) is contiguous.
    const int rows_here = min(128, N - row0);
    const int cnt8 = rows_here * (SPP / 8);
    for (int e8 = threadIdx.x; e8 < cnt8; e8 += 256) {
        const int row = e8 / (SPP / 8);
        const int c8  = e8 - row * (SPP / 8);
        const int loff = row * LSTR + c8 * 8;
        *(bf16x8*)(p + (size_t)row0 * SPP + (size_t)e8 * 8) = *(const bf16x8*)(pS + loff);
    }
    for (int e8 = threadIdx.x; e8 < cnt8; e8 += 256) {
        const int row = e8 / (SPP / 8);
        const int c8  = e8 - row * (SPP / 8);
        const int loff = row * LSTR + c8 * 8;
        *(bf16x8*)(acc_out + (size_t)row0 * SPP + (size_t)e8 * 8) = *(const bf16x8*)(aS + loff);
    }
}

// ---- gather: x_next = bf16(acc + invdeg * sum p[src]) ---------------------

template <int DOUT, int SP, int SN>
__global__ void __launch_bounds__(256)
gatherb_kernel(const int* __restrict__ rowptr, const int* __restrict__ csr,
               const unsigned short* __restrict__ p, const unsigned short* __restrict__ acc,
               unsigned short* __restrict__ xnext, int N) {
    const int node = __builtin_amdgcn_readfirstlane((blockIdx.x * 256 + threadIdx.x) >> 6);
    const int lane = threadIdx.x & 63;
    if (node >= N) return;
    const int beg = rowptr[node], end = rowptr[node + 1];
    const float inv = 1.0f / (float)max(end - beg, 1);
    constexpr int NPAIR = (DOUT + 1) / 2;
    const int co = 2 * lane;

    float s0 = 0.f, s1 = 0.f, s2 = 0.f, s3 = 0.f;
    float h0 = 0.f, h1 = 0.f, h2 = 0.f, h3 = 0.f;
    if (lane < NPAIR) {
        int j = beg;
        for (; j + 4 <= end; j += 4) {
            const unsigned u0 = *(const unsigned*)(p + (size_t)csr[j]     * SP + co);
            const unsigned u1 = *(const unsigned*)(p + (size_t)csr[j + 1] * SP + co);
            const unsigned u2 = *(const unsigned*)(p + (size_t)csr[j + 2] * SP + co);
            const unsigned u3 = *(const unsigned*)(p + (size_t)csr[j + 3] * SP + co);
            s0 += bf2f(u0 & 0xffffu); h0 += bf2f(u0 >> 16);
            s1 += bf2f(u1 & 0xffffu); h1 += bf2f(u1 >> 16);
            s2 += bf2f(u2 & 0xffffu); h2 += bf2f(u2 >> 16);
            s3 += bf2f(u3 & 0xffffu); h3 += bf2f(u3 >> 16);
        }
        for (; j < end; ++j) {
            const unsigned u0 = *(const unsigned*)(p + (size_t)csr[j] * SP + co);
            s0 += bf2f(u0 & 0xffffu); h0 += bf2f(u0 >> 16);
        }
    }
    if (co < SN) {
        const float slo = (s0 + s1) + (s2 + s3);
        const float shi = (h0 + h1) + (h2 + h3);
        float lo = 0.f, hi = 0.f;
        if (co < DOUT)     lo = bf2f((unsigned)acc[(size_t)node * SP + co])     + inv * slo;
        if (co + 1 < DOUT) hi = bf2f((unsigned)acc[(size_t)node * SP + co + 1]) + inv * shi;
        const unsigned w = (unsigned)f2bf(lo) | ((unsigned)f2bf(hi) << 16);
        *(unsigned*)(xnext + (size_t)node * SN + co) = w;
    }
}

// ---- layer-2 gather fused with layer-3 GEMV (28 -> 1) ---------------------

__global__ void __launch_bounds__(256)
gather2g_kernel(const int* __restrict__ rowptr, const int* __restrict__ csr,
                const unsigned short* __restrict__ p, const unsigned short* __restrict__ acc,
                const float* __restrict__ Wl3, const float* __restrict__ bl3,
                const float* __restrict__ Wr3,
                float* __restrict__ p3, float* __restrict__ out, int N) {
    const int node = __builtin_amdgcn_readfirstlane((blockIdx.x * 256 + threadIdx.x) >> 6);
    const int lane = threadIdx.x & 63;
    if (node >= N) return;
    const int beg = rowptr[node], end = rowptr[node + 1];
    const float inv = 1.0f / (float)max(end - beg, 1);
    const int co = 2 * lane;

    float s0 = 0.f, s1 = 0.f, s2 = 0.f, s3 = 0.f;
    float h0 = 0.f, h1 = 0.f, h2 = 0.f, h3 = 0.f;
    if (lane < 14) {
        int j = beg;
        for (; j + 4 <= end; j += 4) {
            const unsigned u0 = *(const unsigned*)(p + (size_t)csr[j]     * 32 + co);
            const unsigned u1 = *(const unsigned*)(p + (size_t)csr[j + 1] * 32 + co);
            const unsigned u2 = *(const unsigned*)(p + (size_t)csr[j + 2] * 32 + co);
            const unsigned u3 = *(const unsigned*)(p + (size_t)csr[j + 3] * 32 + co);
            s0 += bf2f(u0 & 0xffffu); h0 += bf2f(u0 >> 16);
            s1 += bf2f(u1 & 0xffffu); h1 += bf2f(u1 >> 16);
            s2 += bf2f(u2 & 0xffffu); h2 += bf2f(u2 >> 16);
            s3 += bf2f(u3 & 0xffffu); h3 += bf2f(u3 >> 16);
        }
        for (; j < end; ++j) {
            const unsigned u0 = *(const unsigned*)(p + (size_t)csr[j] * 32 + co);
            s0 += bf2f(u0 & 0xffffu); h0 += bf2f(u0 >> 16);
        }
    }
    float xlo = 0.f, xhi = 0.f, wl0 = 0.f, wl1 = 0.f, wr0 = 0.f, wr1 = 0.f;
    if (lane < 14) {
        xlo = bf2f((unsigned)acc[(size_t)node * 32 + co])     + inv * ((s0 + s1) + (s2 + s3));
        xhi = bf2f((unsigned)acc[(size_t)node * 32 + co + 1]) + inv * ((h0 + h1) + (h2 + h3));
        wl0 = Wl3[co]; wl1 = Wl3[co + 1];
        wr0 = Wr3[co]; wr1 = Wr3[co + 1];
    }
    float sl = xlo * wl0 + xhi * wl1;
    float sr = xlo * wr0 + xhi * wr1;
#pragma unroll
    for (int off = 32; off > 0; off >>= 1) {
        sl += __shfl_xor(sl, off, 64);
        sr += __shfl_xor(sr, off, 64);
    }
    if (lane == 0) {
        p3[node] = sl;
        out[node] = sr + bl3[0];
    }
}

__global__ void gather1_kernel(const int* __restrict__ rowptr, const int* __restrict__ csr,
                               const float* __restrict__ p, float* __restrict__ out, int N) {
    const int node = blockIdx.x * blockDim.x + threadIdx.x;
    if (node >= N) return;
    const int beg = rowptr[node], end = rowptr[node + 1];
    const float inv = 1.0f / (float)max(end - beg, 1);
    float a0 = 0.f, a1 = 0.f, a2 = 0.f, a3 = 0.f;
    int j = beg;
    for (; j + 4 <= end; j += 4) {
        a0 += p[csr[j]]; a1 += p[csr[j + 1]]; a2 += p[csr[j + 2]]; a3 += p[csr[j + 3]];
    }
    for (; j < end; ++j) a0 += p[csr[j]];
    out[node] += inv * ((a0 + a1) + (a2 + a3));
}

// ---------------------------------------------------------------------------

extern "C" void kernel_launch(void* const* d_in, const int* in_sizes, int n_in,
                              void* d_out, int out_size, void* d_ws, size_t ws_size,
                              hipStream_t stream) {
    const float* x  = (const float*)d_in[0];
    const int*   ei = (const int*)d_in[1];
    const int N = NNODES;
    const int E = NEDGES;
    const int* esrc = ei;
    const int* edst = ei + E;

    const float* Wl[4] = {(const float*)d_in[2], (const float*)d_in[5],
                          (const float*)d_in[8], (const float*)d_in[11]};
    const float* bl[4] = {(const float*)d_in[3], (const float*)d_in[6],
                          (const float*)d_in[9], (const float*)d_in[12]};
    const float* Wr[4] = {(const float*)d_in[4], (const float*)d_in[7],
                          (const float*)d_in[10], (const float*)d_in[13]};

    // ---- workspace arena (byte offsets, 256B aligned) ----
    char* base = (char*)d_ws;
    size_t off = 0;
    auto alloc = [&](size_t bytes) {
        char* r = base + off;
        off += (bytes + 255) & ~(size_t)255;
        return r;
    };
    unsigned short* pB   = (unsigned short*)alloc((size_t)N * 96 * 2);  // p bf16, stride 96/64/32
    unsigned short* accB = (unsigned short*)alloc((size_t)N * 96 * 2);  // acc bf16, stride 96/64/32
    unsigned short* xp   = (unsigned short*)alloc((size_t)N * 96 * 2);  // x1 (stride 96); reused as x2 (stride 64)
    float*          p3   = (float*)alloc((size_t)N * 4);
    unsigned short* Wc0  = (unsigned short*)alloc((size_t)176 * 128 * 2);
    unsigned short* Wc1  = (unsigned short*)alloc((size_t)112 * 96 * 2);
    unsigned short* Wc2  = (unsigned short*)alloc((size_t)64 * 64 * 2);
    int* degi   = (int*)alloc((size_t)N * 4);
    int* rowptr = (int*)alloc((size_t)(N + 1) * 4);
    int* cursor = (int*)alloc((size_t)N * 4);
    int* csr    = (int*)alloc((size_t)E * 4);
    int* bsum   = (int*)alloc(512 * 4);
    int* bpre   = (int*)alloc(512 * 4);

    unsigned short* x2 = xp;   // x1 dead after L1 proj; reuse region for x2

    const int nb = (N + 255) / 256;  // 391

    // CSR build
    hipMemsetAsync(degi, 0, (size_t)N * sizeof(int), stream);
    hist_kernel<<<(E + 255) / 256, 256, 0, stream>>>(edst, degi, E);
    scanA_kernel<<<nb, 256, 0, stream>>>(degi, bsum, N);
    scanB_kernel<<<1, 512, 0, stream>>>(bsum, bpre, nb);
    scanC_kernel<<<nb, 256, 0, stream>>>(degi, bpre, rowptr, cursor, N, E);
    fill_kernel<<<(E + 255) / 256, 256, 0, stream>>>(esrc, edst, cursor, csr, E);

    // weight packs (transposed, bf16, zero-padded), one dispatch
    const int packTot = 176 * 128 + 112 * 96 + 64 * 64;
    packAll_kernel<<<(packTot + 255) / 256, 256, 0, stream>>>(
        Wl[0], Wr[0], Wl[1], Wr[1], Wl[2], Wr[2], Wc0, Wc1, Wc2);

    const int projBlocks = (N + 127) / 128;  // 782 (4 waves x 32 rows)

    // Layer 0: K=128 fp32 input, 11 col-tiles; p/acc stride 96
    projm_kernel<true, 128, 128, 11, 85, 85, 96><<<projBlocks, 256, 0, stream>>>(
        x, Wc0, bl[0], pB, accB, N);
    gatherb_kernel<85, 96, 96><<<(N + 3) / 4, 256, 0, stream>>>(
        rowptr, csr, pB, accB, xp, N);

    // Layer 1: K=96 (85 zero-padded), 7 col-tiles; p/acc stride 64
    projm_kernel<false, 96, 96, 7, 56, 56, 64><<<projBlocks, 256, 0, stream>>>(
        xp, Wc1, bl[1], pB, accB, N);
    gatherb_kernel<56, 64, 64><<<(N + 3) / 4, 256, 0, stream>>>(
        rowptr, csr, pB, accB, x2, N);

    // Layer 2: K=64 (56 zero-padded), 4 col-tiles; p/acc stride 32
    projm_kernel<false, 64, 64, 4, 28, 28, 32><<<projBlocks, 256, 0, stream>>>(
        x2, Wc2, bl[2], pB, accB, N);

    // Layer-2 gather + layer-3 GEMV fused; then scalar gather for layer 3
    gather2g_kernel<<<(N + 3) / 4, 256, 0, stream>>>(
        rowptr, csr, pB, accB, Wl[3], bl[3], Wr[3], p3, (float*)d_out, N);
    gather1_kernel<<<(N + 255) / 256, 256, 0, stream>>>(
        rowptr, csr, p3, (float*)d_out, N);
}

// Round 11
// 254.937 us; speedup vs baseline: 47.8611x; 1.0124x over previous
//
#include <hip/hip_runtime.h>

// ---------------------------------------------------------------------------
// SageCox: 4-layer GraphSAGE (mean aggr), N=100000, E=640000.
// out = mean_neigh(x)@Wl + bl + x@Wr per layer.
// Restructured: p = x@Wl ; acc = bf16(x@Wr + bl) ; x_next = bf16(acc + invdeg*sum p[src]).
// proj = MFMA bf16 (16x16x32, f32 accum). Weight pack staged in LDS per block
// (B-frags via ds_read_b128, +8 row pad -> 2-way max bank alias). Two phases
// over ONE output LDS buffer: phase A = Wl tiles -> p, phase B = Wr tiles
// (+bias) -> acc; each phase ends with block-cooperative contiguous bf16x8
// stores. Pack has no p/acc straddle: Wl cols [0,HT*16), Wr cols [HT*16, CW).
// Gather: CSR, node-per-wave, paired-uint column loads, 4-edge unroll.
// p/acc/xnext rows padded to 96/64/32 elems (whole 128B lines).
// Layer-3 GEMV fused into layer-2 gather (wave shfl_xor reduce).
// ---------------------------------------------------------------------------

#define NNODES 100000
#define NEDGES 640000

using bf16x8 = __attribute__((ext_vector_type(8))) short;
using f32x4  = __attribute__((ext_vector_type(4))) float;

__device__ __forceinline__ unsigned short f2bf(float f) {
    union { float f; unsigned u; } v; v.f = f;
    unsigned r = v.u + 0x7fffu + ((v.u >> 16) & 1u);
    return (unsigned short)(r >> 16);
}
__device__ __forceinline__ float bf2f(unsigned b) {
    union { unsigned u; float f; } v; v.u = b << 16;
    return v.f;
}

// ---- CSR build ------------------------------------------------------------

__global__ void hist_kernel(const int* __restrict__ edst, int* __restrict__ deg, int E) {
    int i = blockIdx.x * blockDim.x + threadIdx.x;
    if (i < E) atomicAdd(&deg[edst[i]], 1);
}

__global__ void scanA_kernel(const int* __restrict__ deg, int* __restrict__ bsum, int N) {
    __shared__ int s[256];
    int i = blockIdx.x * 256 + threadIdx.x;
    s[threadIdx.x] = (i < N) ? deg[i] : 0;
    __syncthreads();
    for (int off = 128; off > 0; off >>= 1) {
        if (threadIdx.x < off) s[threadIdx.x] += s[threadIdx.x + off];
        __syncthreads();
    }
    if (threadIdx.x == 0) bsum[blockIdx.x] = s[0];
}

__global__ void scanB_kernel(const int* __restrict__ bsum, int* __restrict__ bpre, int nb) {
    __shared__ int s[512];
    int t = threadIdx.x;
    int v = (t < nb) ? bsum[t] : 0;
    s[t] = v;
    __syncthreads();
    for (int off = 1; off < 512; off <<= 1) {
        int add = (t >= off) ? s[t - off] : 0;
        __syncthreads();
        s[t] += add;
        __syncthreads();
    }
    if (t < nb) bpre[t] = s[t] - v;  // exclusive
}

__global__ void scanC_kernel(const int* __restrict__ deg, const int* __restrict__ bpre,
                             int* __restrict__ rowptr, int* __restrict__ cursor, int N, int E) {
    __shared__ int s[256];
    int t = threadIdx.x;
    int i = blockIdx.x * 256 + t;
    int v = (i < N) ? deg[i] : 0;
    s[t] = v;
    __syncthreads();
    for (int off = 1; off < 256; off <<= 1) {
        int add = (t >= off) ? s[t - off] : 0;
        __syncthreads();
        s[t] += add;
        __syncthreads();
    }
    if (i < N) {
        int excl = bpre[blockIdx.x] + s[t] - v;
        rowptr[i] = excl;
        cursor[i] = excl;
        if (i == N - 1) rowptr[N] = E;
    }
}

__global__ void fill_kernel(const int* __restrict__ esrc, const int* __restrict__ edst,
                            int* __restrict__ cursor, int* __restrict__ csr, int E) {
    int i = blockIdx.x * blockDim.x + threadIdx.x;
    if (i < E) {
        int pos = atomicAdd(&cursor[edst[i]], 1);
        csr[pos] = esrc[i];
    }
}

// ---- merged weight pack: WcT[c][k] bf16, no straddle ----------------------
// c < DOUT -> Wl ; DOUTP <= c < DOUTP+DOUT -> Wr ; else 0.

__device__ __forceinline__ void packT_one(const float* Wl, const float* Wr,
                                          unsigned short* WcT, int idx, int DIN,
                                          int KP, int DOUT, int DOUTP) {
    int c = idx / KP, k = idx - c * KP;
    float v = 0.0f;
    if (k < DIN) {
        if (c < DOUT) v = Wl[k * DOUT + c];
        else if (c >= DOUTP && c < DOUTP + DOUT) v = Wr[k * DOUT + (c - DOUTP)];
    }
    WcT[idx] = f2bf(v);
}

__global__ void packAll_kernel(const float* __restrict__ Wl0, const float* __restrict__ Wr0,
                               const float* __restrict__ Wl1, const float* __restrict__ Wr1,
                               const float* __restrict__ Wl2, const float* __restrict__ Wr2,
                               unsigned short* __restrict__ Wc0,
                               unsigned short* __restrict__ Wc1,
                               unsigned short* __restrict__ Wc2) {
    const int S0 = 192 * 128, S1 = 128 * 96, S2 = 64 * 64;
    int idx = blockIdx.x * blockDim.x + threadIdx.x;
    if (idx < S0) packT_one(Wl0, Wr0, Wc0, idx, 128, 128, 85, 96);
    else if (idx < S0 + S1) packT_one(Wl1, Wr1, Wc1, idx - S0, 85, 96, 56, 64);
    else if (idx < S0 + S1 + S2) packT_one(Wl2, Wr2, Wc2, idx - S0 - S1, 56, 64, 28, 32);
}

// ---- MFMA projection: W in LDS + 2-phase LDS-staged epilogue --------------
// block = 4 waves x 32 rows = 128 rows. NTILES = CW/16 (even); phase A =
// tiles [0,HT) -> p, phase B = tiles [HT,NT) (+bias) -> acc.
// D layout: row = rowbase+(lane>>4)*4+j, col(within phase) = nt*16+(lane&15).

template <bool XFP32, int KP, int SIN, int NTILES, int DOUT, int SPP>
__global__ void __launch_bounds__(256)
projm_kernel(const void* __restrict__ xin,
             const unsigned short* __restrict__ WcT,
             const float* __restrict__ bl,
             unsigned short* __restrict__ p,
             unsigned short* __restrict__ acc_out, int N) {
    constexpr int KT   = KP / 32;
    constexpr int HT   = NTILES / 2;
    constexpr int CW   = NTILES * 16;
    constexpr int WSTR = KP + 8;           // W LDS row stride (16B-multiple *2B)
    constexpr int LSTR = SPP + 8;          // out LDS row stride
    static_assert(HT * 16 == SPP, "phase width must equal SPP");
    __shared__ short wS[CW * WSTR];
    __shared__ short oS[128 * LSTR];

    const int lane = threadIdx.x & 63;
    const int wave = threadIdx.x >> 6;
    const int l15 = lane & 15;
    const int lk  = lane >> 4;
    const int row0 = blockIdx.x * 128;
    const int wrow = wave * 32;

    // stage weight pack into LDS (coalesced 16B chunks)
    for (int c8 = threadIdx.x; c8 < CW * (KP / 8); c8 += 256) {
        const int c  = c8 / (KP / 8);
        const int k8 = c8 - c * (KP / 8);
        *(bf16x8*)(wS + c * WSTR + k8 * 8) =
            *(const bf16x8*)(WcT + (size_t)c * KP + k8 * 8);
    }

    // A-fragments (2 x 16 rows per wave), registers
    bf16x8 afrag[2][KT];
#pragma unroll
    for (int h = 0; h < 2; ++h) {
        int arow = row0 + wrow + h * 16 + l15;
        if (arow >= N) arow = N - 1;       // clamp; rows >= N never stored
        if constexpr (XFP32) {
            const float* xr = (const float*)xin + (size_t)arow * SIN + lk * 8;
#pragma unroll
            for (int kt = 0; kt < KT; ++kt) {
                const float4 a = *(const float4*)(xr + kt * 32);
                const float4 b = *(const float4*)(xr + kt * 32 + 4);
                bf16x8 v;
                v[0] = (short)f2bf(a.x); v[1] = (short)f2bf(a.y);
                v[2] = (short)f2bf(a.z); v[3] = (short)f2bf(a.w);
                v[4] = (short)f2bf(b.x); v[5] = (short)f2bf(b.y);
                v[6] = (short)f2bf(b.z); v[7] = (short)f2bf(b.w);
                afrag[h][kt] = v;
            }
        } else {
            const unsigned short* xr = (const unsigned short*)xin + (size_t)arow * SIN + lk * 8;
#pragma unroll
            for (int kt = 0; kt < KT; ++kt)
                afrag[h][kt] = *(const bf16x8*)(xr + kt * 32);
        }
    }

    __syncthreads();

    const int rows_here = min(128, N - row0);
    const int cnt8 = rows_here * (SPP / 8);

#pragma unroll
    for (int ph = 0; ph < 2; ++ph) {
#pragma unroll 2
        for (int nt = 0; nt < HT; ++nt) {
            const short* wp = wS + (size_t)((ph * HT + nt) * 16 + l15) * WSTR + lk * 8;
            bf16x8 bfrag[KT];
#pragma unroll
            for (int kt = 0; kt < KT; ++kt)
                bfrag[kt] = *(const bf16x8*)(wp + kt * 32);

            f32x4 a0 = {0.f, 0.f, 0.f, 0.f};
            f32x4 a1 = {0.f, 0.f, 0.f, 0.f};
#pragma unroll
            for (int kt = 0; kt < KT; ++kt) {
                a0 = __builtin_amdgcn_mfma_f32_16x16x32_bf16(afrag[0][kt], bfrag[kt], a0, 0, 0, 0);
                a1 = __builtin_amdgcn_mfma_f32_16x16x32_bf16(afrag[1][kt], bfrag[kt], a1, 0, 0, 0);
            }

            const int co = nt * 16 + l15;                 // col within phase
            const float bias = (ph == 1 && co < DOUT) ? bl[co] : 0.0f;
#pragma unroll
            for (int h = 0; h < 2; ++h) {
                const f32x4 a = h ? a1 : a0;
                const int rl = wrow + h * 16 + lk * 4;
#pragma unroll
                for (int j = 0; j < 4; ++j)
                    oS[(rl + j) * LSTR + co] = (short)f2bf(a[j] + bias);
            }
        }

        __syncthreads();

        unsigned short* dst = ph ? acc_out : p;
        for (int e8 = threadIdx.x; e8 < cnt8; e8 += 256) {
            const int row = e8 / (SPP / 8);
            const int c8  = e8 - row * (SPP / 8);
            *(bf16x8*)(dst + (size_t)row0 * SPP + (size_t)e8 * 8) =
                *(const bf16x8*)(oS + row * LSTR + c8 * 8);
        }

        __syncthreads();
    }
}

// ---- gather: x_next = bf16(acc + invdeg * sum p[src]) ---------------------

template <int DOUT, int SP, int SN>
__global__ void __launch_bounds__(256)
gatherb_kernel(const int* __restrict__ rowptr, const int* __restrict__ csr,
               const unsigned short* __restrict__ p, const unsigned short* __restrict__ acc,
               unsigned short* __restrict__ xnext, int N) {
    const int node = __builtin_amdgcn_readfirstlane((blockIdx.x * 256 + threadIdx.x) >> 6);
    const int lane = threadIdx.x & 63;
    if (node >= N) return;
    const int beg = rowptr[node], end = rowptr[node + 1];
    const float inv = 1.0f / (float)max(end - beg, 1);
    constexpr int NPAIR = (DOUT + 1) / 2;
    const int co = 2 * lane;

    float s0 = 0.f, s1 = 0.f, s2 = 0.f, s3 = 0.f;
    float h0 = 0.f, h1 = 0.f, h2 = 0.f, h3 = 0.f;
    if (lane < NPAIR) {
        int j = beg;
        for (; j + 4 <= end; j += 4) {
            const unsigned u0 = *(const unsigned*)(p + (size_t)csr[j]     * SP + co);
            const unsigned u1 = *(const unsigned*)(p + (size_t)csr[j + 1] * SP + co);
            const unsigned u2 = *(const unsigned*)(p + (size_t)csr[j + 2] * SP + co);
            const unsigned u3 = *(const unsigned*)(p + (size_t)csr[j + 3] * SP + co);
            s0 += bf2f(u0 & 0xffffu); h0 += bf2f(u0 >> 16);
            s1 += bf2f(u1 & 0xffffu); h1 += bf2f(u1 >> 16);
            s2 += bf2f(u2 & 0xffffu); h2 += bf2f(u2 >> 16);
            s3 += bf2f(u3 & 0xffffu); h3 += bf2f(u3 >> 16);
        }
        for (; j < end; ++j) {
            const unsigned u0 = *(const unsigned*)(p + (size_t)csr[j] * SP + co);
            s0 += bf2f(u0 & 0xffffu); h0 += bf2f(u0 >> 16);
        }
    }
    if (co < SN) {
        const float slo = (s0 + s1) + (s2 + s3);
        const float shi = (h0 + h1) + (h2 + h3);
        float lo = 0.f, hi = 0.f;
        if (co < DOUT)     lo = bf2f((unsigned)acc[(size_t)node * SP + co])     + inv * slo;
        if (co + 1 < DOUT) hi = bf2f((unsigned)acc[(size_t)node * SP + co + 1]) + inv * shi;
        const unsigned w = (unsigned)f2bf(lo) | ((unsigned)f2bf(hi) << 16);
        *(unsigned*)(xnext + (size_t)node * SN + co) = w;
    }
}

// ---- layer-2 gather fused with layer-3 GEMV (28 -> 1) ---------------------

__global__ void __launch_bounds__(256)
gather2g_kernel(const int* __restrict__ rowptr, const int* __restrict__ csr,
                const unsigned short* __restrict__ p, const unsigned short* __restrict__ acc,
                const float* __restrict__ Wl3, const float* __restrict__ bl3,
                const float* __restrict__ Wr3,
                float* __restrict__ p3, float* __restrict__ out, int N) {
    const int node = __builtin_amdgcn_readfirstlane((blockIdx.x * 256 + threadIdx.x) >> 6);
    const int lane = threadIdx.x & 63;
    if (node >= N) return;
    const int beg = rowptr[node], end = rowptr[node + 1];
    const float inv = 1.0f / (float)max(end - beg, 1);
    const int co = 2 * lane;

    float s0 = 0.f, s1 = 0.f, s2 = 0.f, s3 = 0.f;
    float h0 = 0.f, h1 = 0.f, h2 = 0.f, h3 = 0.f;
    if (lane < 14) {
        int j = beg;
        for (; j + 4 <= end; j += 4) {
            const unsigned u0 = *(const unsigned*)(p + (size_t)csr[j]     * 32 + co);
            const unsigned u1 = *(const unsigned*)(p + (size_t)csr[j + 1] * 32 + co);
            const unsigned u2 = *(const unsigned*)(p + (size_t)csr[j + 2] * 32 + co);
            const unsigned u3 = *(const unsigned*)(p + (size_t)csr[j + 3] * 32 + co);
            s0 += bf2f(u0 & 0xffffu); h0 += bf2f(u0 >> 16);
            s1 += bf2f(u1 & 0xffffu); h1 += bf2f(u1 >> 16);
            s2 += bf2f(u2 & 0xffffu); h2 += bf2f(u2 >> 16);
            s3 += bf2f(u3 & 0xffffu); h3 += bf2f(u3 >> 16);
        }
        for (; j < end; ++j) {
            const unsigned u0 = *(const unsigned*)(p + (size_t)csr[j] * 32 + co);
            s0 += bf2f(u0 & 0xffffu); h0 += bf2f(u0 >> 16);
        }
    }
    float xlo = 0.f, xhi = 0.f, wl0 = 0.f, wl1 = 0.f, wr0 = 0.f, wr1 = 0.f;
    if (lane < 14) {
        xlo = bf2f((unsigned)acc[(size_t)node * 32 + co])     + inv * ((s0 + s1) + (s2 + s3));
        xhi = bf2f((unsigned)acc[(size_t)node * 32 + co + 1]) + inv * ((h0 + h1) + (h2 + h3));
        wl0 = Wl3[co]; wl1 = Wl3[co + 1];
        wr0 = Wr3[co]; wr1 = Wr3[co + 1];
    }
    float sl = xlo * wl0 + xhi * wl1;
    float sr = xlo * wr0 + xhi * wr1;
#pragma unroll
    for (int off = 32; off > 0; off >>= 1) {
        sl += __shfl_xor(sl, off, 64);
        sr += __shfl_xor(sr, off, 64);
    }
    if (lane == 0) {
        p3[node] = sl;
        out[node] = sr + bl3[0];
    }
}

__global__ void gather1_kernel(const int* __restrict__ rowptr, const int* __restrict__ csr,
                               const float* __restrict__ p, float* __restrict__ out, int N) {
    const int node = blockIdx.x * blockDim.x + threadIdx.x;
    if (node >= N) return;
    const int beg = rowptr[node], end = rowptr[node + 1];
    const float inv = 1.0f / (float)max(end - beg, 1);
    float a0 = 0.f, a1 = 0.f, a2 = 0.f, a3 = 0.f;
    int j = beg;
    for (; j + 4 <= end; j += 4) {
        a0 += p[csr[j]]; a1 += p[csr[j + 1]]; a2 += p[csr[j + 2]]; a3 += p[csr[j + 3]];
    }
    for (; j < end; ++j) a0 += p[csr[j]];
    out[node] += inv * ((a0 + a1) + (a2 + a3));
}

// ---------------------------------------------------------------------------

extern "C" void kernel_launch(void* const* d_in, const int* in_sizes, int n_in,
                              void* d_out, int out_size, void* d_ws, size_t ws_size,
                              hipStream_t stream) {
    const float* x  = (const float*)d_in[0];
    const int*   ei = (const int*)d_in[1];
    const int N = NNODES;
    const int E = NEDGES;
    const int* esrc = ei;
    const int* edst = ei + E;

    const float* Wl[4] = {(const float*)d_in[2], (const float*)d_in[5],
                          (const float*)d_in[8], (const float*)d_in[11]};
    const float* bl[4] = {(const float*)d_in[3], (const float*)d_in[6],
                          (const float*)d_in[9], (const float*)d_in[12]};
    const float* Wr[4] = {(const float*)d_in[4], (const float*)d_in[7],
                          (const float*)d_in[10], (const float*)d_in[13]};

    // ---- workspace arena (byte offsets, 256B aligned) ----
    char* base = (char*)d_ws;
    size_t off = 0;
    auto alloc = [&](size_t bytes) {
        char* r = base + off;
        off += (bytes + 255) & ~(size_t)255;
        return r;
    };
    unsigned short* pB   = (unsigned short*)alloc((size_t)N * 96 * 2);  // p bf16, stride 96/64/32
    unsigned short* accB = (unsigned short*)alloc((size_t)N * 96 * 2);  // acc bf16, stride 96/64/32
    unsigned short* xp   = (unsigned short*)alloc((size_t)N * 96 * 2);  // x1 (stride 96); reused as x2 (stride 64)
    float*          p3   = (float*)alloc((size_t)N * 4);
    unsigned short* Wc0  = (unsigned short*)alloc((size_t)192 * 128 * 2);
    unsigned short* Wc1  = (unsigned short*)alloc((size_t)128 * 96 * 2);
    unsigned short* Wc2  = (unsigned short*)alloc((size_t)64 * 64 * 2);
    int* degi   = (int*)alloc((size_t)N * 4);
    int* rowptr = (int*)alloc((size_t)(N + 1) * 4);
    int* cursor = (int*)alloc((size_t)N * 4);
    int* csr    = (int*)alloc((size_t)E * 4);
    int* bsum   = (int*)alloc(512 * 4);
    int* bpre   = (int*)alloc(512 * 4);

    unsigned short* x2 = xp;   // x1 dead after L1 proj; reuse region for x2

    const int nb = (N + 255) / 256;  // 391

    // CSR build
    hipMemsetAsync(degi, 0, (size_t)N * sizeof(int), stream);
    hist_kernel<<<(E + 255) / 256, 256, 0, stream>>>(edst, degi, E);
    scanA_kernel<<<nb, 256, 0, stream>>>(degi, bsum, N);
    scanB_kernel<<<1, 512, 0, stream>>>(bsum, bpre, nb);
    scanC_kernel<<<nb, 256, 0, stream>>>(degi, bpre, rowptr, cursor, N, E);
    fill_kernel<<<(E + 255) / 256, 256, 0, stream>>>(esrc, edst, cursor, csr, E);

    // weight packs (transposed, bf16, zero-padded, no straddle), one dispatch
    const int packTot = 192 * 128 + 128 * 96 + 64 * 64;
    packAll_kernel<<<(packTot + 255) / 256, 256, 0, stream>>>(
        Wl[0], Wr[0], Wl[1], Wr[1], Wl[2], Wr[2], Wc0, Wc1, Wc2);

    const int projBlocks = (N + 127) / 128;  // 782 (4 waves x 32 rows)

    // Layer 0: K=128 fp32 input, 12 tiles (6 p + 6 acc); p/acc stride 96
    projm_kernel<true, 128, 128, 12, 85, 96><<<projBlocks, 256, 0, stream>>>(
        x, Wc0, bl[0], pB, accB, N);
    gatherb_kernel<85, 96, 96><<<(N + 3) / 4, 256, 0, stream>>>(
        rowptr, csr, pB, accB, xp, N);

    // Layer 1: K=96 (85 zero-padded), 8 tiles (4+4); p/acc stride 64
    projm_kernel<false, 96, 96, 8, 56, 64><<<projBlocks, 256, 0, stream>>>(
        xp, Wc1, bl[1], pB, accB, N);
    gatherb_kernel<56, 64, 64><<<(N + 3) / 4, 256, 0, stream>>>(
        rowptr, csr, pB, accB, x2, N);

    // Layer 2: K=64 (56 zero-padded), 4 tiles (2+2); p/acc stride 32
    projm_kernel<false, 64, 64, 4, 28, 32><<<projBlocks, 256, 0, stream>>>(
        x2, Wc2, bl[2], pB, accB, N);

    // Layer-2 gather + layer-3 GEMV fused; then scalar gather for layer 3
    gather2g_kernel<<<(N + 3) / 4, 256, 0, stream>>>(
        rowptr, csr, pB, accB, Wl[3], bl[3], Wr[3], p3, (float*)d_out, N);
    gather1_kernel<<<(N + 255) / 256, 256, 0, stream>>>(
        rowptr, csr, p3, (float*)d_out, N);
}

// Round 12
// 233.931 us; speedup vs baseline: 52.1590x; 1.0898x over previous
//
#include <hip/hip_runtime.h>

// ---------------------------------------------------------------------------
// SageCox: 4-layer GraphSAGE (mean aggr), N=100000, E=640000.
// out = mean_neigh(x)@Wl + bl + x@Wr per layer.
// Restructured: p = x@Wl ; acc = bf16(x@Wr + bl) ; x_next = bf16(acc + invdeg*sum p[src]).
// proj = MFMA bf16 (16x16x32, f32 accum). Per-PHASE weight staging in LDS
// (26KB) + 27KB out tile -> 53KB total -> 3 blocks/CU. Phase A = Wl tiles
// -> p; phase B = Wr tiles (+bias) -> acc; phase-B staging overlaps phase-A
// store. Coalesced bf16x8 epilogue stores.
// Gather: CSR, paired-uint column loads, 4-edge unroll; L1/L2 pack 2 nodes
// per wave (halves independent) to fill lanes; L0 (43 pairs) 1 node/wave.
// p/acc/xnext rows padded to 96/64/32 elems (whole 128B lines).
// Layer-3 GEMV fused into layer-2 gather (half-wave shfl_xor reduce).
// ---------------------------------------------------------------------------

#define NNODES 100000
#define NEDGES 640000

using bf16x8 = __attribute__((ext_vector_type(8))) short;
using f32x4  = __attribute__((ext_vector_type(4))) float;

__device__ __forceinline__ unsigned short f2bf(float f) {
    union { float f; unsigned u; } v; v.f = f;
    unsigned r = v.u + 0x7fffu + ((v.u >> 16) & 1u);
    return (unsigned short)(r >> 16);
}
__device__ __forceinline__ float bf2f(unsigned b) {
    union { unsigned u; float f; } v; v.u = b << 16;
    return v.f;
}

// ---- CSR build ------------------------------------------------------------

__global__ void hist_kernel(const int* __restrict__ edst, int* __restrict__ deg, int E) {
    int i = blockIdx.x * blockDim.x + threadIdx.x;
    if (i < E) atomicAdd(&deg[edst[i]], 1);
}

__global__ void scanA_kernel(const int* __restrict__ deg, int* __restrict__ bsum, int N) {
    __shared__ int s[256];
    int i = blockIdx.x * 256 + threadIdx.x;
    s[threadIdx.x] = (i < N) ? deg[i] : 0;
    __syncthreads();
    for (int off = 128; off > 0; off >>= 1) {
        if (threadIdx.x < off) s[threadIdx.x] += s[threadIdx.x + off];
        __syncthreads();
    }
    if (threadIdx.x == 0) bsum[blockIdx.x] = s[0];
}

__global__ void scanB_kernel(const int* __restrict__ bsum, int* __restrict__ bpre, int nb) {
    __shared__ int s[512];
    int t = threadIdx.x;
    int v = (t < nb) ? bsum[t] : 0;
    s[t] = v;
    __syncthreads();
    for (int off = 1; off < 512; off <<= 1) {
        int add = (t >= off) ? s[t - off] : 0;
        __syncthreads();
        s[t] += add;
        __syncthreads();
    }
    if (t < nb) bpre[t] = s[t] - v;  // exclusive
}

__global__ void scanC_kernel(const int* __restrict__ deg, const int* __restrict__ bpre,
                             int* __restrict__ rowptr, int* __restrict__ cursor, int N, int E) {
    __shared__ int s[256];
    int t = threadIdx.x;
    int i = blockIdx.x * 256 + t;
    int v = (i < N) ? deg[i] : 0;
    s[t] = v;
    __syncthreads();
    for (int off = 1; off < 256; off <<= 1) {
        int add = (t >= off) ? s[t - off] : 0;
        __syncthreads();
        s[t] += add;
        __syncthreads();
    }
    if (i < N) {
        int excl = bpre[blockIdx.x] + s[t] - v;
        rowptr[i] = excl;
        cursor[i] = excl;
        if (i == N - 1) rowptr[N] = E;
    }
}

__global__ void fill_kernel(const int* __restrict__ esrc, const int* __restrict__ edst,
                            int* __restrict__ cursor, int* __restrict__ csr, int E) {
    int i = blockIdx.x * blockDim.x + threadIdx.x;
    if (i < E) {
        int pos = atomicAdd(&cursor[edst[i]], 1);
        csr[pos] = esrc[i];
    }
}

// ---- merged weight pack: WcT[c][k] bf16, no straddle ----------------------
// c < DOUT -> Wl ; DOUTP <= c < DOUTP+DOUT -> Wr ; else 0.

__device__ __forceinline__ void packT_one(const float* Wl, const float* Wr,
                                          unsigned short* WcT, int idx, int DIN,
                                          int KP, int DOUT, int DOUTP) {
    int c = idx / KP, k = idx - c * KP;
    float v = 0.0f;
    if (k < DIN) {
        if (c < DOUT) v = Wl[k * DOUT + c];
        else if (c >= DOUTP && c < DOUTP + DOUT) v = Wr[k * DOUT + (c - DOUTP)];
    }
    WcT[idx] = f2bf(v);
}

__global__ void packAll_kernel(const float* __restrict__ Wl0, const float* __restrict__ Wr0,
                               const float* __restrict__ Wl1, const float* __restrict__ Wr1,
                               const float* __restrict__ Wl2, const float* __restrict__ Wr2,
                               unsigned short* __restrict__ Wc0,
                               unsigned short* __restrict__ Wc1,
                               unsigned short* __restrict__ Wc2) {
    const int S0 = 192 * 128, S1 = 128 * 96, S2 = 64 * 64;
    int idx = blockIdx.x * blockDim.x + threadIdx.x;
    if (idx < S0) packT_one(Wl0, Wr0, Wc0, idx, 128, 128, 85, 96);
    else if (idx < S0 + S1) packT_one(Wl1, Wr1, Wc1, idx - S0, 85, 96, 56, 64);
    else if (idx < S0 + S1 + S2) packT_one(Wl2, Wr2, Wc2, idx - S0 - S1, 56, 64, 28, 32);
}

// ---- MFMA projection: per-phase W in LDS + 2-phase coalesced epilogue -----
// block = 4 waves x 32 rows = 128 rows. NTILES even; HT = NTILES/2 tiles per
// phase. Phase A = pack cols [0,HT*16) -> p; phase B = cols [HT*16,NTILES*16)
// (+bias) -> acc. Phase-B staging overlaps phase-A store (disjoint LDS).
// D layout: row = rowbase+(lane>>4)*4+j, col(within phase) = nt*16+(lane&15).

template <bool XFP32, int KP, int SIN, int NTILES, int DOUT, int SPP>
__global__ void __launch_bounds__(256)
projm_kernel(const void* __restrict__ xin,
             const unsigned short* __restrict__ WcT,
             const float* __restrict__ bl,
             unsigned short* __restrict__ p,
             unsigned short* __restrict__ acc_out, int N) {
    constexpr int KT   = KP / 32;
    constexpr int HT   = NTILES / 2;
    constexpr int WSTR = KP + 8;           // W LDS row stride (16B-mult *2B)
    constexpr int LSTR = SPP + 8;          // out LDS row stride
    static_assert(HT * 16 == SPP, "phase width must equal SPP");
    __shared__ short wS[HT * 16 * WSTR];
    __shared__ short oS[128 * LSTR];

    const int lane = threadIdx.x & 63;
    const int wave = threadIdx.x >> 6;
    const int l15 = lane & 15;
    const int lk  = lane >> 4;
    const int row0 = blockIdx.x * 128;
    const int wrow = wave * 32;

    auto stageW = [&](int colbase) {
        for (int c8 = threadIdx.x; c8 < HT * 16 * (KP / 8); c8 += 256) {
            const int c  = c8 / (KP / 8);
            const int k8 = c8 - c * (KP / 8);
            *(bf16x8*)(wS + c * WSTR + k8 * 8) =
                *(const bf16x8*)(WcT + (size_t)(colbase + c) * KP + k8 * 8);
        }
    };

    // stage phase-A weights; A-fragment global loads overlap
    stageW(0);

    bf16x8 afrag[2][KT];
#pragma unroll
    for (int h = 0; h < 2; ++h) {
        int arow = row0 + wrow + h * 16 + l15;
        if (arow >= N) arow = N - 1;       // clamp; rows >= N never stored
        if constexpr (XFP32) {
            const float* xr = (const float*)xin + (size_t)arow * SIN + lk * 8;
#pragma unroll
            for (int kt = 0; kt < KT; ++kt) {
                const float4 a = *(const float4*)(xr + kt * 32);
                const float4 b = *(const float4*)(xr + kt * 32 + 4);
                bf16x8 v;
                v[0] = (short)f2bf(a.x); v[1] = (short)f2bf(a.y);
                v[2] = (short)f2bf(a.z); v[3] = (short)f2bf(a.w);
                v[4] = (short)f2bf(b.x); v[5] = (short)f2bf(b.y);
                v[6] = (short)f2bf(b.z); v[7] = (short)f2bf(b.w);
                afrag[h][kt] = v;
            }
        } else {
            const unsigned short* xr = (const unsigned short*)xin + (size_t)arow * SIN + lk * 8;
#pragma unroll
            for (int kt = 0; kt < KT; ++kt)
                afrag[h][kt] = *(const bf16x8*)(xr + kt * 32);
        }
    }

    __syncthreads();

    const int rows_here = min(128, N - row0);
    const int cnt8 = rows_here * (SPP / 8);

    auto computePhase = [&](bool withBias) {
#pragma unroll 2
        for (int nt = 0; nt < HT; ++nt) {
            const short* wp = wS + (size_t)(nt * 16 + l15) * WSTR + lk * 8;
            bf16x8 bfrag[KT];
#pragma unroll
            for (int kt = 0; kt < KT; ++kt)
                bfrag[kt] = *(const bf16x8*)(wp + kt * 32);

            f32x4 a0 = {0.f, 0.f, 0.f, 0.f};
            f32x4 a1 = {0.f, 0.f, 0.f, 0.f};
#pragma unroll
            for (int kt = 0; kt < KT; ++kt) {
                a0 = __builtin_amdgcn_mfma_f32_16x16x32_bf16(afrag[0][kt], bfrag[kt], a0, 0, 0, 0);
                a1 = __builtin_amdgcn_mfma_f32_16x16x32_bf16(afrag[1][kt], bfrag[kt], a1, 0, 0, 0);
            }

            const int co = nt * 16 + l15;
            const float bias = (withBias && co < DOUT) ? bl[co] : 0.0f;
#pragma unroll
            for (int h = 0; h < 2; ++h) {
                const f32x4 a = h ? a1 : a0;
                const int rl = wrow + h * 16 + lk * 4;
#pragma unroll
                for (int j = 0; j < 4; ++j)
                    oS[(rl + j) * LSTR + co] = (short)f2bf(a[j] + bias);
            }
        }
    };

    auto storeOut = [&](unsigned short* dst) {
        for (int e8 = threadIdx.x; e8 < cnt8; e8 += 256) {
            const int row = e8 / (SPP / 8);
            const int c8  = e8 - row * (SPP / 8);
            *(bf16x8*)(dst + (size_t)row0 * SPP + (size_t)e8 * 8) =
                *(const bf16x8*)(oS + row * LSTR + c8 * 8);
        }
    };

    // phase A
    computePhase(false);
    __syncthreads();
    storeOut(p);        // reads oS
    stageW(HT * 16);    // writes wS (disjoint) — overlaps store
    __syncthreads();
    // phase B
    computePhase(true);
    __syncthreads();
    storeOut(acc_out);
}

// ---- gather: x_next = bf16(acc + invdeg * sum p[src]) ---------------------
// NPW nodes per wave (1 or 2). NPW=2: lanes 0-31 node A, 32-63 node B.

template <int DOUT, int SP, int SN, int NPW>
__global__ void __launch_bounds__(256)
gatherb_kernel(const int* __restrict__ rowptr, const int* __restrict__ csr,
               const unsigned short* __restrict__ p, const unsigned short* __restrict__ acc,
               unsigned short* __restrict__ xnext, int N) {
    const int wid  = (blockIdx.x * 256 + threadIdx.x) >> 6;
    const int lane = threadIdx.x & 63;
    int node, hl;
    if constexpr (NPW == 1) {
        node = __builtin_amdgcn_readfirstlane(wid);
        hl = lane;
    } else {
        node = wid * 2 + (lane >> 5);
        hl = lane & 31;
    }
    if (node >= N) return;
    const int beg = rowptr[node], end = rowptr[node + 1];
    const float inv = 1.0f / (float)max(end - beg, 1);
    constexpr int NPAIR = (DOUT + 1) / 2;
    const int co = 2 * hl;

    float s0 = 0.f, s1 = 0.f, s2 = 0.f, s3 = 0.f;
    float h0 = 0.f, h1 = 0.f, h2 = 0.f, h3 = 0.f;
    if (hl < NPAIR) {
        int j = beg;
        for (; j + 4 <= end; j += 4) {
            const unsigned u0 = *(const unsigned*)(p + (size_t)csr[j]     * SP + co);
            const unsigned u1 = *(const unsigned*)(p + (size_t)csr[j + 1] * SP + co);
            const unsigned u2 = *(const unsigned*)(p + (size_t)csr[j + 2] * SP + co);
            const unsigned u3 = *(const unsigned*)(p + (size_t)csr[j + 3] * SP + co);
            s0 += bf2f(u0 & 0xffffu); h0 += bf2f(u0 >> 16);
            s1 += bf2f(u1 & 0xffffu); h1 += bf2f(u1 >> 16);
            s2 += bf2f(u2 & 0xffffu); h2 += bf2f(u2 >> 16);
            s3 += bf2f(u3 & 0xffffu); h3 += bf2f(u3 >> 16);
        }
        for (; j < end; ++j) {
            const unsigned u0 = *(const unsigned*)(p + (size_t)csr[j] * SP + co);
            s0 += bf2f(u0 & 0xffffu); h0 += bf2f(u0 >> 16);
        }
    }
    if (co < SN) {
        const float slo = (s0 + s1) + (s2 + s3);
        const float shi = (h0 + h1) + (h2 + h3);
        float lo = 0.f, hi = 0.f;
        if (co < DOUT)     lo = bf2f((unsigned)acc[(size_t)node * SP + co])     + inv * slo;
        if (co + 1 < DOUT) hi = bf2f((unsigned)acc[(size_t)node * SP + co + 1]) + inv * shi;
        const unsigned w = (unsigned)f2bf(lo) | ((unsigned)f2bf(hi) << 16);
        *(unsigned*)(xnext + (size_t)node * SN + co) = w;
    }
}

// ---- layer-2 gather fused with layer-3 GEMV (28 -> 1), 2 nodes/wave -------

__global__ void __launch_bounds__(256)
gather2g_kernel(const int* __restrict__ rowptr, const int* __restrict__ csr,
                const unsigned short* __restrict__ p, const unsigned short* __restrict__ acc,
                const float* __restrict__ Wl3, const float* __restrict__ bl3,
                const float* __restrict__ Wr3,
                float* __restrict__ p3, float* __restrict__ out, int N) {
    const int wid  = (blockIdx.x * 256 + threadIdx.x) >> 6;
    const int lane = threadIdx.x & 63;
    const int node = wid * 2 + (lane >> 5);
    const int hl   = lane & 31;
    if (node >= N) return;
    const int beg = rowptr[node], end = rowptr[node + 1];
    const float inv = 1.0f / (float)max(end - beg, 1);
    const int co = 2 * hl;

    float s0 = 0.f, s1 = 0.f, s2 = 0.f, s3 = 0.f;
    float h0 = 0.f, h1 = 0.f, h2 = 0.f, h3 = 0.f;
    if (hl < 14) {
        int j = beg;
        for (; j + 4 <= end; j += 4) {
            const unsigned u0 = *(const unsigned*)(p + (size_t)csr[j]     * 32 + co);
            const unsigned u1 = *(const unsigned*)(p + (size_t)csr[j + 1] * 32 + co);
            const unsigned u2 = *(const unsigned*)(p + (size_t)csr[j + 2] * 32 + co);
            const unsigned u3 = *(const unsigned*)(p + (size_t)csr[j + 3] * 32 + co);
            s0 += bf2f(u0 & 0xffffu); h0 += bf2f(u0 >> 16);
            s1 += bf2f(u1 & 0xffffu); h1 += bf2f(u1 >> 16);
            s2 += bf2f(u2 & 0xffffu); h2 += bf2f(u2 >> 16);
            s3 += bf2f(u3 & 0xffffu); h3 += bf2f(u3 >> 16);
        }
        for (; j < end; ++j) {
            const unsigned u0 = *(const unsigned*)(p + (size_t)csr[j] * 32 + co);
            s0 += bf2f(u0 & 0xffffu); h0 += bf2f(u0 >> 16);
        }
    }
    float xlo = 0.f, xhi = 0.f, wl0 = 0.f, wl1 = 0.f, wr0 = 0.f, wr1 = 0.f;
    if (hl < 14) {
        xlo = bf2f((unsigned)acc[(size_t)node * 32 + co])     + inv * ((s0 + s1) + (s2 + s3));
        xhi = bf2f((unsigned)acc[(size_t)node * 32 + co + 1]) + inv * ((h0 + h1) + (h2 + h3));
        wl0 = Wl3[co]; wl1 = Wl3[co + 1];
        wr0 = Wr3[co]; wr1 = Wr3[co + 1];
    }
    float sl = xlo * wl0 + xhi * wl1;
    float sr = xlo * wr0 + xhi * wr1;
#pragma unroll
    for (int off = 16; off > 0; off >>= 1) {     // half-wave reduce
        sl += __shfl_xor(sl, off, 64);
        sr += __shfl_xor(sr, off, 64);
    }
    if (hl == 0) {
        p3[node] = sl;
        out[node] = sr + bl3[0];
    }
}

__global__ void gather1_kernel(const int* __restrict__ rowptr, const int* __restrict__ csr,
                               const float* __restrict__ p, float* __restrict__ out, int N) {
    const int node = blockIdx.x * blockDim.x + threadIdx.x;
    if (node >= N) return;
    const int beg = rowptr[node], end = rowptr[node + 1];
    const float inv = 1.0f / (float)max(end - beg, 1);
    float a0 = 0.f, a1 = 0.f, a2 = 0.f, a3 = 0.f;
    int j = beg;
    for (; j + 4 <= end; j += 4) {
        a0 += p[csr[j]]; a1 += p[csr[j + 1]]; a2 += p[csr[j + 2]]; a3 += p[csr[j + 3]];
    }
    for (; j < end; ++j) a0 += p[csr[j]];
    out[node] += inv * ((a0 + a1) + (a2 + a3));
}

// ---------------------------------------------------------------------------

extern "C" void kernel_launch(void* const* d_in, const int* in_sizes, int n_in,
                              void* d_out, int out_size, void* d_ws, size_t ws_size,
                              hipStream_t stream) {
    const float* x  = (const float*)d_in[0];
    const int*   ei = (const int*)d_in[1];
    const int N = NNODES;
    const int E = NEDGES;
    const int* esrc = ei;
    const int* edst = ei + E;

    const float* Wl[4] = {(const float*)d_in[2], (const float*)d_in[5],
                          (const float*)d_in[8], (const float*)d_in[11]};
    const float* bl[4] = {(const float*)d_in[3], (const float*)d_in[6],
                          (const float*)d_in[9], (const float*)d_in[12]};
    const float* Wr[4] = {(const float*)d_in[4], (const float*)d_in[7],
                          (const float*)d_in[10], (const float*)d_in[13]};

    // ---- workspace arena (byte offsets, 256B aligned) ----
    char* base = (char*)d_ws;
    size_t off = 0;
    auto alloc = [&](size_t bytes) {
        char* r = base + off;
        off += (bytes + 255) & ~(size_t)255;
        return r;
    };
    unsigned short* pB   = (unsigned short*)alloc((size_t)N * 96 * 2);  // p bf16, stride 96/64/32
    unsigned short* accB = (unsigned short*)alloc((size_t)N * 96 * 2);  // acc bf16, stride 96/64/32
    unsigned short* xp   = (unsigned short*)alloc((size_t)N * 96 * 2);  // x1 (stride 96); reused as x2 (stride 64)
    float*          p3   = (float*)alloc((size_t)N * 4);
    unsigned short* Wc0  = (unsigned short*)alloc((size_t)192 * 128 * 2);
    unsigned short* Wc1  = (unsigned short*)alloc((size_t)128 * 96 * 2);
    unsigned short* Wc2  = (unsigned short*)alloc((size_t)64 * 64 * 2);
    int* degi   = (int*)alloc((size_t)N * 4);
    int* rowptr = (int*)alloc((size_t)(N + 1) * 4);
    int* cursor = (int*)alloc((size_t)N * 4);
    int* csr    = (int*)alloc((size_t)E * 4);
    int* bsum   = (int*)alloc(512 * 4);
    int* bpre   = (int*)alloc(512 * 4);

    unsigned short* x2 = xp;   // x1 dead after L1 proj; reuse region for x2

    const int nb = (N + 255) / 256;  // 391

    // CSR build
    hipMemsetAsync(degi, 0, (size_t)N * sizeof(int), stream);
    hist_kernel<<<(E + 255) / 256, 256, 0, stream>>>(edst, degi, E);
    scanA_kernel<<<nb, 256, 0, stream>>>(degi, bsum, N);
    scanB_kernel<<<1, 512, 0, stream>>>(bsum, bpre, nb);
    scanC_kernel<<<nb, 256, 0, stream>>>(degi, bpre, rowptr, cursor, N, E);
    fill_kernel<<<(E + 255) / 256, 256, 0, stream>>>(esrc, edst, cursor, csr, E);

    // weight packs (transposed, bf16, zero-padded, no straddle), one dispatch
    const int packTot = 192 * 128 + 128 * 96 + 64 * 64;
    packAll_kernel<<<(packTot + 255) / 256, 256, 0, stream>>>(
        Wl[0], Wr[0], Wl[1], Wr[1], Wl[2], Wr[2], Wc0, Wc1, Wc2);

    const int projBlocks = (N + 127) / 128;  // 782 (4 waves x 32 rows)

    // Layer 0: K=128 fp32 input, 12 tiles (6 p + 6 acc); p/acc stride 96
    projm_kernel<true, 128, 128, 12, 85, 96><<<projBlocks, 256, 0, stream>>>(
        x, Wc0, bl[0], pB, accB, N);
    gatherb_kernel<85, 96, 96, 1><<<(N + 3) / 4, 256, 0, stream>>>(
        rowptr, csr, pB, accB, xp, N);

    // Layer 1: K=96 (85 zero-padded), 8 tiles (4+4); p/acc stride 64
    projm_kernel<false, 96, 96, 8, 56, 64><<<projBlocks, 256, 0, stream>>>(
        xp, Wc1, bl[1], pB, accB, N);
    gatherb_kernel<56, 64, 64, 2><<<(N + 7) / 8, 256, 0, stream>>>(
        rowptr, csr, pB, accB, x2, N);

    // Layer 2: K=64 (56 zero-padded), 4 tiles (2+2); p/acc stride 32
    projm_kernel<false, 64, 64, 4, 28, 32><<<projBlocks, 256, 0, stream>>>(
        x2, Wc2, bl[2], pB, accB, N);

    // Layer-2 gather + layer-3 GEMV fused (2 nodes/wave); then scalar gather
    gather2g_kernel<<<(N + 7) / 8, 256, 0, stream>>>(
        rowptr, csr, pB, accB, Wl[3], bl[3], Wr[3], p3, (float*)d_out, N);
    gather1_kernel<<<(N + 255) / 256, 256, 0, stream>>>(
        rowptr, csr, p3, (float*)d_out, N);
}

// Round 13
// 222.105 us; speedup vs baseline: 54.9361x; 1.0532x over previous
//
#include <hip/hip_runtime.h>

// ---------------------------------------------------------------------------
// SageCox: 4-layer GraphSAGE (mean aggr), N=100000, E=640000.
// out = mean_neigh(x)@Wl + bl + x@Wr per layer.
// Restructured: p = x@Wl ; acc = bf16(x@Wr + bl) ; x_next = bf16(acc + invdeg*sum p[src]).
// proj = MFMA bf16 (16x16x32, f32 accum), per-phase W staging in LDS, 2-phase
// coalesced bf16x8 epilogue. Gather: CSR, paired-uint loads, 4-edge unroll,
// L1 2 nodes/wave. CSR fill is XCD-PARTITIONED: block bid%8 handles dst range
// bid%8 only (heuristic bid%8==XCD), so each csr/cursor region stays in one
// L2 -> writebacks collapse (was 39MB for a 2.56MB array). scanB folded into
// scanC; hist fused with packAll (block-split). 12 dispatches.
// ---------------------------------------------------------------------------

#define NNODES 100000
#define NEDGES 640000

using bf16x8 = __attribute__((ext_vector_type(8))) short;
using f32x4  = __attribute__((ext_vector_type(4))) float;

__device__ __forceinline__ unsigned short f2bf(float f) {
    union { float f; unsigned u; } v; v.f = f;
    unsigned r = v.u + 0x7fffu + ((v.u >> 16) & 1u);
    return (unsigned short)(r >> 16);
}
__device__ __forceinline__ float bf2f(unsigned b) {
    union { unsigned u; float f; } v; v.u = b << 16;
    return v.f;
}

// ---- weight pack helper ---------------------------------------------------

__device__ __forceinline__ void packT_one(const float* Wl, const float* Wr,
                                          unsigned short* WcT, int idx, int DIN,
                                          int KP, int DOUT, int DOUTP) {
    int c = idx / KP, k = idx - c * KP;
    float v = 0.0f;
    if (k < DIN) {
        if (c < DOUT) v = Wl[k * DOUT + c];
        else if (c >= DOUTP && c < DOUTP + DOUT) v = Wr[k * DOUT + (c - DOUTP)];
    }
    WcT[idx] = f2bf(v);
}

// ---- fused: packAll (blocks [0,PACKB)) || hist (rest) ---------------------

#define PACKB 160

__global__ void packhist_kernel(const float* __restrict__ Wl0, const float* __restrict__ Wr0,
                                const float* __restrict__ Wl1, const float* __restrict__ Wr1,
                                const float* __restrict__ Wl2, const float* __restrict__ Wr2,
                                unsigned short* __restrict__ Wc0,
                                unsigned short* __restrict__ Wc1,
                                unsigned short* __restrict__ Wc2,
                                const int* __restrict__ edst, int* __restrict__ deg, int E) {
    const int S0 = 192 * 128, S1 = 128 * 96, S2 = 64 * 64;
    if (blockIdx.x < PACKB) {
        int idx = blockIdx.x * 256 + threadIdx.x;
        if (idx < S0) packT_one(Wl0, Wr0, Wc0, idx, 128, 128, 85, 96);
        else if (idx < S0 + S1) packT_one(Wl1, Wr1, Wc1, idx - S0, 85, 96, 56, 64);
        else if (idx < S0 + S1 + S2) packT_one(Wl2, Wr2, Wc2, idx - S0 - S1, 56, 64, 28, 32);
    } else {
        int i = (blockIdx.x - PACKB) * 256 + threadIdx.x;
        if (i < E) atomicAdd(&deg[edst[i]], 1);
    }
}

// ---- scans ----------------------------------------------------------------

__global__ void scanA_kernel(const int* __restrict__ deg, int* __restrict__ bsum, int N) {
    __shared__ int s[256];
    int i = blockIdx.x * 256 + threadIdx.x;
    s[threadIdx.x] = (i < N) ? deg[i] : 0;
    __syncthreads();
    for (int off = 128; off > 0; off >>= 1) {
        if (threadIdx.x < off) s[threadIdx.x] += s[threadIdx.x + off];
        __syncthreads();
    }
    if (threadIdx.x == 0) bsum[blockIdx.x] = s[0];
}

// scanC with inlined block-prefix: each block sums bsum[0..blockIdx.x).
__global__ void scanC_kernel(const int* __restrict__ deg, const int* __restrict__ bsum,
                             int* __restrict__ rowptr, int* __restrict__ cursor, int N, int E) {
    __shared__ int s[256];
    int t = threadIdx.x;

    int a = 0;
    for (int j = t; j < blockIdx.x; j += 256) a += bsum[j];
    s[t] = a;
    __syncthreads();
    for (int off = 128; off > 0; off >>= 1) {
        if (t < off) s[t] += s[t + off];
        __syncthreads();
    }
    const int base = s[0];
    __syncthreads();

    int i = blockIdx.x * 256 + t;
    int v = (i < N) ? deg[i] : 0;
    s[t] = v;
    __syncthreads();
    for (int off = 1; off < 256; off <<= 1) {
        int add = (t >= off) ? s[t - off] : 0;
        __syncthreads();
        s[t] += add;
        __syncthreads();
    }
    if (i < N) {
        int excl = base + s[t] - v;
        rowptr[i] = excl;
        cursor[i] = excl;
        if (i == N - 1) rowptr[N] = E;
    }
}

// ---- XCD-partitioned CSR fill ---------------------------------------------
// Partition p = bid%8 owns dst range [p*N/8, ...); its sub-blocks grid-stride
// the full edge list and filter. Heuristic bid%8==XCD keeps each csr/cursor
// region in one L2 (correctness does not depend on the mapping).

__global__ void fillp_kernel(const int* __restrict__ esrc, const int* __restrict__ edst,
                             int* __restrict__ cursor, int* __restrict__ csr, int E, int N) {
    const int part = blockIdx.x & 7;
    const int sub  = blockIdx.x >> 3;
    const int nsub = gridDim.x >> 3;
    const int chunk = N >> 3;                       // 12500
    const int lo = part * chunk;
    const int hi = (part == 7) ? N : lo + chunk;
    for (int i = sub * 256 + threadIdx.x; i < E; i += nsub * 256) {
        const int d = edst[i];
        if (d >= lo && d < hi) {
            int pos = atomicAdd(&cursor[d], 1);
            csr[pos] = esrc[i];
        }
    }
}

// ---- MFMA projection: per-phase W in LDS + 2-phase coalesced epilogue -----

template <bool XFP32, int KP, int SIN, int NTILES, int DOUT, int SPP>
__global__ void __launch_bounds__(256)
projm_kernel(const void* __restrict__ xin,
             const unsigned short* __restrict__ WcT,
             const float* __restrict__ bl,
             unsigned short* __restrict__ p,
             unsigned short* __restrict__ acc_out, int N) {
    constexpr int KT   = KP / 32;
    constexpr int HT   = NTILES / 2;
    constexpr int WSTR = KP + 8;
    constexpr int LSTR = SPP + 8;
    static_assert(HT * 16 == SPP, "phase width must equal SPP");
    __shared__ short wS[HT * 16 * WSTR];
    __shared__ short oS[128 * LSTR];

    const int lane = threadIdx.x & 63;
    const int wave = threadIdx.x >> 6;
    const int l15 = lane & 15;
    const int lk  = lane >> 4;
    const int row0 = blockIdx.x * 128;
    const int wrow = wave * 32;

    auto stageW = [&](int colbase) {
        for (int c8 = threadIdx.x; c8 < HT * 16 * (KP / 8); c8 += 256) {
            const int c  = c8 / (KP / 8);
            const int k8 = c8 - c * (KP / 8);
            *(bf16x8*)(wS + c * WSTR + k8 * 8) =
                *(const bf16x8*)(WcT + (size_t)(colbase + c) * KP + k8 * 8);
        }
    };

    stageW(0);

    bf16x8 afrag[2][KT];
#pragma unroll
    for (int h = 0; h < 2; ++h) {
        int arow = row0 + wrow + h * 16 + l15;
        if (arow >= N) arow = N - 1;
        if constexpr (XFP32) {
            const float* xr = (const float*)xin + (size_t)arow * SIN + lk * 8;
#pragma unroll
            for (int kt = 0; kt < KT; ++kt) {
                const float4 a = *(const float4*)(xr + kt * 32);
                const float4 b = *(const float4*)(xr + kt * 32 + 4);
                bf16x8 v;
                v[0] = (short)f2bf(a.x); v[1] = (short)f2bf(a.y);
                v[2] = (short)f2bf(a.z); v[3] = (short)f2bf(a.w);
                v[4] = (short)f2bf(b.x); v[5] = (short)f2bf(b.y);
                v[6] = (short)f2bf(b.z); v[7] = (short)f2bf(b.w);
                afrag[h][kt] = v;
            }
        } else {
            const unsigned short* xr = (const unsigned short*)xin + (size_t)arow * SIN + lk * 8;
#pragma unroll
            for (int kt = 0; kt < KT; ++kt)
                afrag[h][kt] = *(const bf16x8*)(xr + kt * 32);
        }
    }

    __syncthreads();

    const int rows_here = min(128, N - row0);
    const int cnt8 = rows_here * (SPP / 8);

    auto computePhase = [&](bool withBias) {
#pragma unroll 2
        for (int nt = 0; nt < HT; ++nt) {
            const short* wp = wS + (size_t)(nt * 16 + l15) * WSTR + lk * 8;
            bf16x8 bfrag[KT];
#pragma unroll
            for (int kt = 0; kt < KT; ++kt)
                bfrag[kt] = *(const bf16x8*)(wp + kt * 32);

            f32x4 a0 = {0.f, 0.f, 0.f, 0.f};
            f32x4 a1 = {0.f, 0.f, 0.f, 0.f};
#pragma unroll
            for (int kt = 0; kt < KT; ++kt) {
                a0 = __builtin_amdgcn_mfma_f32_16x16x32_bf16(afrag[0][kt], bfrag[kt], a0, 0, 0, 0);
                a1 = __builtin_amdgcn_mfma_f32_16x16x32_bf16(afrag[1][kt], bfrag[kt], a1, 0, 0, 0);
            }

            const int co = nt * 16 + l15;
            const float bias = (withBias && co < DOUT) ? bl[co] : 0.0f;
#pragma unroll
            for (int h = 0; h < 2; ++h) {
                const f32x4 a = h ? a1 : a0;
                const int rl = wrow + h * 16 + lk * 4;
#pragma unroll
                for (int j = 0; j < 4; ++j)
                    oS[(rl + j) * LSTR + co] = (short)f2bf(a[j] + bias);
            }
        }
    };

    auto storeOut = [&](unsigned short* dst) {
        for (int e8 = threadIdx.x; e8 < cnt8; e8 += 256) {
            const int row = e8 / (SPP / 8);
            const int c8  = e8 - row * (SPP / 8);
            *(bf16x8*)(dst + (size_t)row0 * SPP + (size_t)e8 * 8) =
                *(const bf16x8*)(oS + row * LSTR + c8 * 8);
        }
    };

    computePhase(false);
    __syncthreads();
    storeOut(p);
    stageW(HT * 16);
    __syncthreads();
    computePhase(true);
    __syncthreads();
    storeOut(acc_out);
}

// ---- gather: x_next = bf16(acc + invdeg * sum p[src]) ---------------------

template <int DOUT, int SP, int SN, int NPW>
__global__ void __launch_bounds__(256)
gatherb_kernel(const int* __restrict__ rowptr, const int* __restrict__ csr,
               const unsigned short* __restrict__ p, const unsigned short* __restrict__ acc,
               unsigned short* __restrict__ xnext, int N) {
    const int wid  = (blockIdx.x * 256 + threadIdx.x) >> 6;
    const int lane = threadIdx.x & 63;
    int node, hl;
    if constexpr (NPW == 1) {
        node = __builtin_amdgcn_readfirstlane(wid);
        hl = lane;
    } else {
        node = wid * 2 + (lane >> 5);
        hl = lane & 31;
    }
    if (node >= N) return;
    const int beg = rowptr[node], end = rowptr[node + 1];
    const float inv = 1.0f / (float)max(end - beg, 1);
    constexpr int NPAIR = (DOUT + 1) / 2;
    const int co = 2 * hl;

    float s0 = 0.f, s1 = 0.f, s2 = 0.f, s3 = 0.f;
    float h0 = 0.f, h1 = 0.f, h2 = 0.f, h3 = 0.f;
    if (hl < NPAIR) {
        int j = beg;
        for (; j + 4 <= end; j += 4) {
            const unsigned u0 = *(const unsigned*)(p + (size_t)csr[j]     * SP + co);
            const unsigned u1 = *(const unsigned*)(p + (size_t)csr[j + 1] * SP + co);
            const unsigned u2 = *(const unsigned*)(p + (size_t)csr[j + 2] * SP + co);
            const unsigned u3 = *(const unsigned*)(p + (size_t)csr[j + 3] * SP + co);
            s0 += bf2f(u0 & 0xffffu); h0 += bf2f(u0 >> 16);
            s1 += bf2f(u1 & 0xffffu); h1 += bf2f(u1 >> 16);
            s2 += bf2f(u2 & 0xffffu); h2 += bf2f(u2 >> 16);
            s3 += bf2f(u3 & 0xffffu); h3 += bf2f(u3 >> 16);
        }
        for (; j < end; ++j) {
            const unsigned u0 = *(const unsigned*)(p + (size_t)csr[j] * SP + co);
            s0 += bf2f(u0 & 0xffffu); h0 += bf2f(u0 >> 16);
        }
    }
    if (co < SN) {
        const float slo = (s0 + s1) + (s2 + s3);
        const float shi = (h0 + h1) + (h2 + h3);
        float lo = 0.f, hi = 0.f;
        if (co < DOUT)     lo = bf2f((unsigned)acc[(size_t)node * SP + co])     + inv * slo;
        if (co + 1 < DOUT) hi = bf2f((unsigned)acc[(size_t)node * SP + co + 1]) + inv * shi;
        const unsigned w = (unsigned)f2bf(lo) | ((unsigned)f2bf(hi) << 16);
        *(unsigned*)(xnext + (size_t)node * SN + co) = w;
    }
}

// ---- layer-2 gather fused with layer-3 GEMV (28 -> 1), 2 nodes/wave -------

__global__ void __launch_bounds__(256)
gather2g_kernel(const int* __restrict__ rowptr, const int* __restrict__ csr,
                const unsigned short* __restrict__ p, const unsigned short* __restrict__ acc,
                const float* __restrict__ Wl3, const float* __restrict__ bl3,
                const float* __restrict__ Wr3,
                float* __restrict__ p3, float* __restrict__ out, int N) {
    const int wid  = (blockIdx.x * 256 + threadIdx.x) >> 6;
    const int lane = threadIdx.x & 63;
    const int node = wid * 2 + (lane >> 5);
    const int hl   = lane & 31;
    if (node >= N) return;
    const int beg = rowptr[node], end = rowptr[node + 1];
    const float inv = 1.0f / (float)max(end - beg, 1);
    const int co = 2 * hl;

    float s0 = 0.f, s1 = 0.f, s2 = 0.f, s3 = 0.f;
    float h0 = 0.f, h1 = 0.f, h2 = 0.f, h3 = 0.f;
    if (hl < 14) {
        int j = beg;
        for (; j + 4 <= end; j += 4) {
            const unsigned u0 = *(const unsigned*)(p + (size_t)csr[j]     * 32 + co);
            const unsigned u1 = *(const unsigned*)(p + (size_t)csr[j + 1] * 32 + co);
            const unsigned u2 = *(const unsigned*)(p + (size_t)csr[j + 2] * 32 + co);
            const unsigned u3 = *(const unsigned*)(p + (size_t)csr[j + 3] * 32 + co);
            s0 += bf2f(u0 & 0xffffu); h0 += bf2f(u0 >> 16);
            s1 += bf2f(u1 & 0xffffu); h1 += bf2f(u1 >> 16);
            s2 += bf2f(u2 & 0xffffu); h2 += bf2f(u2 >> 16);
            s3 += bf2f(u3 & 0xffffu); h3 += bf2f(u3 >> 16);
        }
        for (; j < end; ++j) {
            const unsigned u0 = *(const unsigned*)(p + (size_t)csr[j] * 32 + co);
            s0 += bf2f(u0 & 0xffffu); h0 += bf2f(u0 >> 16);
        }
    }
    float xlo = 0.f, xhi = 0.f, wl0 = 0.f, wl1 = 0.f, wr0 = 0.f, wr1 = 0.f;
    if (hl < 14) {
        xlo = bf2f((unsigned)acc[(size_t)node * 32 + co])     + inv * ((s0 + s1) + (s2 + s3));
        xhi = bf2f((unsigned)acc[(size_t)node * 32 + co + 1]) + inv * ((h0 + h1) + (h2 + h3));
        wl0 = Wl3[co]; wl1 = Wl3[co + 1];
        wr0 = Wr3[co]; wr1 = Wr3[co + 1];
    }
    float sl = xlo * wl0 + xhi * wl1;
    float sr = xlo * wr0 + xhi * wr1;
#pragma unroll
    for (int off = 16; off > 0; off >>= 1) {
        sl += __shfl_xor(sl, off, 64);
        sr += __shfl_xor(sr, off, 64);
    }
    if (hl == 0) {
        p3[node] = sl;
        out[node] = sr + bl3[0];
    }
}

__global__ void gather1_kernel(const int* __restrict__ rowptr, const int* __restrict__ csr,
                               const float* __restrict__ p, float* __restrict__ out, int N) {
    const int node = blockIdx.x * blockDim.x + threadIdx.x;
    if (node >= N) return;
    const int beg = rowptr[node], end = rowptr[node + 1];
    const float inv = 1.0f / (float)max(end - beg, 1);
    float a0 = 0.f, a1 = 0.f, a2 = 0.f, a3 = 0.f;
    int j = beg;
    for (; j + 4 <= end; j += 4) {
        a0 += p[csr[j]]; a1 += p[csr[j + 1]]; a2 += p[csr[j + 2]]; a3 += p[csr[j + 3]];
    }
    for (; j < end; ++j) a0 += p[csr[j]];
    out[node] += inv * ((a0 + a1) + (a2 + a3));
}

// ---------------------------------------------------------------------------

extern "C" void kernel_launch(void* const* d_in, const int* in_sizes, int n_in,
                              void* d_out, int out_size, void* d_ws, size_t ws_size,
                              hipStream_t stream) {
    const float* x  = (const float*)d_in[0];
    const int*   ei = (const int*)d_in[1];
    const int N = NNODES;
    const int E = NEDGES;
    const int* esrc = ei;
    const int* edst = ei + E;

    const float* Wl[4] = {(const float*)d_in[2], (const float*)d_in[5],
                          (const float*)d_in[8], (const float*)d_in[11]};
    const float* bl[4] = {(const float*)d_in[3], (const float*)d_in[6],
                          (const float*)d_in[9], (const float*)d_in[12]};
    const float* Wr[4] = {(const float*)d_in[4], (const float*)d_in[7],
                          (const float*)d_in[10], (const float*)d_in[13]};

    // ---- workspace arena (byte offsets, 256B aligned) ----
    char* base = (char*)d_ws;
    size_t off = 0;
    auto alloc = [&](size_t bytes) {
        char* r = base + off;
        off += (bytes + 255) & ~(size_t)255;
        return r;
    };
    unsigned short* pB   = (unsigned short*)alloc((size_t)N * 96 * 2);
    unsigned short* accB = (unsigned short*)alloc((size_t)N * 96 * 2);
    unsigned short* xp   = (unsigned short*)alloc((size_t)N * 96 * 2);
    float*          p3   = (float*)alloc((size_t)N * 4);
    unsigned short* Wc0  = (unsigned short*)alloc((size_t)192 * 128 * 2);
    unsigned short* Wc1  = (unsigned short*)alloc((size_t)128 * 96 * 2);
    unsigned short* Wc2  = (unsigned short*)alloc((size_t)64 * 64 * 2);
    int* degi   = (int*)alloc((size_t)N * 4);
    int* rowptr = (int*)alloc((size_t)(N + 1) * 4);
    int* cursor = (int*)alloc((size_t)N * 4);
    int* csr    = (int*)alloc((size_t)E * 4);
    int* bsum   = (int*)alloc(512 * 4);

    unsigned short* x2 = xp;   // x1 dead after L1 proj; reuse region for x2

    const int nb = (N + 255) / 256;  // 391
    const int histB = (E + 255) / 256;  // 2500

    // degi = 0, then fused {packAll || hist}
    hipMemsetAsync(degi, 0, (size_t)N * sizeof(int), stream);
    packhist_kernel<<<PACKB + histB, 256, 0, stream>>>(
        Wl[0], Wr[0], Wl[1], Wr[1], Wl[2], Wr[2], Wc0, Wc1, Wc2, edst, degi, E);

    // scans (scanB folded into scanC) + partitioned fill
    scanA_kernel<<<nb, 256, 0, stream>>>(degi, bsum, N);
    scanC_kernel<<<nb, 256, 0, stream>>>(degi, bsum, rowptr, cursor, N, E);
    fillp_kernel<<<2048, 256, 0, stream>>>(esrc, edst, cursor, csr, E, N);

    const int projBlocks = (N + 127) / 128;  // 782

    // Layer 0: K=128 fp32 input, 12 tiles (6 p + 6 acc); p/acc stride 96
    projm_kernel<true, 128, 128, 12, 85, 96><<<projBlocks, 256, 0, stream>>>(
        x, Wc0, bl[0], pB, accB, N);
    gatherb_kernel<85, 96, 96, 1><<<(N + 3) / 4, 256, 0, stream>>>(
        rowptr, csr, pB, accB, xp, N);

    // Layer 1: K=96 (85 zero-padded), 8 tiles (4+4); p/acc stride 64
    projm_kernel<false, 96, 96, 8, 56, 64><<<projBlocks, 256, 0, stream>>>(
        xp, Wc1, bl[1], pB, accB, N);
    gatherb_kernel<56, 64, 64, 2><<<(N + 7) / 8, 256, 0, stream>>>(
        rowptr, csr, pB, accB, x2, N);

    // Layer 2: K=64 (56 zero-padded), 4 tiles (2+2); p/acc stride 32
    projm_kernel<false, 64, 64, 4, 28, 32><<<projBlocks, 256, 0, stream>>>(
        x2, Wc2, bl[2], pB, accB, N);

    // Layer-2 gather + layer-3 GEMV fused (2 nodes/wave); then scalar gather
    gather2g_kernel<<<(N + 7) / 8, 256, 0, stream>>>(
        rowptr, csr, pB, accB, Wl[3], bl[3], Wr[3], p3, (float*)d_out, N);
    gather1_kernel<<<(N + 255) / 256, 256, 0, stream>>>(
        rowptr, csr, p3, (float*)d_out, N);
}

// Round 14
// 216.414 us; speedup vs baseline: 56.3808x; 1.0263x over previous
//
#include <hip/hip_runtime.h>

// ---------------------------------------------------------------------------
// SageCox: 4-layer GraphSAGE (mean aggr), N=100000, E=640000.
// out = mean_neigh(x)@Wl + bl + x@Wr per layer.
// Restructured: p = x@Wl ; acc = bf16(x@Wr + bl) ; x_next = bf16(acc + invdeg*sum p[src]).
// proj = MFMA bf16 (16x16x32, f32 accum), per-phase W staging in LDS, 2-phase
// coalesced bf16x8 epilogue. CSR fill XCD-partitioned (bid%8 -> dst range) and
// FUSED with projm L0 (block-split: fill blocks [0,FILLB), projm after) since
// the two are independent -> fill's atomic latency hides under L0 compute.
// Gather: CSR, paired-uint loads, 4-edge unroll, L1 2 nodes/wave.
// p/acc/xnext rows padded to 96/64/32 elems. L3 GEMV fused into L2 gather.
// 11 dispatches.
// ---------------------------------------------------------------------------

#define NNODES 100000
#define NEDGES 640000
#define FILLB 1024

using bf16x8 = __attribute__((ext_vector_type(8))) short;
using f32x4  = __attribute__((ext_vector_type(4))) float;

__device__ __forceinline__ unsigned short f2bf(float f) {
    union { float f; unsigned u; } v; v.f = f;
    unsigned r = v.u + 0x7fffu + ((v.u >> 16) & 1u);
    return (unsigned short)(r >> 16);
}
__device__ __forceinline__ float bf2f(unsigned b) {
    union { unsigned u; float f; } v; v.u = b << 16;
    return v.f;
}

// ---- weight pack helper ---------------------------------------------------

__device__ __forceinline__ void packT_one(const float* Wl, const float* Wr,
                                          unsigned short* WcT, int idx, int DIN,
                                          int KP, int DOUT, int DOUTP) {
    int c = idx / KP, k = idx - c * KP;
    float v = 0.0f;
    if (k < DIN) {
        if (c < DOUT) v = Wl[k * DOUT + c];
        else if (c >= DOUTP && c < DOUTP + DOUT) v = Wr[k * DOUT + (c - DOUTP)];
    }
    WcT[idx] = f2bf(v);
}

// ---- fused: packAll (blocks [0,PACKB)) || hist (rest) ---------------------

#define PACKB 160

__global__ void packhist_kernel(const float* __restrict__ Wl0, const float* __restrict__ Wr0,
                                const float* __restrict__ Wl1, const float* __restrict__ Wr1,
                                const float* __restrict__ Wl2, const float* __restrict__ Wr2,
                                unsigned short* __restrict__ Wc0,
                                unsigned short* __restrict__ Wc1,
                                unsigned short* __restrict__ Wc2,
                                const int* __restrict__ edst, int* __restrict__ deg, int E) {
    const int S0 = 192 * 128, S1 = 128 * 96, S2 = 64 * 64;
    if (blockIdx.x < PACKB) {
        int idx = blockIdx.x * 256 + threadIdx.x;
        if (idx < S0) packT_one(Wl0, Wr0, Wc0, idx, 128, 128, 85, 96);
        else if (idx < S0 + S1) packT_one(Wl1, Wr1, Wc1, idx - S0, 85, 96, 56, 64);
        else if (idx < S0 + S1 + S2) packT_one(Wl2, Wr2, Wc2, idx - S0 - S1, 56, 64, 28, 32);
    } else {
        int i = (blockIdx.x - PACKB) * 256 + threadIdx.x;
        if (i < E) atomicAdd(&deg[edst[i]], 1);
    }
}

// ---- scans ----------------------------------------------------------------

__global__ void scanA_kernel(const int* __restrict__ deg, int* __restrict__ bsum, int N) {
    __shared__ int s[256];
    int i = blockIdx.x * 256 + threadIdx.x;
    s[threadIdx.x] = (i < N) ? deg[i] : 0;
    __syncthreads();
    for (int off = 128; off > 0; off >>= 1) {
        if (threadIdx.x < off) s[threadIdx.x] += s[threadIdx.x + off];
        __syncthreads();
    }
    if (threadIdx.x == 0) bsum[blockIdx.x] = s[0];
}

// scanC with inlined block-prefix: each block sums bsum[0..blockIdx.x).
__global__ void scanC_kernel(const int* __restrict__ deg, const int* __restrict__ bsum,
                             int* __restrict__ rowptr, int* __restrict__ cursor, int N, int E) {
    __shared__ int s[256];
    int t = threadIdx.x;

    int a = 0;
    for (int j = t; j < blockIdx.x; j += 256) a += bsum[j];
    s[t] = a;
    __syncthreads();
    for (int off = 128; off > 0; off >>= 1) {
        if (t < off) s[t] += s[t + off];
        __syncthreads();
    }
    const int base = s[0];
    __syncthreads();

    int i = blockIdx.x * 256 + t;
    int v = (i < N) ? deg[i] : 0;
    s[t] = v;
    __syncthreads();
    for (int off = 1; off < 256; off <<= 1) {
        int add = (t >= off) ? s[t - off] : 0;
        __syncthreads();
        s[t] += add;
        __syncthreads();
    }
    if (i < N) {
        int excl = base + s[t] - v;
        rowptr[i] = excl;
        cursor[i] = excl;
        if (i == N - 1) rowptr[N] = E;
    }
}

// ---- MFMA projection body: per-phase W in LDS + 2-phase epilogue ----------

template <bool XFP32, int KP, int SIN, int NTILES, int DOUT, int SPP>
__device__ __forceinline__ void
projm_body(int bid, const void* __restrict__ xin,
           const unsigned short* __restrict__ WcT,
           const float* __restrict__ bl,
           unsigned short* __restrict__ p,
           unsigned short* __restrict__ acc_out, int N) {
    constexpr int KT   = KP / 32;
    constexpr int HT   = NTILES / 2;
    constexpr int WSTR = KP + 8;
    constexpr int LSTR = SPP + 8;
    static_assert(HT * 16 == SPP, "phase width must equal SPP");
    __shared__ short wS[HT * 16 * WSTR];
    __shared__ short oS[128 * LSTR];

    const int lane = threadIdx.x & 63;
    const int wave = threadIdx.x >> 6;
    const int l15 = lane & 15;
    const int lk  = lane >> 4;
    const int row0 = bid * 128;
    const int wrow = wave * 32;

    auto stageW = [&](int colbase) {
        for (int c8 = threadIdx.x; c8 < HT * 16 * (KP / 8); c8 += 256) {
            const int c  = c8 / (KP / 8);
            const int k8 = c8 - c * (KP / 8);
            *(bf16x8*)(wS + c * WSTR + k8 * 8) =
                *(const bf16x8*)(WcT + (size_t)(colbase + c) * KP + k8 * 8);
        }
    };

    stageW(0);

    bf16x8 afrag[2][KT];
#pragma unroll
    for (int h = 0; h < 2; ++h) {
        int arow = row0 + wrow + h * 16 + l15;
        if (arow >= N) arow = N - 1;
        if constexpr (XFP32) {
            const float* xr = (const float*)xin + (size_t)arow * SIN + lk * 8;
#pragma unroll
            for (int kt = 0; kt < KT; ++kt) {
                const float4 a = *(const float4*)(xr + kt * 32);
                const float4 b = *(const float4*)(xr + kt * 32 + 4);
                bf16x8 v;
                v[0] = (short)f2bf(a.x); v[1] = (short)f2bf(a.y);
                v[2] = (short)f2bf(a.z); v[3] = (short)f2bf(a.w);
                v[4] = (short)f2bf(b.x); v[5] = (short)f2bf(b.y);
                v[6] = (short)f2bf(b.z); v[7] = (short)f2bf(b.w);
                afrag[h][kt] = v;
            }
        } else {
            const unsigned short* xr = (const unsigned short*)xin + (size_t)arow * SIN + lk * 8;
#pragma unroll
            for (int kt = 0; kt < KT; ++kt)
                afrag[h][kt] = *(const bf16x8*)(xr + kt * 32);
        }
    }

    __syncthreads();

    const int rows_here = min(128, N - row0);
    const int cnt8 = rows_here * (SPP / 8);

    auto computePhase = [&](bool withBias) {
#pragma unroll 2
        for (int nt = 0; nt < HT; ++nt) {
            const short* wp = wS + (size_t)(nt * 16 + l15) * WSTR + lk * 8;
            bf16x8 bfrag[KT];
#pragma unroll
            for (int kt = 0; kt < KT; ++kt)
                bfrag[kt] = *(const bf16x8*)(wp + kt * 32);

            f32x4 a0 = {0.f, 0.f, 0.f, 0.f};
            f32x4 a1 = {0.f, 0.f, 0.f, 0.f};
#pragma unroll
            for (int kt = 0; kt < KT; ++kt) {
                a0 = __builtin_amdgcn_mfma_f32_16x16x32_bf16(afrag[0][kt], bfrag[kt], a0, 0, 0, 0);
                a1 = __builtin_amdgcn_mfma_f32_16x16x32_bf16(afrag[1][kt], bfrag[kt], a1, 0, 0, 0);
            }

            const int co = nt * 16 + l15;
            const float bias = (withBias && co < DOUT) ? bl[co] : 0.0f;
#pragma unroll
            for (int h = 0; h < 2; ++h) {
                const f32x4 a = h ? a1 : a0;
                const int rl = wrow + h * 16 + lk * 4;
#pragma unroll
                for (int j = 0; j < 4; ++j)
                    oS[(rl + j) * LSTR + co] = (short)f2bf(a[j] + bias);
            }
        }
    };

    auto storeOut = [&](unsigned short* dst) {
        for (int e8 = threadIdx.x; e8 < cnt8; e8 += 256) {
            const int row = e8 / (SPP / 8);
            const int c8  = e8 - row * (SPP / 8);
            *(bf16x8*)(dst + (size_t)row0 * SPP + (size_t)e8 * 8) =
                *(const bf16x8*)(oS + row * LSTR + c8 * 8);
        }
    };

    computePhase(false);
    __syncthreads();
    storeOut(p);
    stageW(HT * 16);
    __syncthreads();
    computePhase(true);
    __syncthreads();
    storeOut(acc_out);
}

template <bool XFP32, int KP, int SIN, int NTILES, int DOUT, int SPP>
__global__ void __launch_bounds__(256)
projm_kernel(const void* __restrict__ xin,
             const unsigned short* __restrict__ WcT,
             const float* __restrict__ bl,
             unsigned short* __restrict__ p,
             unsigned short* __restrict__ acc_out, int N) {
    projm_body<XFP32, KP, SIN, NTILES, DOUT, SPP>(blockIdx.x, xin, WcT, bl, p, acc_out, N);
}

// ---- fused: XCD-partitioned CSR fill (blocks [0,FILLB)) || projm L0 -------
// Fill partition p = fb%8 owns dst range [p*N/8, ...); sub-blocks grid-stride
// the edge list and filter (heuristic fb%8==XCD keeps each csr/cursor region
// in one L2; correctness independent of mapping). projm blocks follow.

__global__ void __launch_bounds__(256)
projfill_kernel(const float* __restrict__ x,
                const unsigned short* __restrict__ Wc0,
                const float* __restrict__ bl0,
                unsigned short* __restrict__ p,
                unsigned short* __restrict__ acc_out, int N,
                const int* __restrict__ esrc, const int* __restrict__ edst,
                int* __restrict__ cursor, int* __restrict__ csr, int E) {
    if (blockIdx.x < FILLB) {
        const int part = blockIdx.x & 7;
        const int sub  = blockIdx.x >> 3;
        const int nsub = FILLB >> 3;
        const int chunk = N >> 3;
        const int lo = part * chunk;
        const int hi = (part == 7) ? N : lo + chunk;
        for (int i = sub * 256 + threadIdx.x; i < E; i += nsub * 256) {
            const int d = edst[i];
            if (d >= lo && d < hi) {
                int pos = atomicAdd(&cursor[d], 1);
                csr[pos] = esrc[i];
            }
        }
        return;
    }
    projm_body<true, 128, 128, 12, 85, 96>(blockIdx.x - FILLB, x, Wc0, bl0, p, acc_out, N);
}

// ---- gather: x_next = bf16(acc + invdeg * sum p[src]) ---------------------

template <int DOUT, int SP, int SN, int NPW>
__global__ void __launch_bounds__(256)
gatherb_kernel(const int* __restrict__ rowptr, const int* __restrict__ csr,
               const unsigned short* __restrict__ p, const unsigned short* __restrict__ acc,
               unsigned short* __restrict__ xnext, int N) {
    const int wid  = (blockIdx.x * 256 + threadIdx.x) >> 6;
    const int lane = threadIdx.x & 63;
    int node, hl;
    if constexpr (NPW == 1) {
        node = __builtin_amdgcn_readfirstlane(wid);
        hl = lane;
    } else {
        node = wid * 2 + (lane >> 5);
        hl = lane & 31;
    }
    if (node >= N) return;
    const int beg = rowptr[node], end = rowptr[node + 1];
    const float inv = 1.0f / (float)max(end - beg, 1);
    constexpr int NPAIR = (DOUT + 1) / 2;
    const int co = 2 * hl;

    float s0 = 0.f, s1 = 0.f, s2 = 0.f, s3 = 0.f;
    float h0 = 0.f, h1 = 0.f, h2 = 0.f, h3 = 0.f;
    if (hl < NPAIR) {
        int j = beg;
        for (; j + 4 <= end; j += 4) {
            const unsigned u0 = *(const unsigned*)(p + (size_t)csr[j]     * SP + co);
            const unsigned u1 = *(const unsigned*)(p + (size_t)csr[j + 1] * SP + co);
            const unsigned u2 = *(const unsigned*)(p + (size_t)csr[j + 2] * SP + co);
            const unsigned u3 = *(const unsigned*)(p + (size_t)csr[j + 3] * SP + co);
            s0 += bf2f(u0 & 0xffffu); h0 += bf2f(u0 >> 16);
            s1 += bf2f(u1 & 0xffffu); h1 += bf2f(u1 >> 16);
            s2 += bf2f(u2 & 0xffffu); h2 += bf2f(u2 >> 16);
            s3 += bf2f(u3 & 0xffffu); h3 += bf2f(u3 >> 16);
        }
        for (; j < end; ++j) {
            const unsigned u0 = *(const unsigned*)(p + (size_t)csr[j] * SP + co);
            s0 += bf2f(u0 & 0xffffu); h0 += bf2f(u0 >> 16);
        }
    }
    if (co < SN) {
        const float slo = (s0 + s1) + (s2 + s3);
        const float shi = (h0 + h1) + (h2 + h3);
        float lo = 0.f, hi = 0.f;
        if (co < DOUT)     lo = bf2f((unsigned)acc[(size_t)node * SP + co])     + inv * slo;
        if (co + 1 < DOUT) hi = bf2f((unsigned)acc[(size_t)node * SP + co + 1]) + inv * shi;
        const unsigned w = (unsigned)f2bf(lo) | ((unsigned)f2bf(hi) << 16);
        *(unsigned*)(xnext + (size_t)node * SN + co) = w;
    }
}

// ---- layer-2 gather fused with layer-3 GEMV (28 -> 1), 2 nodes/wave -------

__global__ void __launch_bounds__(256)
gather2g_kernel(const int* __restrict__ rowptr, const int* __restrict__ csr,
                const unsigned short* __restrict__ p, const unsigned short* __restrict__ acc,
                const float* __restrict__ Wl3, const float* __restrict__ bl3,
                const float* __restrict__ Wr3,
                float* __restrict__ p3, float* __restrict__ out, int N) {
    const int wid  = (blockIdx.x * 256 + threadIdx.x) >> 6;
    const int lane = threadIdx.x & 63;
    const int node = wid * 2 + (lane >> 5);
    const int hl   = lane & 31;
    if (node >= N) return;
    const int beg = rowptr[node], end = rowptr[node + 1];
    const float inv = 1.0f / (float)max(end - beg, 1);
    const int co = 2 * hl;

    float s0 = 0.f, s1 = 0.f, s2 = 0.f, s3 = 0.f;
    float h0 = 0.f, h1 = 0.f, h2 = 0.f, h3 = 0.f;
    if (hl < 14) {
        int j = beg;
        for (; j + 4 <= end; j += 4) {
            const unsigned u0 = *(const unsigned*)(p + (size_t)csr[j]     * 32 + co);
            const unsigned u1 = *(const unsigned*)(p + (size_t)csr[j + 1] * 32 + co);
            const unsigned u2 = *(const unsigned*)(p + (size_t)csr[j + 2] * 32 + co);
            const unsigned u3 = *(const unsigned*)(p + (size_t)csr[j + 3] * 32 + co);
            s0 += bf2f(u0 & 0xffffu); h0 += bf2f(u0 >> 16);
            s1 += bf2f(u1 & 0xffffu); h1 += bf2f(u1 >> 16);
            s2 += bf2f(u2 & 0xffffu); h2 += bf2f(u2 >> 16);
            s3 += bf2f(u3 & 0xffffu); h3 += bf2f(u3 >> 16);
        }
        for (; j < end; ++j) {
            const unsigned u0 = *(const unsigned*)(p + (size_t)csr[j] * 32 + co);
            s0 += bf2f(u0 & 0xffffu); h0 += bf2f(u0 >> 16);
        }
    }
    float xlo = 0.f, xhi = 0.f, wl0 = 0.f, wl1 = 0.f, wr0 = 0.f, wr1 = 0.f;
    if (hl < 14) {
        xlo = bf2f((unsigned)acc[(size_t)node * 32 + co])     + inv * ((s0 + s1) + (s2 + s3));
        xhi = bf2f((unsigned)acc[(size_t)node * 32 + co + 1]) + inv * ((h0 + h1) + (h2 + h3));
        wl0 = Wl3[co]; wl1 = Wl3[co + 1];
        wr0 = Wr3[co]; wr1 = Wr3[co + 1];
    }
    float sl = xlo * wl0 + xhi * wl1;
    float sr = xlo * wr0 + xhi * wr1;
#pragma unroll
    for (int off = 16; off > 0; off >>= 1) {
        sl += __shfl_xor(sl, off, 64);
        sr += __shfl_xor(sr, off, 64);
    }
    if (hl == 0) {
        p3[node] = sl;
        out[node] = sr + bl3[0];
    }
}

__global__ void gather1_kernel(const int* __restrict__ rowptr, const int* __restrict__ csr,
                               const float* __restrict__ p, float* __restrict__ out, int N) {
    const int node = blockIdx.x * blockDim.x + threadIdx.x;
    if (node >= N) return;
    const int beg = rowptr[node], end = rowptr[node + 1];
    const float inv = 1.0f / (float)max(end - beg, 1);
    float a0 = 0.f, a1 = 0.f, a2 = 0.f, a3 = 0.f;
    int j = beg;
    for (; j + 4 <= end; j += 4) {
        a0 += p[csr[j]]; a1 += p[csr[j + 1]]; a2 += p[csr[j + 2]]; a3 += p[csr[j + 3]];
    }
    for (; j < end; ++j) a0 += p[csr[j]];
    out[node] += inv * ((a0 + a1) + (a2 + a3));
}

// ---------------------------------------------------------------------------

extern "C" void kernel_launch(void* const* d_in, const int* in_sizes, int n_in,
                              void* d_out, int out_size, void* d_ws, size_t ws_size,
                              hipStream_t stream) {
    const float* x  = (const float*)d_in[0];
    const int*   ei = (const int*)d_in[1];
    const int N = NNODES;
    const int E = NEDGES;
    const int* esrc = ei;
    const int* edst = ei + E;

    const float* Wl[4] = {(const float*)d_in[2], (const float*)d_in[5],
                          (const float*)d_in[8], (const float*)d_in[11]};
    const float* bl[4] = {(const float*)d_in[3], (const float*)d_in[6],
                          (const float*)d_in[9], (const float*)d_in[12]};
    const float* Wr[4] = {(const float*)d_in[4], (const float*)d_in[7],
                          (const float*)d_in[10], (const float*)d_in[13]};

    // ---- workspace arena (byte offsets, 256B aligned) ----
    char* base = (char*)d_ws;
    size_t off = 0;
    auto alloc = [&](size_t bytes) {
        char* r = base + off;
        off += (bytes + 255) & ~(size_t)255;
        return r;
    };
    unsigned short* pB   = (unsigned short*)alloc((size_t)N * 96 * 2);
    unsigned short* accB = (unsigned short*)alloc((size_t)N * 96 * 2);
    unsigned short* xp   = (unsigned short*)alloc((size_t)N * 96 * 2);
    float*          p3   = (float*)alloc((size_t)N * 4);
    unsigned short* Wc0  = (unsigned short*)alloc((size_t)192 * 128 * 2);
    unsigned short* Wc1  = (unsigned short*)alloc((size_t)128 * 96 * 2);
    unsigned short* Wc2  = (unsigned short*)alloc((size_t)64 * 64 * 2);
    int* degi   = (int*)alloc((size_t)N * 4);
    int* rowptr = (int*)alloc((size_t)(N + 1) * 4);
    int* cursor = (int*)alloc((size_t)N * 4);
    int* csr    = (int*)alloc((size_t)E * 4);
    int* bsum   = (int*)alloc(512 * 4);

    unsigned short* x2 = xp;   // x1 dead after L1 proj; reuse region for x2

    const int nb = (N + 255) / 256;     // 391
    const int histB = (E + 255) / 256;  // 2500
    const int projBlocks = (N + 127) / 128;  // 782

    // degi = 0, then fused {packAll || hist}
    hipMemsetAsync(degi, 0, (size_t)N * sizeof(int), stream);
    packhist_kernel<<<PACKB + histB, 256, 0, stream>>>(
        Wl[0], Wr[0], Wl[1], Wr[1], Wl[2], Wr[2], Wc0, Wc1, Wc2, edst, degi, E);

    // scans (scanB folded into scanC)
    scanA_kernel<<<nb, 256, 0, stream>>>(degi, bsum, N);
    scanC_kernel<<<nb, 256, 0, stream>>>(degi, bsum, rowptr, cursor, N, E);

    // fused {partitioned fill || projm L0}
    projfill_kernel<<<FILLB + projBlocks, 256, 0, stream>>>(
        x, Wc0, bl[0], pB, accB, N, esrc, edst, cursor, csr, E);
    gatherb_kernel<85, 96, 96, 1><<<(N + 3) / 4, 256, 0, stream>>>(
        rowptr, csr, pB, accB, xp, N);

    // Layer 1: K=96 (85 zero-padded), 8 tiles (4+4); p/acc stride 64
    projm_kernel<false, 96, 96, 8, 56, 64><<<projBlocks, 256, 0, stream>>>(
        xp, Wc1, bl[1], pB, accB, N);
    gatherb_kernel<56, 64, 64, 2><<<(N + 7) / 8, 256, 0, stream>>>(
        rowptr, csr, pB, accB, x2, N);

    // Layer 2: K=64 (56 zero-padded), 4 tiles (2+2); p/acc stride 32
    projm_kernel<false, 64, 64, 4, 28, 32><<<projBlocks, 256, 0, stream>>>(
        x2, Wc2, bl[2], pB, accB, N);

    // Layer-2 gather + layer-3 GEMV fused (2 nodes/wave); then scalar gather
    gather2g_kernel<<<(N + 7) / 8, 256, 0, stream>>>(
        rowptr, csr, pB, accB, Wl[3], bl[3], Wr[3], p3, (float*)d_out, N);
    gather1_kernel<<<(N + 255) / 256, 256, 0, stream>>>(
        rowptr, csr, p3, (float*)d_out, N);
}